// Round 5
// baseline (455.263 us; speedup 1.0000x reference)
//
#include <hip/hip_runtime.h>
#include <math.h>

#define TT   1024
#define BBZ  4
#define DD   512
#define DFF_ 2048
#define HH   8
#define DKK  64
#define NTOK 4096
#define EPSF 1e-5f
#define MB   1048576

typedef unsigned short u16;
typedef __attribute__((ext_vector_type(8))) short s8v;    // 8 bf16 (4 VGPRs)
typedef __attribute__((ext_vector_type(4))) float f32x4;
typedef __attribute__((ext_vector_type(4))) unsigned short us4;

__device__ __forceinline__ float b2f(u16 v){
    union { unsigned int u; float f; } x; x.u = ((unsigned int)v) << 16; return x.f;
}
__device__ __forceinline__ u16 f2b(float f){
    union { float f; unsigned int u; } x; x.f = f;
    unsigned int r = x.u + 0x7fffu + ((x.u >> 16) & 1u);
    return (u16)(r >> 16);
}
__device__ __forceinline__ float sigmoidf_(float x){ return 1.0f/(1.0f+__expf(-x)); }

__device__ __forceinline__ void gld16(const u16* g, u16* l){
    __builtin_amdgcn_global_load_lds(
        (const __attribute__((address_space(1))) unsigned int*)g,
        (__attribute__((address_space(3))) unsigned int*)l, 16, 0, 0);
}

// ================= batched MFMA GEMM =================
// C = epilogue(A @ B^T_view), A:(M,K) bf16 row-major, B:(N,K) bf16 row-major.
// OMODE 0: f32 out (+bias, act, *alpha, +resid)   1: bf16 out (+bias, act)
// OMODE 5: merged QKV epilogue. Cv=qub; qvb/kb/vt at fixed elem offsets
//          (2M, 4M, 6M). gn<512: dual q store (+posu/+posv); <1024: k; else v^T.
template<int OMODE>
__global__ __launch_bounds__(256) void bgemm(
    const u16* __restrict__ A, int lda, long sAb, long sAh,
    const u16* __restrict__ B, int ldb, long sBb, long sBh,
    void* __restrict__ Cv, int ldc, long sCb, long sCh,
    int M, int N, int K,
    const float* __restrict__ bias, int act, float alpha,
    const float* __restrict__ resid,
    const float* __restrict__ posu, const float* __restrict__ posv)
{
    int z  = blockIdx.z;
    int zb = z >> 3, zh = z & 7;
    int n0 = blockIdx.x * 64;
    int m0 = blockIdx.y * 128;
    const u16* Ab = A + (size_t)zb*sAb + (size_t)zh*sAh;
    const u16* Bb = B + (size_t)zb*sBb + (size_t)zh*sBh;

    __shared__ u16 As[128*64];
    __shared__ u16 Bs[64*64];

    int t = threadIdx.x;
    int w = t >> 6, l = t & 63;
    int lrow = l >> 3, lslot = l & 7;
    int kswz = (lslot ^ lrow) * 8;
    int wm = w >> 1, wn = w & 1;
    int lr = l & 15, lk = l >> 4;

    f32x4 acc[4][2] = {};

    for (int k0 = 0; k0 < K; k0 += 64){
        #pragma unroll
        for (int it = 0; it < 4; ++it){
            int rb = it*32 + w*8;
            gld16(Ab + (size_t)(m0 + rb + lrow)*lda + k0 + kswz, &As[rb*64]);
        }
        #pragma unroll
        for (int it = 0; it < 2; ++it){
            int rb = it*32 + w*8;
            gld16(Bb + (size_t)(n0 + rb + lrow)*ldb + k0 + kswz, &Bs[rb*64]);
        }
        __syncthreads();

        s8v af[2][4], bf[2][2];
        #pragma unroll
        for (int kh = 0; kh < 2; ++kh){
            #pragma unroll
            for (int mi = 0; mi < 4; ++mi){
                int row = wm*64 + mi*16 + lr;
                int sl  = (kh*4 + lk) ^ (lr & 7);
                af[kh][mi] = *(const s8v*)&As[row*64 + sl*8];
            }
            #pragma unroll
            for (int ni = 0; ni < 2; ++ni){
                int row = wn*32 + ni*16 + lr;
                int sl  = (kh*4 + lk) ^ (lr & 7);
                bf[kh][ni] = *(const s8v*)&Bs[row*64 + sl*8];
            }
        }
        #pragma unroll
        for (int kh = 0; kh < 2; ++kh)
            #pragma unroll
            for (int mi = 0; mi < 4; ++mi)
                #pragma unroll
                for (int ni = 0; ni < 2; ++ni)
                    acc[mi][ni] = __builtin_amdgcn_mfma_f32_16x16x32_bf16(
                        af[kh][mi], bf[kh][ni], acc[mi][ni], 0, 0, 0);
        __syncthreads();
    }

    #pragma unroll
    for (int mi = 0; mi < 4; ++mi){
        #pragma unroll
        for (int ni = 0; ni < 2; ++ni){
            int gn = n0 + wn*32 + ni*16 + lr;
            float bval = bias ? bias[gn] : 0.0f;
            #pragma unroll
            for (int r = 0; r < 4; ++r){
                int gm = m0 + wm*64 + mi*16 + lk*4 + r;
                float vv = acc[mi][ni][r] + bval;
                if (act) vv = vv * sigmoidf_(vv);
                if (OMODE == 0){
                    vv *= alpha;
                    if (resid) vv += resid[(size_t)gm*ldc + gn];
                    ((float*)Cv)[(size_t)zb*sCb + (size_t)zh*sCh + (size_t)gm*ldc + gn] = vv;
                } else if (OMODE == 1){
                    ((u16*)Cv)[(size_t)zb*sCb + (size_t)zh*sCh + (size_t)gm*ldc + gn] = f2b(vv);
                } else { // 5: merged QKV
                    u16* base = (u16*)Cv;
                    if (gn < 512){
                        size_t idx = (size_t)gm*512 + gn;
                        base[idx]              = f2b(vv + posu[gn]);
                        base[idx + (2u<<20)]   = f2b(vv + posv[gn]);
                    } else if (gn < 1024){
                        base[(4u<<20) + (size_t)gm*512 + (gn-512)] = f2b(vv);
                    } else {
                        int gnp = gn - 1024;
                        int bb = gm >> 10, tt2 = gm & 1023;
                        size_t idx = (((size_t)(bb*8 + (gnp>>6)))*64 + (gnp&63))*1024 + tt2;
                        base[(6u<<20) + idx] = f2b(vv);
                    }
                }
            }
        }
    }
}

// ================= fused rel-pos flash attention (j-split flash-decoding) ====
// grid 1024 blocks: s -> z=(s&7)|((s>>8)<<3) (XCD-grouped), ih=(s>>3)&31,
// i0=(ih>>1)*64, half=ih&1 (j in [half*512, half*512+512)).
__global__ __launch_bounds__(256, 4) void attn_fused(
    const u16* __restrict__ qub, const u16* __restrict__ qvb,
    const u16* __restrict__ kb,  const u16* __restrict__ vt,
    const u16* __restrict__ pp,
    float* __restrict__ opart, float* __restrict__ mlpart)
{
    int s  = blockIdx.x;
    int z  = (s & 7) | ((s >> 8) << 3);
    int ih = (s >> 3) & 31;
    int i0   = (ih >> 1) * 64;
    int half = ih & 1;
    int b = z >> 3, hh = z & 7;
    int j0beg = half * 512;

    __shared__ u16 KV[64*64];        // K then V (dual-use)
    __shared__ u16 Ps[128*64];       // P stage; rows 0..63 alias P-tilde
    __shared__ float Band[64*64];    // shifted bd band, rotate-swizzled

    int t = threadIdx.x;
    int w = t >> 6, l = t & 63;
    int lrow = l >> 3, lslot = l & 7;
    int kswz = (lslot ^ lrow) * 8;
    int lr = l & 15, lk = l >> 4;

    // stage Q (qu -> Ps rows 0..63, qv -> rows 64..127), frags to regs
    #pragma unroll
    for (int it = 0; it < 2; ++it){
        int rb = it*32 + w*8;
        gld16(qub + (size_t)(b*TT + i0 + rb + lrow)*DD + hh*64 + kswz, &Ps[rb*64]);
        gld16(qvb + (size_t)(b*TT + i0 + rb + lrow)*DD + hh*64 + kswz, &Ps[(64+rb)*64]);
    }
    __syncthreads();
    s8v af_u[2], af_v[2];
    #pragma unroll
    for (int kh = 0; kh < 2; ++kh){
        int sl = (kh*4 + lk) ^ (lr & 7);
        af_u[kh] = *(const s8v*)&Ps[(w*16 + lr)*64 + sl*8];
        af_v[kh] = *(const s8v*)&Ps[(64 + w*16 + lr)*64 + sl*8];
    }

    f32x4 o[4] = {};
    float M_[4], L_[4];
    #pragma unroll
    for (int r = 0; r < 4; ++r){ M_[r] = -3e38f; L_[r] = 0.0f; }

    for (int jt = 0; jt < 8; ++jt){
        int j0 = j0beg + jt*64;
        int r0 = 960 + j0 - i0;
        __syncthreads();   // prev PV reads done; KV/Ps free (also covers Q-frag reads)
        #pragma unroll
        for (int it = 0; it < 2; ++it){
            int rb = it*32 + w*8;
            gld16(kb + (size_t)(b*TT + j0 + rb + lrow)*DD + hh*64 + kswz, &KV[rb*64]);
        }
        #pragma unroll
        for (int it = 0; it < 4; ++it){
            int rb = it*32 + w*8;
            gld16(pp + (size_t)(r0 + rb + lrow)*DD + hh*64 + kswz, &Ps[rb*64]);
        }
        __syncthreads();   // staged

        // ---- S_ac (16x64) and G (16x128) per wave ----
        f32x4 sac[4] = {};
        f32x4 g[8] = {};
        #pragma unroll
        for (int kh = 0; kh < 2; ++kh){
            int sl = (kh*4 + lk) ^ (lr & 7);
            #pragma unroll
            for (int n = 0; n < 4; ++n){
                s8v bK = *(const s8v*)&KV[(n*16 + lr)*64 + sl*8];
                sac[n] = __builtin_amdgcn_mfma_f32_16x16x32_bf16(af_u[kh], bK, sac[n], 0,0,0);
            }
            #pragma unroll
            for (int n = 0; n < 8; ++n){
                s8v bP = *(const s8v*)&Ps[(n*16 + lr)*64 + sl*8];
                g[n] = __builtin_amdgcn_mfma_f32_16x16x32_bf16(af_v[kh], bP, g[n], 0,0,0);
            }
        }
        // write band portion of G to LDS (f32, rotate swizzle, predicated)
        #pragma unroll
        for (int n = 0; n < 8; ++n)
            #pragma unroll
            for (int r = 0; r < 4; ++r){
                int ii = w*16 + lk*4 + r;
                int jj = n*16 + lr - 63 + ii;
                if (jj >= 0 && jj < 64)
                    Band[ii*64 + ((jj + 4*ii) & 63)] = g[n][r];
            }
        __syncthreads();   // all K/P reads done; Band visible

        // stage V into KV (lands before next barrier's vmcnt drain)
        #pragma unroll
        for (int it = 0; it < 2; ++it){
            int rb = it*32 + w*8;
            gld16(vt + ((size_t)z*64 + rb + lrow)*TT + j0 + kswz, &KV[rb*64]);
        }

        // ---- combine band + online softmax ----
        float p_[4][4], sc_[4];
        #pragma unroll
        for (int r = 0; r < 4; ++r){
            int ii = w*16 + lk*4 + r;
            float sv[4]; float mx = -3e38f;
            #pragma unroll
            for (int n = 0; n < 4; ++n){
                int jj = n*16 + lr;
                float vvv = (sac[n][r] + Band[ii*64 + ((jj + 4*ii) & 63)]) * 0.125f;
                sv[n] = vvv; mx = fmaxf(mx, vvv);
            }
            #pragma unroll
            for (int msk = 1; msk < 16; msk <<= 1) mx = fmaxf(mx, __shfl_xor(mx, msk));
            float nm = fmaxf(M_[r], mx);
            float scale = __expf(M_[r] - nm);
            float rs = 0.0f;
            #pragma unroll
            for (int n = 0; n < 4; ++n){ p_[n][r] = __expf(sv[n] - nm); rs += p_[n][r]; }
            #pragma unroll
            for (int msk = 1; msk < 16; msk <<= 1) rs += __shfl_xor(rs, msk);
            L_[r] = L_[r]*scale + rs;
            M_[r] = nm;
            sc_[r] = scale;
        }
        #pragma unroll
        for (int n = 0; n < 4; ++n)
            #pragma unroll
            for (int r = 0; r < 4; ++r)
                o[n][r] *= sc_[r];

        // write P-tilde (swizzled bf16) into Ps rows 0..63 (P reads done)
        #pragma unroll
        for (int n = 0; n < 4; ++n)
            #pragma unroll
            for (int r = 0; r < 4; ++r){
                int ii  = w*16 + lk*4 + r;
                int col = n*16 + lr;
                int sl  = (col>>3) ^ (ii&7);
                Ps[ii*64 + sl*8 + (col&7)] = f2b(p_[n][r]);
            }
        __syncthreads();   // V staged + P-tilde visible

        // ---- PV ----
        #pragma unroll
        for (int kh = 0; kh < 2; ++kh){
            int sl = (kh*4 + lk) ^ (lr & 7);
            s8v ap = *(const s8v*)&Ps[(w*16 + lr)*64 + sl*8];
            #pragma unroll
            for (int n = 0; n < 4; ++n){
                s8v bV = *(const s8v*)&KV[(n*16 + lr)*64 + sl*8];
                o[n] = __builtin_amdgcn_mfma_f32_16x16x32_bf16(ap, bV, o[n], 0,0,0);
            }
        }
    }

    // ---- store partial (o, M, L) ----
    size_t zs = (size_t)(half*32 + z);
    #pragma unroll
    for (int n = 0; n < 4; ++n)
        #pragma unroll
        for (int r = 0; r < 4; ++r){
            int i = i0 + w*16 + lk*4 + r;
            opart[(zs*TT + i)*64 + n*16 + lr] = o[n][r];
        }
    if (lr == 0){
        #pragma unroll
        for (int r = 0; r < 4; ++r){
            int i = i0 + w*16 + lk*4 + r;
            mlpart[(zs*TT + i)*2 + 0] = M_[r];
            mlpart[(zs*TT + i)*2 + 1] = L_[r];
        }
    }
}

// merge the two j-halves: out = (o0*e0 + o1*e1)/(L0*e0 + L1*e1)
__global__ __launch_bounds__(256) void attn_combine(
    const float* __restrict__ opart, const float* __restrict__ ml,
    u16* __restrict__ out)
{
    int idx = blockIdx.x*256 + threadIdx.x;    // 32*1024*64
    int d = idx & 63;
    int i = (idx >> 6) & 1023;
    int z = idx >> 16;
    size_t row0 = (size_t)z*TT + i, row1 = (size_t)(32+z)*TT + i;
    float M0 = ml[row0*2], L0 = ml[row0*2+1];
    float M1 = ml[row1*2], L1 = ml[row1*2+1];
    float Mx = fmaxf(M0, M1);
    float e0 = __expf(M0 - Mx), e1 = __expf(M1 - Mx);
    float o0 = opart[row0*64 + d], o1 = opart[row1*64 + d];
    float val = (o0*e0 + o1*e1) / (L0*e0 + L1*e1);
    out[((size_t)(z>>3)*TT + i)*DD + (z&7)*64 + d] = f2b(val);
}

// ================= LayerNorm: wave per row, shuffle reduce, no barriers =====
template<int OB>
__global__ __launch_bounds__(256) void ln_kernel(const float* __restrict__ in,
    const float* __restrict__ g, const float* __restrict__ b, void* __restrict__ outv)
{
    int w = threadIdx.x >> 6, l = threadIdx.x & 63;
    int row = blockIdx.x*4 + w;
    const float4* xr = (const float4*)(in + (size_t)row*DD);
    float4 v0 = xr[l], v1 = xr[64 + l];
    float s = v0.x+v0.y+v0.z+v0.w + v1.x+v1.y+v1.z+v1.w;
    float q = v0.x*v0.x+v0.y*v0.y+v0.z*v0.z+v0.w*v0.w
            + v1.x*v1.x+v1.y*v1.y+v1.z*v1.z+v1.w*v1.w;
    #pragma unroll
    for (int msk = 1; msk < 64; msk <<= 1){
        s += __shfl_xor(s, msk);
        q += __shfl_xor(q, msk);
    }
    float mean = s*(1.0f/DD);
    float var  = q*(1.0f/DD) - mean*mean;
    float inv  = rsqrtf(var+EPSF);
    float4 g0 = ((const float4*)g)[l], g1 = ((const float4*)g)[64+l];
    float4 b0 = ((const float4*)b)[l], b1 = ((const float4*)b)[64+l];
    float y0x=(v0.x-mean)*inv*g0.x+b0.x, y0y=(v0.y-mean)*inv*g0.y+b0.y;
    float y0z=(v0.z-mean)*inv*g0.z+b0.z, y0w=(v0.w-mean)*inv*g0.w+b0.w;
    float y1x=(v1.x-mean)*inv*g1.x+b1.x, y1y=(v1.y-mean)*inv*g1.y+b1.y;
    float y1z=(v1.z-mean)*inv*g1.z+b1.z, y1w=(v1.w-mean)*inv*g1.w+b1.w;
    if (OB){
        us4 o0 = { f2b(y0x), f2b(y0y), f2b(y0z), f2b(y0w) };
        us4 o1 = { f2b(y1x), f2b(y1y), f2b(y1z), f2b(y1w) };
        us4* op = (us4*)((u16*)outv + (size_t)row*DD);
        op[l] = o0; op[64+l] = o1;
    } else {
        float4 o0 = { y0x, y0y, y0z, y0w };
        float4 o1 = { y1x, y1y, y1z, y1w };
        float4* op = (float4*)((float*)outv + (size_t)row*DD);
        op[l] = o0; op[64+l] = o1;
    }
}

// ================= consolidated weight prep =================
struct Prep9 {
    const float* s[9];
    u16* d[9];
    int R[9], C[9];
    int t0[10];
};

__global__ __launch_bounds__(256) void prep_transpose(Prep9 P)
{
    __shared__ float tile[32][33];
    int bid = blockIdx.x;
    int j = 0;
    #pragma unroll
    for (int e=1; e<9; e++) if (bid >= P.t0[e]) j = e;
    int lb = bid - P.t0[j];
    int nx = P.C[j] >> 5;
    int c0 = (lb % nx) << 5;
    int r0 = (lb / nx) << 5;
    const float* in = P.s[j];
    u16* out = P.d[j];
    int R = P.R[j], C = P.C[j];
    int tx = threadIdx.x & 31, ty = threadIdx.x >> 5;
    #pragma unroll
    for (int i=0;i<4;i++){
        int rr = ty + i*8;
        tile[rr][tx] = in[(size_t)(r0+rr)*C + c0+tx];
    }
    __syncthreads();
    #pragma unroll
    for (int i=0;i<4;i++){
        int cc = ty + i*8;
        out[(size_t)(c0+cc)*R + r0+tx] = f2b(tile[tx][cc]);
    }
}

__global__ __launch_bounds__(256) void prep_convert(
    const float* __restrict__ pw1_w, const float* __restrict__ pw2_w,
    const float* __restrict__ pos_emb, const float* __restrict__ dw_w,
    const float* __restrict__ bq, const float* __restrict__ bk,
    const float* __restrict__ bv,
    u16* __restrict__ pw1b, u16* __restrict__ pw2b,
    u16* __restrict__ posb, float* __restrict__ wt, float* __restrict__ bqkv)
{
    int i = blockIdx.x*256 + threadIdx.x;
    if (i < 524288) { pw1b[i] = f2b(pw1_w[i]); return; }
    i -= 524288;
    if (i < 262144) { pw2b[i] = f2b(pw2_w[i]); return; }
    i -= 262144;
    if (i < 1048576) { posb[i] = (i < 2047*512) ? f2b(pos_emb[i]) : (u16)0; return; }
    i -= 1048576;
    if (i < 15872) { int kk = i >> 9, d = i & 511; wt[i] = dw_w[d*31+kk]; return; }
    i -= 15872;
    if (i < 1536) bqkv[i] = (i < 512) ? bq[i] : (i < 1024 ? bk[i-512] : bv[i-1024]);
}

// ================= conv-module =================
// depthwise conv K=31 with fused GLU input: reads pw1 output (f32) directly
__global__ __launch_bounds__(256) void dwconv_kernel(const float* __restrict__ t2,
    const float* __restrict__ wt, const float* __restrict__ bias, float* __restrict__ z)
{
    int d  = blockIdx.x*256 + threadIdx.x;   // gridDim.x = 2
    int c  = blockIdx.y;                     // 0..511
    int b  = c >> 7;
    int t0 = (c & 127) << 3;
    const float* pa = t2 + (size_t)b*TT*1024 + d;
    float wv[31];
    #pragma unroll
    for (int kk=0;kk<31;kk++) wv[kk] = wt[kk*512 + d];
    float xv[38];
    #pragma unroll
    for (int e=0;e<38;e++){
        int tp = t0 - 15 + e;
        if (tp >= 0 && tp < TT){
            float a  = pa[(size_t)tp*1024];
            float gg = pa[(size_t)tp*1024 + 512];
            xv[e] = a * sigmoidf_(gg);
        } else xv[e] = 0.0f;
    }
    float bsv = bias[d];
    #pragma unroll
    for (int j=0;j<8;j++){
        float sum = bsv;
        #pragma unroll
        for (int kk=0;kk<31;kk++) sum = fmaf(xv[j+kk], wv[kk], sum);
        z[(size_t)(b*TT+t0+j)*DD + d] = sum;
    }
}

__global__ __launch_bounds__(256) void bn_reduce_kernel(const float* __restrict__ z, float* __restrict__ stats)
{
    int c = blockIdx.x, t = threadIdx.x;
    float s=0.f, q=0.f;
    for (int r=t; r<NTOK; r+=256){
        float vv = z[(size_t)r*DD + c];
        s += vv; q += vv*vv;
    }
    __shared__ float rs[256], rq[256];
    rs[t]=s; rq[t]=q; __syncthreads();
    for (int st=128; st>0; st>>=1){
        if (t<st){ rs[t]+=rs[t+st]; rq[t]+=rq[t+st]; }
        __syncthreads();
    }
    if (t==0){ stats[c]=rs[0]; stats[DD+c]=rq[0]; }
}

__global__ __launch_bounds__(256) void bn_apply_kernel(const float* __restrict__ z,
    const float* __restrict__ stats, const float* __restrict__ g, const float* __restrict__ b,
    u16* __restrict__ out)
{
    int idx = blockIdx.x*256 + threadIdx.x;
    int c = idx & (DD-1);
    float m   = stats[c]*(1.0f/NTOK);
    float var = stats[DD+c]*(1.0f/NTOK) - m*m;
    float vv  = (z[idx]-m)*rsqrtf(var+EPSF)*g[c] + b[c];
    out[idx]  = f2b(vv*sigmoidf_(vv));
}

extern "C" void kernel_launch(void* const* d_in, const int* in_sizes, int n_in,
                              void* d_out, int out_size, void* d_ws, size_t ws_size,
                              hipStream_t stream)
{
    const float* x       = (const float*)d_in[0];
    const float* pos_emb = (const float*)d_in[1];
    const float* ln1_g=(const float*)d_in[2],  *ln1_b=(const float*)d_in[3];
    const float* ln2_g=(const float*)d_in[4],  *ln2_b=(const float*)d_in[5];
    const float* ln3_g=(const float*)d_in[6],  *ln3_b=(const float*)d_in[7];
    const float* ln4_g=(const float*)d_in[8],  *ln4_b=(const float*)d_in[9];
    const float* ln5_g=(const float*)d_in[10], *ln5_b=(const float*)d_in[11];
    const float* ff1_w1=(const float*)d_in[12], *ff1_b1=(const float*)d_in[13];
    const float* ff1_w2=(const float*)d_in[14], *ff1_b2=(const float*)d_in[15];
    const float* wq=(const float*)d_in[16], *bq=(const float*)d_in[17];
    const float* wk=(const float*)d_in[18], *bk=(const float*)d_in[19];
    const float* wv=(const float*)d_in[20], *bv=(const float*)d_in[21];
    const float* wp=(const float*)d_in[22];
    const float* wo=(const float*)d_in[23], *bo=(const float*)d_in[24];
    const float* pos_u=(const float*)d_in[25], *pos_v=(const float*)d_in[26];
    const float* pw1_w=(const float*)d_in[27], *pw1_b=(const float*)d_in[28];
    const float* dw_w=(const float*)d_in[29],  *dw_b=(const float*)d_in[30];
    const float* bn_g=(const float*)d_in[31],  *bn_b=(const float*)d_in[32];
    const float* pw2_w=(const float*)d_in[33], *pw2_b=(const float*)d_in[34];
    const float* ff2_w1=(const float*)d_in[35], *ff2_b1=(const float*)d_in[36];
    const float* ff2_w2=(const float*)d_in[37], *ff2_b2=(const float*)d_in[38];

    char* W = (char*)d_ws;
    float* h    = (float*)(W);                  // 8 MB f32
    u16*  xn    = (u16*) (W + (size_t) 8*MB);   // 4 MB (ln out / attn out)
    u16*  wall  = (u16*) (W + (size_t)12*MB);   // 16 MB prepped weights
    u16*  qub   = (u16*) (W + (size_t)28*MB);   // qub/qvb/kb/vt contiguous (OMODE5)
    u16*  qvb   = (u16*) (W + (size_t)32*MB);
    u16*  kb    = (u16*) (W + (size_t)36*MB);
    u16*  vt    = (u16*) (W + (size_t)40*MB);   // (B,H,DK,T)
    u16*  pproj = (u16*) (W + (size_t)44*MB);   // 2048x512
    char* big   = W + (size_t)48*MB;            // shared region
    u16*  ffh   = (u16*)big;                    // 16 MB FFN hidden
    float* t2   = (float*)big;                  // 16 MB conv pw1 out
    float* t3   = (float*)(big + (size_t)16*MB);// 8 MB dwconv out
    float* opart= (float*)big;                  // 16 MB attn partials
    float* mlprt= (float*)(big + (size_t)16*MB);// 512 KB attn M/L
    float* stats= (float*)(W + (size_t)112*MB); // 4 KB
    float* wt   = stats + 4096;                 // (31,512) f32
    float* bqkv = wt + 15872;                   // 1536 f32

    u16* ff1w1T = wall;
    u16* ff1w2T = wall + 1048576;
    u16* wqT    = wall + 2097152;   // wq/wk/wv contiguous -> N=1536 merged GEMM
    u16* wkT    = wall + 2359296;
    u16* wvT    = wall + 2621440;
    u16* wpT    = wall + 2883584;
    u16* woT    = wall + 3145728;
    u16* ff2w1T = wall + 3407872;
    u16* ff2w2T = wall + 4456448;
    u16* pw1b   = wall + 5505024;
    u16* pw2b   = wall + 6029312;
    u16* posb   = wall + 6291456;

    dim3 blk(256);
    const long S0 = 0;

    // ---------------- weight prep (2 launches) ----------------
    Prep9 P;
    P.s[0]=ff1_w1; P.d[0]=ff1w1T; P.R[0]=512;  P.C[0]=2048;
    P.s[1]=ff1_w2; P.d[1]=ff1w2T; P.R[1]=2048; P.C[1]=512;
    P.s[2]=wq;     P.d[2]=wqT;    P.R[2]=512;  P.C[2]=512;
    P.s[3]=wk;     P.d[3]=wkT;    P.R[3]=512;  P.C[3]=512;
    P.s[4]=wv;     P.d[4]=wvT;    P.R[4]=512;  P.C[4]=512;
    P.s[5]=wp;     P.d[5]=wpT;    P.R[5]=512;  P.C[5]=512;
    P.s[6]=wo;     P.d[6]=woT;    P.R[6]=512;  P.C[6]=512;
    P.s[7]=ff2_w1; P.d[7]=ff2w1T; P.R[7]=512;  P.C[7]=2048;
    P.s[8]=ff2_w2; P.d[8]=ff2w2T; P.R[8]=2048; P.C[8]=512;
    int tc[9] = {1024,1024,256,256,256,256,256,1024,1024};
    P.t0[0]=0; for (int e=0;e<9;e++) P.t0[e+1]=P.t0[e]+tc[e];
    prep_transpose<<<dim3(5376), blk, 0, stream>>>(P);
    prep_convert<<<dim3(7236), blk, 0, stream>>>(pw1_w, pw2_w, pos_emb, dw_w,
                                                 bq, bk, bv,
                                                 pw1b, pw2b, posb, wt, bqkv);

    // ---------------- FFN1: h = x + 0.5*ffn(ln1(x)) ----------------
    ln_kernel<1><<<dim3(NTOK/4), blk, 0, stream>>>(x, ln1_g, ln1_b, xn);
    bgemm<1><<<dim3(32,32,1), blk, 0, stream>>>(xn,512,S0,S0, ff1w1T,512,S0,S0,
        ffh,2048,S0,S0, 4096,2048,512, ff1_b1,1,1.f, nullptr,nullptr,nullptr);
    bgemm<0><<<dim3(8,32,1), blk, 0, stream>>>(ffh,2048,S0,S0, ff1w2T,2048,S0,S0,
        h,512,S0,S0, 4096,512,2048, ff1_b2,0,0.5f, x,nullptr,nullptr);

    // ---------------- Attention: h = h + attn(ln2(h)) ----------------
    ln_kernel<1><<<dim3(NTOK/4), blk, 0, stream>>>(h, ln2_g, ln2_b, xn);
    bgemm<5><<<dim3(24,32,1), blk, 0, stream>>>(xn,512,S0,S0, wqT,512,S0,S0,
        qub,512,S0,S0, 4096,1536,512, bqkv,0,1.f, nullptr,pos_u,pos_v);
    bgemm<1><<<dim3(8,16,1), blk, 0, stream>>>(posb,512,S0,S0, wpT,512,S0,S0,
        pproj,512,S0,S0, 2048,512,512, nullptr,0,1.f, nullptr,nullptr,nullptr);

    attn_fused<<<dim3(1024), blk, 0, stream>>>(qub, qvb, kb, vt, pproj, opart, mlprt);
    attn_combine<<<dim3(8192), blk, 0, stream>>>(opart, mlprt, xn);

    bgemm<0><<<dim3(8,32,1), blk, 0, stream>>>(xn,512,S0,S0, woT,512,S0,S0,
        h,512,S0,S0, 4096,512,512, bo,0,1.f, h,nullptr,nullptr);

    // ---------------- Conv module ----------------
    ln_kernel<1><<<dim3(NTOK/4), blk, 0, stream>>>(h, ln3_g, ln3_b, xn);
    bgemm<0><<<dim3(16,32,1), blk, 0, stream>>>(xn,512,S0,S0, pw1b,512,S0,S0,
        t2,1024,S0,S0, 4096,1024,512, pw1_b,0,1.f, nullptr,nullptr,nullptr);
    dwconv_kernel<<<dim3(2,512), blk, 0, stream>>>(t2, wt, dw_b, t3);
    bn_reduce_kernel<<<dim3(DD), blk, 0, stream>>>(t3, stats);
    bn_apply_kernel<<<dim3(NTOK*DD/256), blk, 0, stream>>>(t3, stats, bn_g, bn_b, xn);
    bgemm<0><<<dim3(8,32,1), blk, 0, stream>>>(xn,512,S0,S0, pw2b,512,S0,S0,
        h,512,S0,S0, 4096,512,512, pw2_b,0,1.f, h,nullptr,nullptr);

    // ---------------- FFN2 ----------------
    ln_kernel<1><<<dim3(NTOK/4), blk, 0, stream>>>(h, ln4_g, ln4_b, xn);
    bgemm<1><<<dim3(32,32,1), blk, 0, stream>>>(xn,512,S0,S0, ff2w1T,512,S0,S0,
        ffh,2048,S0,S0, 4096,2048,512, ff2_b1,1,1.f, nullptr,nullptr,nullptr);
    bgemm<0><<<dim3(8,32,1), blk, 0, stream>>>(ffh,2048,S0,S0, ff2w2T,2048,S0,S0,
        h,512,S0,S0, 4096,512,2048, ff2_b2,0,0.5f, h,nullptr,nullptr);

    // ---------------- Final LN ----------------
    ln_kernel<0><<<dim3(NTOK/4), blk, 0, stream>>>(h, ln5_g, ln5_b, (float*)d_out);
}

// Round 6
// 335.400 us; speedup vs baseline: 1.3574x; 1.3574x over previous
//
#include <hip/hip_runtime.h>
#include <math.h>

#define TT   1024
#define BBZ  4
#define DD   512
#define DFF_ 2048
#define HH   8
#define DKK  64
#define NTOK 4096
#define EPSF 1e-5f
#define MB   1048576

typedef unsigned short u16;
typedef __attribute__((ext_vector_type(8))) short s8v;    // 8 bf16 (4 VGPRs)
typedef __attribute__((ext_vector_type(4))) float f32x4;
typedef __attribute__((ext_vector_type(4))) unsigned short us4;

__device__ __forceinline__ float b2f(u16 v){
    union { unsigned int u; float f; } x; x.u = ((unsigned int)v) << 16; return x.f;
}
__device__ __forceinline__ u16 f2b(float f){
    union { float f; unsigned int u; } x; x.f = f;
    unsigned int r = x.u + 0x7fffu + ((x.u >> 16) & 1u);
    return (u16)(r >> 16);
}
__device__ __forceinline__ float sigmoidf_(float x){ return 1.0f/(1.0f+__expf(-x)); }

__device__ __forceinline__ void gld16(const u16* g, u16* l){
    __builtin_amdgcn_global_load_lds(
        (const __attribute__((address_space(1))) unsigned int*)g,
        (__attribute__((address_space(3))) unsigned int*)l, 16, 0, 0);
}

// ================= batched MFMA GEMM =================
// C = epilogue(A @ B^T_view), A:(M,K) bf16 row-major, B:(N,K) bf16 row-major.
// OMODE 0: f32 out (+bias, act, *alpha, +resid)   1: bf16 out (+bias, act)
// OMODE 5: merged QKV epilogue. Cv=qub; qvb/kb/vt at fixed elem offsets
//          (2M, 4M, 6M). gn<512: dual q store (+posu/+posv, *0.125); <1024: k;
//          else v^T.
template<int OMODE>
__global__ __launch_bounds__(256) void bgemm(
    const u16* __restrict__ A, int lda, long sAb, long sAh,
    const u16* __restrict__ B, int ldb, long sBb, long sBh,
    void* __restrict__ Cv, int ldc, long sCb, long sCh,
    int M, int N, int K,
    const float* __restrict__ bias, int act, float alpha,
    const float* __restrict__ resid,
    const float* __restrict__ posu, const float* __restrict__ posv)
{
    int z  = blockIdx.z;
    int zb = z >> 3, zh = z & 7;
    int n0 = blockIdx.x * 64;
    int m0 = blockIdx.y * 128;
    const u16* Ab = A + (size_t)zb*sAb + (size_t)zh*sAh;
    const u16* Bb = B + (size_t)zb*sBb + (size_t)zh*sBh;

    __shared__ u16 As[128*64];
    __shared__ u16 Bs[64*64];

    int t = threadIdx.x;
    int w = t >> 6, l = t & 63;
    int lrow = l >> 3, lslot = l & 7;
    int kswz = (lslot ^ lrow) * 8;
    int wm = w >> 1, wn = w & 1;
    int lr = l & 15, lk = l >> 4;

    f32x4 acc[4][2] = {};

    for (int k0 = 0; k0 < K; k0 += 64){
        #pragma unroll
        for (int it = 0; it < 4; ++it){
            int rb = it*32 + w*8;
            gld16(Ab + (size_t)(m0 + rb + lrow)*lda + k0 + kswz, &As[rb*64]);
        }
        #pragma unroll
        for (int it = 0; it < 2; ++it){
            int rb = it*32 + w*8;
            gld16(Bb + (size_t)(n0 + rb + lrow)*ldb + k0 + kswz, &Bs[rb*64]);
        }
        __syncthreads();

        s8v af[2][4], bf[2][2];
        #pragma unroll
        for (int kh = 0; kh < 2; ++kh){
            #pragma unroll
            for (int mi = 0; mi < 4; ++mi){
                int row = wm*64 + mi*16 + lr;
                int sl  = (kh*4 + lk) ^ (lr & 7);
                af[kh][mi] = *(const s8v*)&As[row*64 + sl*8];
            }
            #pragma unroll
            for (int ni = 0; ni < 2; ++ni){
                int row = wn*32 + ni*16 + lr;
                int sl  = (kh*4 + lk) ^ (lr & 7);
                bf[kh][ni] = *(const s8v*)&Bs[row*64 + sl*8];
            }
        }
        #pragma unroll
        for (int kh = 0; kh < 2; ++kh)
            #pragma unroll
            for (int mi = 0; mi < 4; ++mi)
                #pragma unroll
                for (int ni = 0; ni < 2; ++ni)
                    acc[mi][ni] = __builtin_amdgcn_mfma_f32_16x16x32_bf16(
                        af[kh][mi], bf[kh][ni], acc[mi][ni], 0, 0, 0);
        __syncthreads();
    }

    #pragma unroll
    for (int mi = 0; mi < 4; ++mi){
        #pragma unroll
        for (int ni = 0; ni < 2; ++ni){
            int gn = n0 + wn*32 + ni*16 + lr;
            float bval = bias ? bias[gn] : 0.0f;
            #pragma unroll
            for (int r = 0; r < 4; ++r){
                int gm = m0 + wm*64 + mi*16 + lk*4 + r;
                float vv = acc[mi][ni][r] + bval;
                if (act) vv = vv * sigmoidf_(vv);
                if (OMODE == 0){
                    vv *= alpha;
                    if (resid) vv += resid[(size_t)gm*ldc + gn];
                    ((float*)Cv)[(size_t)zb*sCb + (size_t)zh*sCh + (size_t)gm*ldc + gn] = vv;
                } else if (OMODE == 1){
                    ((u16*)Cv)[(size_t)zb*sCb + (size_t)zh*sCh + (size_t)gm*ldc + gn] = f2b(vv);
                } else { // 5: merged QKV
                    u16* base = (u16*)Cv;
                    if (gn < 512){
                        size_t idx = (size_t)gm*512 + gn;
                        base[idx]              = f2b((vv + posu[gn])*0.125f);
                        base[idx + (2u<<20)]   = f2b((vv + posv[gn])*0.125f);
                    } else if (gn < 1024){
                        base[(4u<<20) + (size_t)gm*512 + (gn-512)] = f2b(vv);
                    } else {
                        int gnp = gn - 1024;
                        int bb = gm >> 10, tt2 = gm & 1023;
                        size_t idx = (((size_t)(bb*8 + (gnp>>6)))*64 + (gnp&63))*1024 + tt2;
                        base[(6u<<20) + idx] = f2b(vv);
                    }
                }
            }
        }
    }
}

// ================= fused rel-pos flash attention =================
// grid (16, 32): i0 = blockIdx.x*64, z = blockIdx.y (b*8+h).
// Lockstep j-loop (all blocks read the same K/V tile index concurrently ->
// L2-resident live set). K/P double-buffered: next tile issued before compute.
// q pre-scaled by 0.125.  Scores = qu.K^T + band(qv.P^T); online softmax; PV.
__global__ __launch_bounds__(256) void attn_fused(
    const u16* __restrict__ qub, const u16* __restrict__ qvb,
    const u16* __restrict__ kb,  const u16* __restrict__ vt,
    const u16* __restrict__ pp,  u16* __restrict__ out)
{
    int z = blockIdx.y;
    int b = z >> 3, hh = z & 7;
    int i0 = blockIdx.x * 64;

    __shared__ u16 Kb2[2][64*64];     // 16 KB
    __shared__ u16 Pb[2][128*64];     // 32 KB (Pb[0] holds qu/qv during prologue)
    __shared__ u16 Vb[64*64];         //  8 KB
    __shared__ u16 PT[64*64];         //  8 KB (P-tilde, wave-local rows)
    __shared__ float Band[64*64];     // 16 KB (rotate-swizzled, wave-local rows)

    int t = threadIdx.x;
    int w = t >> 6, l = t & 63;
    int lrow = l >> 3, lslot = l & 7;
    int kswz = (lslot ^ lrow) * 8;
    int lr = l & 15, lk = l >> 4;

    // ---- prologue: qu/qv -> Pb[0], K_0 -> Kb2[0], P_0 -> Pb[1] ----
    #pragma unroll
    for (int it = 0; it < 2; ++it){
        int rb = it*32 + w*8;
        gld16(qub + (size_t)(b*TT + i0 + rb + lrow)*DD + hh*64 + kswz, &Pb[0][rb*64]);
        gld16(qvb + (size_t)(b*TT + i0 + rb + lrow)*DD + hh*64 + kswz, &Pb[0][(64+rb)*64]);
        gld16(kb  + (size_t)(b*TT +      rb + lrow)*DD + hh*64 + kswz, &Kb2[0][rb*64]);
    }
    {
        int r0 = 960 - i0;
        #pragma unroll
        for (int it = 0; it < 4; ++it){
            int rb = it*32 + w*8;
            gld16(pp + (size_t)(r0 + rb + lrow)*DD + hh*64 + kswz, &Pb[1][rb*64]);
        }
    }
    __syncthreads();
    s8v af_u[2], af_v[2];
    #pragma unroll
    for (int kh = 0; kh < 2; ++kh){
        int sl = (kh*4 + lk) ^ (lr & 7);
        af_u[kh] = *(const s8v*)&Pb[0][(w*16 + lr)*64 + sl*8];
        af_v[kh] = *(const s8v*)&Pb[0][(64 + w*16 + lr)*64 + sl*8];
    }

    f32x4 o_[4] = {};
    float M_[4], L_[4];
    #pragma unroll
    for (int r = 0; r < 4; ++r){ M_[r] = -3e38f; L_[r] = 0.0f; }

    int nbase = 3 - w;   // band-intersecting P sub-tiles for this wave: nn in [3-w, 7-w]

    for (int jt = 0; jt < 16; ++jt){
        int cur = jt & 1;
        __syncthreads();  // prev PV done (Vb/PT free); Q-frag reads done (jt=0)

        // issue async staging: V_jt -> Vb; K_{jt+1} -> Kb2[cur^1]; P_{jt+1} -> Pb[cur]
        #pragma unroll
        for (int it = 0; it < 2; ++it){
            int rb = it*32 + w*8;
            gld16(vt + ((size_t)z*64 + rb + lrow)*TT + jt*64 + kswz, &Vb[rb*64]);
            if (jt < 15)
                gld16(kb + (size_t)(b*TT + (jt+1)*64 + rb + lrow)*DD + hh*64 + kswz,
                      &Kb2[cur^1][rb*64]);
        }
        if (jt < 15){
            int r0n = 960 + (jt+1)*64 - i0;
            #pragma unroll
            for (int it = 0; it < 4; ++it){
                int rb = it*32 + w*8;
                gld16(pp + (size_t)(r0n + rb + lrow)*DD + hh*64 + kswz, &Pb[cur][rb*64]);
            }
        }

        // ---- S_ac (16x64) and band G (16x80) per wave, from current buffers ----
        f32x4 sac[4] = {};
        f32x4 g[5] = {};
        #pragma unroll
        for (int kh = 0; kh < 2; ++kh){
            int sl = (kh*4 + lk) ^ (lr & 7);
            #pragma unroll
            for (int n = 0; n < 4; ++n){
                s8v bK = *(const s8v*)&Kb2[cur][(n*16 + lr)*64 + sl*8];
                sac[n] = __builtin_amdgcn_mfma_f32_16x16x32_bf16(af_u[kh], bK, sac[n], 0,0,0);
            }
            #pragma unroll
            for (int n = 0; n < 5; ++n){
                int nn = nbase + n;
                s8v bP = *(const s8v*)&Pb[cur^1][(nn*16 + lr)*64 + sl*8];
                g[n] = __builtin_amdgcn_mfma_f32_16x16x32_bf16(af_v[kh], bP, g[n], 0,0,0);
            }
        }
        // band write (f32, rotate swizzle, wave-local rows -> no barrier)
        #pragma unroll
        for (int n = 0; n < 5; ++n){
            int nn = nbase + n;
            #pragma unroll
            for (int r = 0; r < 4; ++r){
                int ii = w*16 + lk*4 + r;
                int jj = nn*16 + lr - 63 + ii;
                if (jj >= 0 && jj < 64)
                    Band[ii*64 + ((jj + 4*ii) & 63)] = g[n][r];
            }
        }

        // ---- combine band + online softmax (wave-local) ----
        float p_[4][4], sc_[4];
        #pragma unroll
        for (int r = 0; r < 4; ++r){
            int ii = w*16 + lk*4 + r;
            float sv[4]; float mx = -3e38f;
            #pragma unroll
            for (int n = 0; n < 4; ++n){
                int jj = n*16 + lr;
                float vvv = sac[n][r] + Band[ii*64 + ((jj + 4*ii) & 63)];
                sv[n] = vvv; mx = fmaxf(mx, vvv);
            }
            #pragma unroll
            for (int msk = 1; msk < 16; msk <<= 1) mx = fmaxf(mx, __shfl_xor(mx, msk));
            float nm = fmaxf(M_[r], mx);
            float scale = __expf(M_[r] - nm);
            float rs = 0.0f;
            #pragma unroll
            for (int n = 0; n < 4; ++n){ p_[n][r] = __expf(sv[n] - nm); rs += p_[n][r]; }
            #pragma unroll
            for (int msk = 1; msk < 16; msk <<= 1) rs += __shfl_xor(rs, msk);
            L_[r] = L_[r]*scale + rs;
            M_[r] = nm;
            sc_[r] = scale;
        }
        #pragma unroll
        for (int n = 0; n < 4; ++n)
            #pragma unroll
            for (int r = 0; r < 4; ++r)
                o_[n][r] *= sc_[r];

        // write P-tilde (swizzled bf16, wave-local rows)
        #pragma unroll
        for (int n = 0; n < 4; ++n)
            #pragma unroll
            for (int r = 0; r < 4; ++r){
                int ii  = w*16 + lk*4 + r;
                int col = n*16 + lr;
                int sl  = (col>>3) ^ (ii&7);
                PT[ii*64 + sl*8 + (col&7)] = f2b(p_[n][r]);
            }

        __syncthreads();  // drains V (+ next K/P) staging; PT wave-local anyway

        // ---- PV ----
        #pragma unroll
        for (int kh = 0; kh < 2; ++kh){
            int sl = (kh*4 + lk) ^ (lr & 7);
            s8v ap = *(const s8v*)&PT[(w*16 + lr)*64 + sl*8];
            #pragma unroll
            for (int n = 0; n < 4; ++n){
                s8v bV = *(const s8v*)&Vb[(n*16 + lr)*64 + sl*8];
                o_[n] = __builtin_amdgcn_mfma_f32_16x16x32_bf16(ap, bV, o_[n], 0,0,0);
            }
        }
    }

    #pragma unroll
    for (int n = 0; n < 4; ++n)
        #pragma unroll
        for (int r = 0; r < 4; ++r){
            int i  = i0 + w*16 + lk*4 + r;
            int dk = n*16 + lr;
            out[(size_t)(b*TT + i)*DD + hh*64 + dk] = f2b(o_[n][r] / L_[r]);
        }
}

// ================= LayerNorm: wave per row, shuffle reduce, no barriers =====
template<int OB>
__global__ __launch_bounds__(256) void ln_kernel(const float* __restrict__ in,
    const float* __restrict__ g, const float* __restrict__ b, void* __restrict__ outv)
{
    int w = threadIdx.x >> 6, l = threadIdx.x & 63;
    int row = blockIdx.x*4 + w;
    const float4* xr = (const float4*)(in + (size_t)row*DD);
    float4 v0 = xr[l], v1 = xr[64 + l];
    float s = v0.x+v0.y+v0.z+v0.w + v1.x+v1.y+v1.z+v1.w;
    float q = v0.x*v0.x+v0.y*v0.y+v0.z*v0.z+v0.w*v0.w
            + v1.x*v1.x+v1.y*v1.y+v1.z*v1.z+v1.w*v1.w;
    #pragma unroll
    for (int msk = 1; msk < 64; msk <<= 1){
        s += __shfl_xor(s, msk);
        q += __shfl_xor(q, msk);
    }
    float mean = s*(1.0f/DD);
    float var  = q*(1.0f/DD) - mean*mean;
    float inv  = rsqrtf(var+EPSF);
    float4 g0 = ((const float4*)g)[l], g1 = ((const float4*)g)[64+l];
    float4 b0 = ((const float4*)b)[l], b1 = ((const float4*)b)[64+l];
    float y0x=(v0.x-mean)*inv*g0.x+b0.x, y0y=(v0.y-mean)*inv*g0.y+b0.y;
    float y0z=(v0.z-mean)*inv*g0.z+b0.z, y0w=(v0.w-mean)*inv*g0.w+b0.w;
    float y1x=(v1.x-mean)*inv*g1.x+b1.x, y1y=(v1.y-mean)*inv*g1.y+b1.y;
    float y1z=(v1.z-mean)*inv*g1.z+b1.z, y1w=(v1.w-mean)*inv*g1.w+b1.w;
    if (OB){
        us4 o0 = { f2b(y0x), f2b(y0y), f2b(y0z), f2b(y0w) };
        us4 o1 = { f2b(y1x), f2b(y1y), f2b(y1z), f2b(y1w) };
        us4* op = (us4*)((u16*)outv + (size_t)row*DD);
        op[l] = o0; op[64+l] = o1;
    } else {
        float4 o0 = { y0x, y0y, y0z, y0w };
        float4 o1 = { y1x, y1y, y1z, y1w };
        float4* op = (float4*)((float*)outv + (size_t)row*DD);
        op[l] = o0; op[64+l] = o1;
    }
}

// ================= consolidated weight prep =================
struct Prep9 {
    const float* s[9];
    u16* d[9];
    int R[9], C[9];
    int t0[10];
};

__global__ __launch_bounds__(256) void prep_transpose(Prep9 P)
{
    __shared__ float tile[32][33];
    int bid = blockIdx.x;
    int j = 0;
    #pragma unroll
    for (int e=1; e<9; e++) if (bid >= P.t0[e]) j = e;
    int lb = bid - P.t0[j];
    int nx = P.C[j] >> 5;
    int c0 = (lb % nx) << 5;
    int r0 = (lb / nx) << 5;
    const float* in = P.s[j];
    u16* out = P.d[j];
    int R = P.R[j], C = P.C[j];
    int tx = threadIdx.x & 31, ty = threadIdx.x >> 5;
    #pragma unroll
    for (int i=0;i<4;i++){
        int rr = ty + i*8;
        tile[rr][tx] = in[(size_t)(r0+rr)*C + c0+tx];
    }
    __syncthreads();
    #pragma unroll
    for (int i=0;i<4;i++){
        int cc = ty + i*8;
        out[(size_t)(c0+cc)*R + r0+tx] = f2b(tile[tx][cc]);
    }
}

__global__ __launch_bounds__(256) void prep_convert(
    const float* __restrict__ pw1_w, const float* __restrict__ pw2_w,
    const float* __restrict__ pos_emb, const float* __restrict__ dw_w,
    const float* __restrict__ bq, const float* __restrict__ bk,
    const float* __restrict__ bv,
    u16* __restrict__ pw1b, u16* __restrict__ pw2b,
    u16* __restrict__ posb, float* __restrict__ wt, float* __restrict__ bqkv)
{
    int i = blockIdx.x*256 + threadIdx.x;
    if (i < 524288) { pw1b[i] = f2b(pw1_w[i]); return; }
    i -= 524288;
    if (i < 262144) { pw2b[i] = f2b(pw2_w[i]); return; }
    i -= 262144;
    if (i < 1048576) { posb[i] = (i < 2047*512) ? f2b(pos_emb[i]) : (u16)0; return; }
    i -= 1048576;
    if (i < 15872) { int kk = i >> 9, d = i & 511; wt[i] = dw_w[d*31+kk]; return; }
    i -= 15872;
    if (i < 1536) bqkv[i] = (i < 512) ? bq[i] : (i < 1024 ? bk[i-512] : bv[i-1024]);
}

// ================= conv-module =================
// depthwise conv K=31 with fused GLU input: reads pw1 output (f32) directly
__global__ __launch_bounds__(256) void dwconv_kernel(const float* __restrict__ t2,
    const float* __restrict__ wt, const float* __restrict__ bias, float* __restrict__ z)
{
    int d  = blockIdx.x*256 + threadIdx.x;   // gridDim.x = 2
    int c  = blockIdx.y;                     // 0..511
    int b  = c >> 7;
    int t0 = (c & 127) << 3;
    const float* pa = t2 + (size_t)b*TT*1024 + d;
    float wv[31];
    #pragma unroll
    for (int kk=0;kk<31;kk++) wv[kk] = wt[kk*512 + d];
    float xv[38];
    #pragma unroll
    for (int e=0;e<38;e++){
        int tp = t0 - 15 + e;
        if (tp >= 0 && tp < TT){
            float a  = pa[(size_t)tp*1024];
            float gg = pa[(size_t)tp*1024 + 512];
            xv[e] = a * sigmoidf_(gg);
        } else xv[e] = 0.0f;
    }
    float bsv = bias[d];
    #pragma unroll
    for (int j=0;j<8;j++){
        float sum = bsv;
        #pragma unroll
        for (int kk=0;kk<31;kk++) sum = fmaf(xv[j+kk], wv[kk], sum);
        z[(size_t)(b*TT+t0+j)*DD + d] = sum;
    }
}

__global__ __launch_bounds__(256) void bn_reduce_kernel(const float* __restrict__ z, float* __restrict__ stats)
{
    int c = blockIdx.x, t = threadIdx.x;
    float s=0.f, q=0.f;
    for (int r=t; r<NTOK; r+=256){
        float vv = z[(size_t)r*DD + c];
        s += vv; q += vv*vv;
    }
    __shared__ float rs[256], rq[256];
    rs[t]=s; rq[t]=q; __syncthreads();
    for (int st=128; st>0; st>>=1){
        if (t<st){ rs[t]+=rs[t+st]; rq[t]+=rq[t+st]; }
        __syncthreads();
    }
    if (t==0){ stats[c]=rs[0]; stats[DD+c]=rq[0]; }
}

__global__ __launch_bounds__(256) void bn_apply_kernel(const float* __restrict__ z,
    const float* __restrict__ stats, const float* __restrict__ g, const float* __restrict__ b,
    u16* __restrict__ out)
{
    int idx = blockIdx.x*256 + threadIdx.x;
    int c = idx & (DD-1);
    float m   = stats[c]*(1.0f/NTOK);
    float var = stats[DD+c]*(1.0f/NTOK) - m*m;
    float vv  = (z[idx]-m)*rsqrtf(var+EPSF)*g[c] + b[c];
    out[idx]  = f2b(vv*sigmoidf_(vv));
}

extern "C" void kernel_launch(void* const* d_in, const int* in_sizes, int n_in,
                              void* d_out, int out_size, void* d_ws, size_t ws_size,
                              hipStream_t stream)
{
    const float* x       = (const float*)d_in[0];
    const float* pos_emb = (const float*)d_in[1];
    const float* ln1_g=(const float*)d_in[2],  *ln1_b=(const float*)d_in[3];
    const float* ln2_g=(const float*)d_in[4],  *ln2_b=(const float*)d_in[5];
    const float* ln3_g=(const float*)d_in[6],  *ln3_b=(const float*)d_in[7];
    const float* ln4_g=(const float*)d_in[8],  *ln4_b=(const float*)d_in[9];
    const float* ln5_g=(const float*)d_in[10], *ln5_b=(const float*)d_in[11];
    const float* ff1_w1=(const float*)d_in[12], *ff1_b1=(const float*)d_in[13];
    const float* ff1_w2=(const float*)d_in[14], *ff1_b2=(const float*)d_in[15];
    const float* wq=(const float*)d_in[16], *bq=(const float*)d_in[17];
    const float* wk=(const float*)d_in[18], *bk=(const float*)d_in[19];
    const float* wv=(const float*)d_in[20], *bv=(const float*)d_in[21];
    const float* wp=(const float*)d_in[22];
    const float* wo=(const float*)d_in[23], *bo=(const float*)d_in[24];
    const float* pos_u=(const float*)d_in[25], *pos_v=(const float*)d_in[26];
    const float* pw1_w=(const float*)d_in[27], *pw1_b=(const float*)d_in[28];
    const float* dw_w=(const float*)d_in[29],  *dw_b=(const float*)d_in[30];
    const float* bn_g=(const float*)d_in[31],  *bn_b=(const float*)d_in[32];
    const float* pw2_w=(const float*)d_in[33], *pw2_b=(const float*)d_in[34];
    const float* ff2_w1=(const float*)d_in[35], *ff2_b1=(const float*)d_in[36];
    const float* ff2_w2=(const float*)d_in[37], *ff2_b2=(const float*)d_in[38];

    char* W = (char*)d_ws;
    float* h    = (float*)(W);                  // 8 MB f32
    u16*  xn    = (u16*) (W + (size_t) 8*MB);   // 4 MB (ln out / attn out)
    u16*  wall  = (u16*) (W + (size_t)12*MB);   // 16 MB prepped weights
    u16*  qub   = (u16*) (W + (size_t)28*MB);   // qub/qvb/kb/vt contiguous (OMODE5)
    u16*  qvb   = (u16*) (W + (size_t)32*MB);
    u16*  kb    = (u16*) (W + (size_t)36*MB);
    u16*  vt    = (u16*) (W + (size_t)40*MB);   // (B,H,DK,T)
    u16*  pproj = (u16*) (W + (size_t)44*MB);   // 2048x512
    char* big   = W + (size_t)48*MB;            // shared region
    u16*  ffh   = (u16*)big;                    // 16 MB FFN hidden
    float* t2   = (float*)big;                  // 16 MB conv pw1 out
    float* t3   = (float*)(big + (size_t)16*MB);// 8 MB dwconv out
    float* stats= (float*)(W + (size_t)112*MB); // 4 KB
    float* wt   = stats + 4096;                 // (31,512) f32
    float* bqkv = wt + 15872;                   // 1536 f32

    u16* ff1w1T = wall;
    u16* ff1w2T = wall + 1048576;
    u16* wqT    = wall + 2097152;   // wq/wk/wv contiguous -> N=1536 merged GEMM
    u16* wkT    = wall + 2359296;
    u16* wvT    = wall + 2621440;
    u16* wpT    = wall + 2883584;
    u16* woT    = wall + 3145728;
    u16* ff2w1T = wall + 3407872;
    u16* ff2w2T = wall + 4456448;
    u16* pw1b   = wall + 5505024;
    u16* pw2b   = wall + 6029312;
    u16* posb   = wall + 6291456;

    dim3 blk(256);
    const long S0 = 0;

    // ---------------- weight prep (2 launches) ----------------
    Prep9 P;
    P.s[0]=ff1_w1; P.d[0]=ff1w1T; P.R[0]=512;  P.C[0]=2048;
    P.s[1]=ff1_w2; P.d[1]=ff1w2T; P.R[1]=2048; P.C[1]=512;
    P.s[2]=wq;     P.d[2]=wqT;    P.R[2]=512;  P.C[2]=512;
    P.s[3]=wk;     P.d[3]=wkT;    P.R[3]=512;  P.C[3]=512;
    P.s[4]=wv;     P.d[4]=wvT;    P.R[4]=512;  P.C[4]=512;
    P.s[5]=wp;     P.d[5]=wpT;    P.R[5]=512;  P.C[5]=512;
    P.s[6]=wo;     P.d[6]=woT;    P.R[6]=512;  P.C[6]=512;
    P.s[7]=ff2_w1; P.d[7]=ff2w1T; P.R[7]=512;  P.C[7]=2048;
    P.s[8]=ff2_w2; P.d[8]=ff2w2T; P.R[8]=2048; P.C[8]=512;
    int tc[9] = {1024,1024,256,256,256,256,256,1024,1024};
    P.t0[0]=0; for (int e=0;e<9;e++) P.t0[e+1]=P.t0[e]+tc[e];
    prep_transpose<<<dim3(5376), blk, 0, stream>>>(P);
    prep_convert<<<dim3(7236), blk, 0, stream>>>(pw1_w, pw2_w, pos_emb, dw_w,
                                                 bq, bk, bv,
                                                 pw1b, pw2b, posb, wt, bqkv);

    // ---------------- FFN1: h = x + 0.5*ffn(ln1(x)) ----------------
    ln_kernel<1><<<dim3(NTOK/4), blk, 0, stream>>>(x, ln1_g, ln1_b, xn);
    bgemm<1><<<dim3(32,32,1), blk, 0, stream>>>(xn,512,S0,S0, ff1w1T,512,S0,S0,
        ffh,2048,S0,S0, 4096,2048,512, ff1_b1,1,1.f, nullptr,nullptr,nullptr);
    bgemm<0><<<dim3(8,32,1), blk, 0, stream>>>(ffh,2048,S0,S0, ff1w2T,2048,S0,S0,
        h,512,S0,S0, 4096,512,2048, ff1_b2,0,0.5f, x,nullptr,nullptr);

    // ---------------- Attention: h = h + attn(ln2(h)) ----------------
    ln_kernel<1><<<dim3(NTOK/4), blk, 0, stream>>>(h, ln2_g, ln2_b, xn);
    bgemm<5><<<dim3(24,32,1), blk, 0, stream>>>(xn,512,S0,S0, wqT,512,S0,S0,
        qub,512,S0,S0, 4096,1536,512, bqkv,0,1.f, nullptr,pos_u,pos_v);
    bgemm<1><<<dim3(8,16,1), blk, 0, stream>>>(posb,512,S0,S0, wpT,512,S0,S0,
        pproj,512,S0,S0, 2048,512,512, nullptr,0,1.f, nullptr,nullptr,nullptr);

    attn_fused<<<dim3(16,32), blk, 0, stream>>>(qub, qvb, kb, vt, pproj, xn);

    bgemm<0><<<dim3(8,32,1), blk, 0, stream>>>(xn,512,S0,S0, woT,512,S0,S0,
        h,512,S0,S0, 4096,512,512, bo,0,1.f, h,nullptr,nullptr);

    // ---------------- Conv module ----------------
    ln_kernel<1><<<dim3(NTOK/4), blk, 0, stream>>>(h, ln3_g, ln3_b, xn);
    bgemm<0><<<dim3(16,32,1), blk, 0, stream>>>(xn,512,S0,S0, pw1b,512,S0,S0,
        t2,1024,S0,S0, 4096,1024,512, pw1_b,0,1.f, nullptr,nullptr,nullptr);
    dwconv_kernel<<<dim3(2,512), blk, 0, stream>>>(t2, wt, dw_b, t3);
    bn_reduce_kernel<<<dim3(DD), blk, 0, stream>>>(t3, stats);
    bn_apply_kernel<<<dim3(NTOK*DD/256), blk, 0, stream>>>(t3, stats, bn_g, bn_b, xn);
    bgemm<0><<<dim3(8,32,1), blk, 0, stream>>>(xn,512,S0,S0, pw2b,512,S0,S0,
        h,512,S0,S0, 4096,512,512, pw2_b,0,1.f, h,nullptr,nullptr);

    // ---------------- FFN2 ----------------
    ln_kernel<1><<<dim3(NTOK/4), blk, 0, stream>>>(h, ln4_g, ln4_b, xn);
    bgemm<1><<<dim3(32,32,1), blk, 0, stream>>>(xn,512,S0,S0, ff2w1T,512,S0,S0,
        ffh,2048,S0,S0, 4096,2048,512, ff2_b1,1,1.f, nullptr,nullptr,nullptr);
    bgemm<0><<<dim3(8,32,1), blk, 0, stream>>>(ffh,2048,S0,S0, ff2w2T,2048,S0,S0,
        h,512,S0,S0, 4096,512,2048, ff2_b2,0,0.5f, h,nullptr,nullptr);

    // ---------------- Final LN ----------------
    ln_kernel<0><<<dim3(NTOK/4), blk, 0, stream>>>(h, ln5_g, ln5_b, (float*)d_out);
}

// Round 7
// 304.791 us; speedup vs baseline: 1.4937x; 1.1004x over previous
//
#include <hip/hip_runtime.h>
#include <math.h>

#define TT   1024
#define BBZ  4
#define DD   512
#define DFF_ 2048
#define HH   8
#define DKK  64
#define NTOK 4096
#define EPSF 1e-5f
#define MB   1048576

typedef unsigned short u16;
typedef __attribute__((ext_vector_type(8))) short s8v;    // 8 bf16 (4 VGPRs)
typedef __attribute__((ext_vector_type(4))) float f32x4;
typedef __attribute__((ext_vector_type(4))) unsigned short us4;

__device__ __forceinline__ float b2f(u16 v){
    union { unsigned int u; float f; } x; x.u = ((unsigned int)v) << 16; return x.f;
}
__device__ __forceinline__ u16 f2b(float f){
    union { float f; unsigned int u; } x; x.f = f;
    unsigned int r = x.u + 0x7fffu + ((x.u >> 16) & 1u);
    return (u16)(r >> 16);
}
__device__ __forceinline__ float sigmoidf_(float x){ return 1.0f/(1.0f+__expf(-x)); }

__device__ __forceinline__ void gld16(const u16* g, u16* l){
    __builtin_amdgcn_global_load_lds(
        (const __attribute__((address_space(1))) unsigned int*)g,
        (__attribute__((address_space(3))) unsigned int*)l, 16, 0, 0);
}

// ================= 128x128-tile MFMA GEMM (wide N) =================
// C = epilogue(A @ B^T_view), A:(M,K) bf16 row-major, B:(N,K) bf16 row-major.
// OMODE 0: f32 out (+bias, act, *alpha, +resid)   1: bf16 out (+bias, act)
// OMODE 5: merged QKV epilogue. Cv=qub; qvb/kb/vt at elem offsets 2M/4M/6M.
template<int OMODE>
__global__ __launch_bounds__(256) void bgemm128(
    const u16* __restrict__ A, int lda,
    const u16* __restrict__ B, int ldb,
    void* __restrict__ Cv, int ldc, int K,
    const float* __restrict__ bias, int act, float alpha,
    const float* __restrict__ resid,
    const float* __restrict__ posu, const float* __restrict__ posv)
{
    int n0 = blockIdx.x * 128;
    int m0 = blockIdx.y * 128;

    __shared__ u16 As[128*64];
    __shared__ u16 Bs[128*64];

    int t = threadIdx.x;
    int w = t >> 6, l = t & 63;
    int lrow = l >> 3, lslot = l & 7;
    int kswz = (lslot ^ lrow) * 8;
    int wm = w >> 1, wn = w & 1;
    int lr = l & 15, lk = l >> 4;

    f32x4 acc[4][4] = {};

    for (int k0 = 0; k0 < K; k0 += 64){
        #pragma unroll
        for (int it = 0; it < 4; ++it){
            int rb = it*32 + w*8;
            gld16(A + (size_t)(m0 + rb + lrow)*lda + k0 + kswz, &As[rb*64]);
            gld16(B + (size_t)(n0 + rb + lrow)*ldb + k0 + kswz, &Bs[rb*64]);
        }
        __syncthreads();

        s8v af[2][4], bf[2][4];
        #pragma unroll
        for (int kh = 0; kh < 2; ++kh){
            int sl = (kh*4 + lk) ^ (lr & 7);
            #pragma unroll
            for (int mi = 0; mi < 4; ++mi)
                af[kh][mi] = *(const s8v*)&As[(wm*64 + mi*16 + lr)*64 + sl*8];
            #pragma unroll
            for (int ni = 0; ni < 4; ++ni)
                bf[kh][ni] = *(const s8v*)&Bs[(wn*64 + ni*16 + lr)*64 + sl*8];
        }
        #pragma unroll
        for (int kh = 0; kh < 2; ++kh)
            #pragma unroll
            for (int mi = 0; mi < 4; ++mi)
                #pragma unroll
                for (int ni = 0; ni < 4; ++ni)
                    acc[mi][ni] = __builtin_amdgcn_mfma_f32_16x16x32_bf16(
                        af[kh][mi], bf[kh][ni], acc[mi][ni], 0, 0, 0);
        __syncthreads();
    }

    #pragma unroll
    for (int mi = 0; mi < 4; ++mi){
        #pragma unroll
        for (int ni = 0; ni < 4; ++ni){
            int gn = n0 + wn*64 + ni*16 + lr;
            float bval = bias ? bias[gn] : 0.0f;
            #pragma unroll
            for (int r = 0; r < 4; ++r){
                int gm = m0 + wm*64 + mi*16 + lk*4 + r;
                float vv = acc[mi][ni][r] + bval;
                if (act) vv = vv * sigmoidf_(vv);
                if (OMODE == 0){
                    vv *= alpha;
                    if (resid) vv += resid[(size_t)gm*ldc + gn];
                    ((float*)Cv)[(size_t)gm*ldc + gn] = vv;
                } else if (OMODE == 1){
                    ((u16*)Cv)[(size_t)gm*ldc + gn] = f2b(vv);
                } else { // 5: merged QKV
                    u16* base = (u16*)Cv;
                    if (gn < 512){
                        size_t idx = (size_t)gm*512 + gn;
                        base[idx]              = f2b((vv + posu[gn])*0.125f);
                        base[idx + (2u<<20)]   = f2b((vv + posv[gn])*0.125f);
                    } else if (gn < 1024){
                        base[(4u<<20) + (size_t)gm*512 + (gn-512)] = f2b(vv);
                    } else {
                        int gnp = gn - 1024;
                        int bb = gm >> 10, tt2 = gm & 1023;
                        size_t idx = (((size_t)(bb*8 + (gnp>>6)))*64 + (gnp&63))*1024 + tt2;
                        base[(6u<<20) + idx] = f2b(vv);
                    }
                }
            }
        }
    }
}

// ================= 64x64-tile MFMA GEMM (N=512 shapes; 2 blocks/CU) =========
// OMODE 0: f32 out (+bias, *alpha, +resid)   1: bf16 out (+bias)
template<int OMODE>
__global__ __launch_bounds__(256) void bgemm64(
    const u16* __restrict__ A, int lda,
    const u16* __restrict__ B, int ldb,
    void* __restrict__ Cv, int ldc, int K,
    const float* __restrict__ bias, float alpha,
    const float* __restrict__ resid)
{
    int n0 = blockIdx.x * 64;
    int m0 = blockIdx.y * 64;

    __shared__ u16 As[64*64];
    __shared__ u16 Bs[64*64];

    int t = threadIdx.x;
    int w = t >> 6, l = t & 63;
    int lrow = l >> 3, lslot = l & 7;
    int kswz = (lslot ^ lrow) * 8;
    int wm = w >> 1, wn = w & 1;
    int lr = l & 15, lk = l >> 4;

    f32x4 acc[2][2] = {};

    for (int k0 = 0; k0 < K; k0 += 64){
        #pragma unroll
        for (int it = 0; it < 2; ++it){
            int rb = it*32 + w*8;
            gld16(A + (size_t)(m0 + rb + lrow)*lda + k0 + kswz, &As[rb*64]);
            gld16(B + (size_t)(n0 + rb + lrow)*ldb + k0 + kswz, &Bs[rb*64]);
        }
        __syncthreads();

        s8v af[2][2], bf[2][2];
        #pragma unroll
        for (int kh = 0; kh < 2; ++kh){
            int sl = (kh*4 + lk) ^ (lr & 7);
            #pragma unroll
            for (int mi = 0; mi < 2; ++mi)
                af[kh][mi] = *(const s8v*)&As[(wm*32 + mi*16 + lr)*64 + sl*8];
            #pragma unroll
            for (int ni = 0; ni < 2; ++ni)
                bf[kh][ni] = *(const s8v*)&Bs[(wn*32 + ni*16 + lr)*64 + sl*8];
        }
        #pragma unroll
        for (int kh = 0; kh < 2; ++kh)
            #pragma unroll
            for (int mi = 0; mi < 2; ++mi)
                #pragma unroll
                for (int ni = 0; ni < 2; ++ni)
                    acc[mi][ni] = __builtin_amdgcn_mfma_f32_16x16x32_bf16(
                        af[kh][mi], bf[kh][ni], acc[mi][ni], 0, 0, 0);
        __syncthreads();
    }

    #pragma unroll
    for (int mi = 0; mi < 2; ++mi){
        #pragma unroll
        for (int ni = 0; ni < 2; ++ni){
            int gn = n0 + wn*32 + ni*16 + lr;
            float bval = bias ? bias[gn] : 0.0f;
            #pragma unroll
            for (int r = 0; r < 4; ++r){
                int gm = m0 + wm*32 + mi*16 + lk*4 + r;
                float vv = acc[mi][ni][r] + bval;
                if (OMODE == 0){
                    vv *= alpha;
                    if (resid) vv += resid[(size_t)gm*ldc + gn];
                    ((float*)Cv)[(size_t)gm*ldc + gn] = vv;
                } else {
                    ((u16*)Cv)[(size_t)gm*ldc + gn] = f2b(vv);
                }
            }
        }
    }
}

// ================= fused rel-pos flash attention =================
// grid (16, 32): i0 = blockIdx.x*64, z = blockIdx.y (b*8+h). Lockstep j-loop.
// K double-buffered; P in a 3-chunk ring (64 new rows/iter); V staged during
// softmax. q pre-scaled by 0.125.
__global__ __launch_bounds__(256) void attn_fused(
    const u16* __restrict__ qub, const u16* __restrict__ qvb,
    const u16* __restrict__ kb,  const u16* __restrict__ vt,
    const u16* __restrict__ pp,  u16* __restrict__ out)
{
    int z = blockIdx.y;
    int b = z >> 3, hh = z & 7;
    int i0 = blockIdx.x * 64;

    __shared__ u16 Kb2[2][64*64];     // 16 KB
    __shared__ u16 Pring[3][64*64];   // 24 KB (ring of 64-row P chunks)
    __shared__ u16 Vb[64*64];         //  8 KB
    __shared__ u16 PT[64*64];         //  8 KB (P-tilde, wave-local rows)
    __shared__ float Band[64*64];     // 16 KB (rotate-swizzled, wave-local rows)

    int t = threadIdx.x;
    int w = t >> 6, l = t & 63;
    int lrow = l >> 3, lslot = l & 7;
    int kswz = (lslot ^ lrow) * 8;
    int lr = l & 15, lk = l >> 4;

    // ---- prologue: qu -> Vb, qv -> PT (temp use), frags to regs ----
    #pragma unroll
    for (int it = 0; it < 2; ++it){
        int rb = it*32 + w*8;
        gld16(qub + (size_t)(b*TT + i0 + rb + lrow)*DD + hh*64 + kswz, &Vb[rb*64]);
        gld16(qvb + (size_t)(b*TT + i0 + rb + lrow)*DD + hh*64 + kswz, &PT[rb*64]);
    }
    __syncthreads();
    s8v af_u[2], af_v[2];
    #pragma unroll
    for (int kh = 0; kh < 2; ++kh){
        int sl = (kh*4 + lk) ^ (lr & 7);
        af_u[kh] = *(const s8v*)&Vb[(w*16 + lr)*64 + sl*8];
        af_v[kh] = *(const s8v*)&PT[(w*16 + lr)*64 + sl*8];
    }
    // stage K_0 and P chunks 0,1 (other buffers; drained at first loop barrier)
    #pragma unroll
    for (int it = 0; it < 2; ++it){
        int rb = it*32 + w*8;
        gld16(kb + (size_t)(b*TT +        rb + lrow)*DD + hh*64 + kswz, &Kb2[0][rb*64]);
        gld16(pp + (size_t)(960  - i0 +   rb + lrow)*DD + hh*64 + kswz, &Pring[0][rb*64]);
        gld16(pp + (size_t)(1024 - i0 +   rb + lrow)*DD + hh*64 + kswz, &Pring[1][rb*64]);
    }

    f32x4 o_[4] = {};
    float M_[4], L_[4];
    #pragma unroll
    for (int r = 0; r < 4; ++r){ M_[r] = -3e38f; L_[r] = 0.0f; }

    int nbase = 3 - w;   // band-intersecting P sub-tiles: nn in [3-w, 7-w]
    int s0 = 0, s1 = 1, s2 = 2;

    for (int jt = 0; jt < 16; ++jt){
        int cur = jt & 1;
        __syncthreads();  // staged data ready (vmcnt drained); prev PV done

        // issue async staging: V_jt -> Vb; K_{jt+1}; P chunk jt+2 -> ring slot s2
        #pragma unroll
        for (int it = 0; it < 2; ++it){
            int rb = it*32 + w*8;
            gld16(vt + ((size_t)z*64 + rb + lrow)*TT + jt*64 + kswz, &Vb[rb*64]);
            if (jt < 15){
                gld16(kb + (size_t)(b*TT + (jt+1)*64 + rb + lrow)*DD + hh*64 + kswz,
                      &Kb2[cur^1][rb*64]);
                gld16(pp + (size_t)(960 + (jt+2)*64 - i0 + rb + lrow)*DD + hh*64 + kswz,
                      &Pring[s2][rb*64]);
            }
        }

        // ---- S_ac (16x64) and band G (16x80) per wave ----
        f32x4 sac[4] = {};
        f32x4 g[5] = {};
        #pragma unroll
        for (int kh = 0; kh < 2; ++kh){
            int sl = (kh*4 + lk) ^ (lr & 7);
            #pragma unroll
            for (int n = 0; n < 4; ++n){
                s8v bK = *(const s8v*)&Kb2[cur][(n*16 + lr)*64 + sl*8];
                sac[n] = __builtin_amdgcn_mfma_f32_16x16x32_bf16(af_u[kh], bK, sac[n], 0,0,0);
            }
            #pragma unroll
            for (int n = 0; n < 5; ++n){
                int nn = nbase + n;
                const u16* pc = (nn & 4) ? &Pring[s1][0] : &Pring[s0][0];
                s8v bP = *(const s8v*)&pc[(((nn&3)*16) + lr)*64 + sl*8];
                g[n] = __builtin_amdgcn_mfma_f32_16x16x32_bf16(af_v[kh], bP, g[n], 0,0,0);
            }
        }
        // band write (f32, rotate swizzle, wave-local rows -> no barrier)
        #pragma unroll
        for (int n = 0; n < 5; ++n){
            int nn = nbase + n;
            #pragma unroll
            for (int r = 0; r < 4; ++r){
                int ii = w*16 + lk*4 + r;
                int jj = nn*16 + lr - 63 + ii;
                if (jj >= 0 && jj < 64)
                    Band[ii*64 + ((jj + 4*ii) & 63)] = g[n][r];
            }
        }

        // ---- combine band + online softmax (wave-local) ----
        float p_[4][4], sc_[4];
        #pragma unroll
        for (int r = 0; r < 4; ++r){
            int ii = w*16 + lk*4 + r;
            float sv[4]; float mx = -3e38f;
            #pragma unroll
            for (int n = 0; n < 4; ++n){
                int jj = n*16 + lr;
                float vvv = sac[n][r] + Band[ii*64 + ((jj + 4*ii) & 63)];
                sv[n] = vvv; mx = fmaxf(mx, vvv);
            }
            #pragma unroll
            for (int msk = 1; msk < 16; msk <<= 1) mx = fmaxf(mx, __shfl_xor(mx, msk));
            float nm = fmaxf(M_[r], mx);
            float scale = __expf(M_[r] - nm);
            float rs = 0.0f;
            #pragma unroll
            for (int n = 0; n < 4; ++n){ p_[n][r] = __expf(sv[n] - nm); rs += p_[n][r]; }
            #pragma unroll
            for (int msk = 1; msk < 16; msk <<= 1) rs += __shfl_xor(rs, msk);
            L_[r] = L_[r]*scale + rs;
            M_[r] = nm;
            sc_[r] = scale;
        }
        #pragma unroll
        for (int n = 0; n < 4; ++n)
            #pragma unroll
            for (int r = 0; r < 4; ++r)
                o_[n][r] *= sc_[r];

        // write P-tilde (swizzled bf16, wave-local rows)
        #pragma unroll
        for (int n = 0; n < 4; ++n)
            #pragma unroll
            for (int r = 0; r < 4; ++r){
                int ii  = w*16 + lk*4 + r;
                int col = n*16 + lr;
                int sl  = (col>>3) ^ (ii&7);
                PT[ii*64 + sl*8 + (col&7)] = f2b(p_[n][r]);
            }

        __syncthreads();  // drains V (+ next K/P) staging

        // ---- PV ----
        #pragma unroll
        for (int kh = 0; kh < 2; ++kh){
            int sl = (kh*4 + lk) ^ (lr & 7);
            s8v ap = *(const s8v*)&PT[(w*16 + lr)*64 + sl*8];
            #pragma unroll
            for (int n = 0; n < 4; ++n){
                s8v bV = *(const s8v*)&Vb[(n*16 + lr)*64 + sl*8];
                o_[n] = __builtin_amdgcn_mfma_f32_16x16x32_bf16(ap, bV, o_[n], 0,0,0);
            }
        }
        int tmp = s0; s0 = s1; s1 = s2; s2 = tmp;
    }

    #pragma unroll
    for (int n = 0; n < 4; ++n)
        #pragma unroll
        for (int r = 0; r < 4; ++r){
            int i  = i0 + w*16 + lk*4 + r;
            int dk = n*16 + lr;
            out[(size_t)(b*TT + i)*DD + hh*64 + dk] = f2b(o_[n][r] / L_[r]);
        }
}

// ================= LayerNorm: wave per row, shuffle reduce, no barriers =====
template<int OB>
__global__ __launch_bounds__(256) void ln_kernel(const float* __restrict__ in,
    const float* __restrict__ g, const float* __restrict__ b, void* __restrict__ outv)
{
    int w = threadIdx.x >> 6, l = threadIdx.x & 63;
    int row = blockIdx.x*4 + w;
    const float4* xr = (const float4*)(in + (size_t)row*DD);
    float4 v0 = xr[l], v1 = xr[64 + l];
    float s = v0.x+v0.y+v0.z+v0.w + v1.x+v1.y+v1.z+v1.w;
    float q = v0.x*v0.x+v0.y*v0.y+v0.z*v0.z+v0.w*v0.w
            + v1.x*v1.x+v1.y*v1.y+v1.z*v1.z+v1.w*v1.w;
    #pragma unroll
    for (int msk = 1; msk < 64; msk <<= 1){
        s += __shfl_xor(s, msk);
        q += __shfl_xor(q, msk);
    }
    float mean = s*(1.0f/DD);
    float var  = q*(1.0f/DD) - mean*mean;
    float inv  = rsqrtf(var+EPSF);
    float4 g0 = ((const float4*)g)[l], g1 = ((const float4*)g)[64+l];
    float4 b0 = ((const float4*)b)[l], b1 = ((const float4*)b)[64+l];
    float y0x=(v0.x-mean)*inv*g0.x+b0.x, y0y=(v0.y-mean)*inv*g0.y+b0.y;
    float y0z=(v0.z-mean)*inv*g0.z+b0.z, y0w=(v0.w-mean)*inv*g0.w+b0.w;
    float y1x=(v1.x-mean)*inv*g1.x+b1.x, y1y=(v1.y-mean)*inv*g1.y+b1.y;
    float y1z=(v1.z-mean)*inv*g1.z+b1.z, y1w=(v1.w-mean)*inv*g1.w+b1.w;
    if (OB){
        us4 o0 = { f2b(y0x), f2b(y0y), f2b(y0z), f2b(y0w) };
        us4 o1 = { f2b(y1x), f2b(y1y), f2b(y1z), f2b(y1w) };
        us4* op = (us4*)((u16*)outv + (size_t)row*DD);
        op[l] = o0; op[64+l] = o1;
    } else {
        float4 o0 = { y0x, y0y, y0z, y0w };
        float4 o1 = { y1x, y1y, y1z, y1w };
        float4* op = (float4*)((float*)outv + (size_t)row*DD);
        op[l] = o0; op[64+l] = o1;
    }
}

// ================= consolidated weight prep =================
struct Prep9 {
    const float* s[9];
    u16* d[9];
    int R[9], C[9];
    int t0[10];
};

__global__ __launch_bounds__(256) void prep_transpose(Prep9 P)
{
    __shared__ float tile[32][33];
    int bid = blockIdx.x;
    int j = 0;
    #pragma unroll
    for (int e=1; e<9; e++) if (bid >= P.t0[e]) j = e;
    int lb = bid - P.t0[j];
    int nx = P.C[j] >> 5;
    int c0 = (lb % nx) << 5;
    int r0 = (lb / nx) << 5;
    const float* in = P.s[j];
    u16* out = P.d[j];
    int R = P.R[j], C = P.C[j];
    int tx = threadIdx.x & 31, ty = threadIdx.x >> 5;
    #pragma unroll
    for (int i=0;i<4;i++){
        int rr = ty + i*8;
        tile[rr][tx] = in[(size_t)(r0+rr)*C + c0+tx];
    }
    __syncthreads();
    #pragma unroll
    for (int i=0;i<4;i++){
        int cc = ty + i*8;
        out[(size_t)(c0+cc)*R + r0+tx] = f2b(tile[tx][cc]);
    }
}

__global__ __launch_bounds__(256) void prep_convert(
    const float* __restrict__ pw1_w, const float* __restrict__ pw2_w,
    const float* __restrict__ pos_emb, const float* __restrict__ dw_w,
    const float* __restrict__ bq, const float* __restrict__ bk,
    const float* __restrict__ bv,
    u16* __restrict__ pw1b, u16* __restrict__ pw2b,
    u16* __restrict__ posb, float* __restrict__ wt, float* __restrict__ bqkv)
{
    int i = blockIdx.x*256 + threadIdx.x;
    if (i < 524288) { pw1b[i] = f2b(pw1_w[i]); return; }
    i -= 524288;
    if (i < 262144) { pw2b[i] = f2b(pw2_w[i]); return; }
    i -= 262144;
    if (i < 1048576) { posb[i] = (i < 2047*512) ? f2b(pos_emb[i]) : (u16)0; return; }
    i -= 1048576;
    if (i < 15872) { int kk = i >> 9, d = i & 511; wt[i] = dw_w[d*31+kk]; return; }
    i -= 15872;
    if (i < 1536) bqkv[i] = (i < 512) ? bq[i] : (i < 1024 ? bk[i-512] : bv[i-1024]);
}

// ================= conv-module =================
// depthwise conv K=31 with fused GLU input: reads pw1 output (f32) directly
__global__ __launch_bounds__(256) void dwconv_kernel(const float* __restrict__ t2,
    const float* __restrict__ wt, const float* __restrict__ bias, float* __restrict__ z)
{
    int d  = blockIdx.x*256 + threadIdx.x;   // gridDim.x = 2
    int c  = blockIdx.y;                     // 0..511
    int b  = c >> 7;
    int t0 = (c & 127) << 3;
    const float* pa = t2 + (size_t)b*TT*1024 + d;
    float wv[31];
    #pragma unroll
    for (int kk=0;kk<31;kk++) wv[kk] = wt[kk*512 + d];
    float xv[38];
    #pragma unroll
    for (int e=0;e<38;e++){
        int tp = t0 - 15 + e;
        if (tp >= 0 && tp < TT){
            float a  = pa[(size_t)tp*1024];
            float gg = pa[(size_t)tp*1024 + 512];
            xv[e] = a * sigmoidf_(gg);
        } else xv[e] = 0.0f;
    }
    float bsv = bias[d];
    #pragma unroll
    for (int j=0;j<8;j++){
        float sum = bsv;
        #pragma unroll
        for (int kk=0;kk<31;kk++) sum = fmaf(xv[j+kk], wv[kk], sum);
        z[(size_t)(b*TT+t0+j)*DD + d] = sum;
    }
}

__global__ __launch_bounds__(256) void bn_reduce_kernel(const float* __restrict__ z, float* __restrict__ stats)
{
    int c = blockIdx.x, t = threadIdx.x;
    float s=0.f, q=0.f;
    for (int r=t; r<NTOK; r+=256){
        float vv = z[(size_t)r*DD + c];
        s += vv; q += vv*vv;
    }
    __shared__ float rs[256], rq[256];
    rs[t]=s; rq[t]=q; __syncthreads();
    for (int st=128; st>0; st>>=1){
        if (t<st){ rs[t]+=rs[t+st]; rq[t]+=rq[t+st]; }
        __syncthreads();
    }
    if (t==0){ stats[c]=rs[0]; stats[DD+c]=rq[0]; }
}

__global__ __launch_bounds__(256) void bn_apply_kernel(const float* __restrict__ z,
    const float* __restrict__ stats, const float* __restrict__ g, const float* __restrict__ b,
    u16* __restrict__ out)
{
    int idx = blockIdx.x*256 + threadIdx.x;
    int c = idx & (DD-1);
    float m   = stats[c]*(1.0f/NTOK);
    float var = stats[DD+c]*(1.0f/NTOK) - m*m;
    float vv  = (z[idx]-m)*rsqrtf(var+EPSF)*g[c] + b[c];
    out[idx]  = f2b(vv*sigmoidf_(vv));
}

extern "C" void kernel_launch(void* const* d_in, const int* in_sizes, int n_in,
                              void* d_out, int out_size, void* d_ws, size_t ws_size,
                              hipStream_t stream)
{
    const float* x       = (const float*)d_in[0];
    const float* pos_emb = (const float*)d_in[1];
    const float* ln1_g=(const float*)d_in[2],  *ln1_b=(const float*)d_in[3];
    const float* ln2_g=(const float*)d_in[4],  *ln2_b=(const float*)d_in[5];
    const float* ln3_g=(const float*)d_in[6],  *ln3_b=(const float*)d_in[7];
    const float* ln4_g=(const float*)d_in[8],  *ln4_b=(const float*)d_in[9];
    const float* ln5_g=(const float*)d_in[10], *ln5_b=(const float*)d_in[11];
    const float* ff1_w1=(const float*)d_in[12], *ff1_b1=(const float*)d_in[13];
    const float* ff1_w2=(const float*)d_in[14], *ff1_b2=(const float*)d_in[15];
    const float* wq=(const float*)d_in[16], *bq=(const float*)d_in[17];
    const float* wk=(const float*)d_in[18], *bk=(const float*)d_in[19];
    const float* wv=(const float*)d_in[20], *bv=(const float*)d_in[21];
    const float* wp=(const float*)d_in[22];
    const float* wo=(const float*)d_in[23], *bo=(const float*)d_in[24];
    const float* pos_u=(const float*)d_in[25], *pos_v=(const float*)d_in[26];
    const float* pw1_w=(const float*)d_in[27], *pw1_b=(const float*)d_in[28];
    const float* dw_w=(const float*)d_in[29],  *dw_b=(const float*)d_in[30];
    const float* bn_g=(const float*)d_in[31],  *bn_b=(const float*)d_in[32];
    const float* pw2_w=(const float*)d_in[33], *pw2_b=(const float*)d_in[34];
    const float* ff2_w1=(const float*)d_in[35], *ff2_b1=(const float*)d_in[36];
    const float* ff2_w2=(const float*)d_in[37], *ff2_b2=(const float*)d_in[38];

    char* W = (char*)d_ws;
    float* h    = (float*)(W);                  // 8 MB f32
    u16*  xn    = (u16*) (W + (size_t) 8*MB);   // 4 MB (ln out / attn out)
    u16*  wall  = (u16*) (W + (size_t)12*MB);   // 16 MB prepped weights
    u16*  qub   = (u16*) (W + (size_t)28*MB);   // qub/qvb/kb/vt contiguous (OMODE5)
    u16*  qvb   = (u16*) (W + (size_t)32*MB);
    u16*  kb    = (u16*) (W + (size_t)36*MB);
    u16*  vt    = (u16*) (W + (size_t)40*MB);   // (B,H,DK,T)
    u16*  pproj = (u16*) (W + (size_t)44*MB);   // 2048x512
    char* big   = W + (size_t)48*MB;            // shared region
    u16*  ffh   = (u16*)big;                    // 16 MB FFN hidden
    float* t2   = (float*)big;                  // 16 MB conv pw1 out
    float* t3   = (float*)(big + (size_t)16*MB);// 8 MB dwconv out
    float* stats= (float*)(W + (size_t)112*MB); // 4 KB
    float* wt   = stats + 4096;                 // (31,512) f32
    float* bqkv = wt + 15872;                   // 1536 f32

    u16* ff1w1T = wall;
    u16* ff1w2T = wall + 1048576;
    u16* wqT    = wall + 2097152;   // wq/wk/wv contiguous -> N=1536 merged GEMM
    u16* wkT    = wall + 2359296;
    u16* wvT    = wall + 2621440;
    u16* wpT    = wall + 2883584;
    u16* woT    = wall + 3145728;
    u16* ff2w1T = wall + 3407872;
    u16* ff2w2T = wall + 4456448;
    u16* pw1b   = wall + 5505024;
    u16* pw2b   = wall + 6029312;
    u16* posb   = wall + 6291456;

    dim3 blk(256);

    // ---------------- weight prep (2 launches) ----------------
    Prep9 P;
    P.s[0]=ff1_w1; P.d[0]=ff1w1T; P.R[0]=512;  P.C[0]=2048;
    P.s[1]=ff1_w2; P.d[1]=ff1w2T; P.R[1]=2048; P.C[1]=512;
    P.s[2]=wq;     P.d[2]=wqT;    P.R[2]=512;  P.C[2]=512;
    P.s[3]=wk;     P.d[3]=wkT;    P.R[3]=512;  P.C[3]=512;
    P.s[4]=wv;     P.d[4]=wvT;    P.R[4]=512;  P.C[4]=512;
    P.s[5]=wp;     P.d[5]=wpT;    P.R[5]=512;  P.C[5]=512;
    P.s[6]=wo;     P.d[6]=woT;    P.R[6]=512;  P.C[6]=512;
    P.s[7]=ff2_w1; P.d[7]=ff2w1T; P.R[7]=512;  P.C[7]=2048;
    P.s[8]=ff2_w2; P.d[8]=ff2w2T; P.R[8]=2048; P.C[8]=512;
    int tc[9] = {1024,1024,256,256,256,256,256,1024,1024};
    P.t0[0]=0; for (int e=0;e<9;e++) P.t0[e+1]=P.t0[e]+tc[e];
    prep_transpose<<<dim3(5376), blk, 0, stream>>>(P);
    prep_convert<<<dim3(7236), blk, 0, stream>>>(pw1_w, pw2_w, pos_emb, dw_w,
                                                 bq, bk, bv,
                                                 pw1b, pw2b, posb, wt, bqkv);

    // ---------------- FFN1: h = x + 0.5*ffn(ln1(x)) ----------------
    ln_kernel<1><<<dim3(NTOK/4), blk, 0, stream>>>(x, ln1_g, ln1_b, xn);
    bgemm128<1><<<dim3(16,32), blk, 0, stream>>>(xn,512, ff1w1T,512,
        ffh,2048, 512, ff1_b1,1,1.f, nullptr,nullptr,nullptr);
    bgemm64<0><<<dim3(8,64), blk, 0, stream>>>(ffh,2048, ff1w2T,2048,
        h,512, 2048, ff1_b2,0.5f, x);

    // ---------------- Attention: h = h + attn(ln2(h)) ----------------
    ln_kernel<1><<<dim3(NTOK/4), blk, 0, stream>>>(h, ln2_g, ln2_b, xn);
    bgemm128<5><<<dim3(12,32), blk, 0, stream>>>(xn,512, wqT,512,
        qub,512, 512, bqkv,0,1.f, nullptr,pos_u,pos_v);
    bgemm64<1><<<dim3(8,32), blk, 0, stream>>>(posb,512, wpT,512,
        pproj,512, 512, nullptr,1.f, nullptr);

    attn_fused<<<dim3(16,32), blk, 0, stream>>>(qub, qvb, kb, vt, pproj, xn);

    bgemm64<0><<<dim3(8,64), blk, 0, stream>>>(xn,512, woT,512,
        h,512, 512, bo,1.f, h);

    // ---------------- Conv module ----------------
    ln_kernel<1><<<dim3(NTOK/4), blk, 0, stream>>>(h, ln3_g, ln3_b, xn);
    bgemm128<0><<<dim3(8,32), blk, 0, stream>>>(xn,512, pw1b,512,
        t2,1024, 512, pw1_b,0,1.f, nullptr,nullptr,nullptr);
    dwconv_kernel<<<dim3(2,512), blk, 0, stream>>>(t2, wt, dw_b, t3);
    bn_reduce_kernel<<<dim3(DD), blk, 0, stream>>>(t3, stats);
    bn_apply_kernel<<<dim3(NTOK*DD/256), blk, 0, stream>>>(t3, stats, bn_g, bn_b, xn);
    bgemm64<0><<<dim3(8,64), blk, 0, stream>>>(xn,512, pw2b,512,
        h,512, 512, pw2_b,1.f, h);

    // ---------------- FFN2 ----------------
    ln_kernel<1><<<dim3(NTOK/4), blk, 0, stream>>>(h, ln4_g, ln4_b, xn);
    bgemm128<1><<<dim3(16,32), blk, 0, stream>>>(xn,512, ff2w1T,512,
        ffh,2048, 512, ff2_b1,1,1.f, nullptr,nullptr,nullptr);
    bgemm64<0><<<dim3(8,64), blk, 0, stream>>>(ffh,2048, ff2w2T,2048,
        h,512, 2048, ff2_b2,0.5f, h);

    // ---------------- Final LN ----------------
    ln_kernel<0><<<dim3(NTOK/4), blk, 0, stream>>>(h, ln5_g, ln5_b, (float*)d_out);
}

// Round 8
// 291.401 us; speedup vs baseline: 1.5623x; 1.0459x over previous
//
#include <hip/hip_runtime.h>
#include <math.h>

#define TT   1024
#define BBZ  4
#define DD   512
#define DFF_ 2048
#define HH   8
#define DKK  64
#define NTOK 4096
#define EPSF 1e-5f
#define MB   1048576

typedef unsigned short u16;
typedef __attribute__((ext_vector_type(8))) short s8v;    // 8 bf16 (4 VGPRs)
typedef __attribute__((ext_vector_type(4))) float f32x4;
typedef __attribute__((ext_vector_type(4))) unsigned short us4;

__device__ __forceinline__ float b2f(u16 v){
    union { unsigned int u; float f; } x; x.u = ((unsigned int)v) << 16; return x.f;
}
__device__ __forceinline__ u16 f2b(float f){
    union { float f; unsigned int u; } x; x.f = f;
    unsigned int r = x.u + 0x7fffu + ((x.u >> 16) & 1u);
    return (u16)(r >> 16);
}
__device__ __forceinline__ float sigmoidf_(float x){ return 1.0f/(1.0f+__expf(-x)); }

__device__ __forceinline__ void gld16(const u16* g, u16* l){
    __builtin_amdgcn_global_load_lds(
        (const __attribute__((address_space(1))) unsigned int*)g,
        (__attribute__((address_space(3))) unsigned int*)l, 16, 0, 0);
}

// ================= 128x128-tile MFMA GEMM (wide N) =================
// C = epilogue(A @ B^T_view), A:(M,K) bf16 row-major, B:(N,K) bf16 row-major.
// OMODE 0: f32 out (+bias, act, *alpha, +resid)   1: bf16 out (+bias, act)
// OMODE 5: merged QKV epilogue (q scaled by 0.125, dual +posu/+posv).
// OMODE 6: interleaved GLU-pair bf16 store: (row, d, a/g) for dwconv.
template<int OMODE>
__global__ __launch_bounds__(256) void bgemm128(
    const u16* __restrict__ A, int lda,
    const u16* __restrict__ B, int ldb,
    void* __restrict__ Cv, int ldc, int K,
    const float* __restrict__ bias, int act, float alpha,
    const float* __restrict__ resid,
    const float* __restrict__ posu, const float* __restrict__ posv)
{
    int n0 = blockIdx.x * 128;
    int m0 = blockIdx.y * 128;

    __shared__ u16 As[128*64];
    __shared__ u16 Bs[128*64];

    int t = threadIdx.x;
    int w = t >> 6, l = t & 63;
    int lrow = l >> 3, lslot = l & 7;
    int kswz = (lslot ^ lrow) * 8;
    int wm = w >> 1, wn = w & 1;
    int lr = l & 15, lk = l >> 4;

    f32x4 acc[4][4] = {};

    for (int k0 = 0; k0 < K; k0 += 64){
        #pragma unroll
        for (int it = 0; it < 4; ++it){
            int rb = it*32 + w*8;
            gld16(A + (size_t)(m0 + rb + lrow)*lda + k0 + kswz, &As[rb*64]);
            gld16(B + (size_t)(n0 + rb + lrow)*ldb + k0 + kswz, &Bs[rb*64]);
        }
        __syncthreads();

        s8v af[2][4], bf[2][4];
        #pragma unroll
        for (int kh = 0; kh < 2; ++kh){
            int sl = (kh*4 + lk) ^ (lr & 7);
            #pragma unroll
            for (int mi = 0; mi < 4; ++mi)
                af[kh][mi] = *(const s8v*)&As[(wm*64 + mi*16 + lr)*64 + sl*8];
            #pragma unroll
            for (int ni = 0; ni < 4; ++ni)
                bf[kh][ni] = *(const s8v*)&Bs[(wn*64 + ni*16 + lr)*64 + sl*8];
        }
        #pragma unroll
        for (int kh = 0; kh < 2; ++kh)
            #pragma unroll
            for (int mi = 0; mi < 4; ++mi)
                #pragma unroll
                for (int ni = 0; ni < 4; ++ni)
                    acc[mi][ni] = __builtin_amdgcn_mfma_f32_16x16x32_bf16(
                        af[kh][mi], bf[kh][ni], acc[mi][ni], 0, 0, 0);
        __syncthreads();
    }

    #pragma unroll
    for (int mi = 0; mi < 4; ++mi){
        #pragma unroll
        for (int ni = 0; ni < 4; ++ni){
            int gn = n0 + wn*64 + ni*16 + lr;
            float bval = bias ? bias[gn] : 0.0f;
            #pragma unroll
            for (int r = 0; r < 4; ++r){
                int gm = m0 + wm*64 + mi*16 + lk*4 + r;
                float vv = acc[mi][ni][r] + bval;
                if (act) vv = vv * sigmoidf_(vv);
                if (OMODE == 0){
                    vv *= alpha;
                    if (resid) vv += resid[(size_t)gm*ldc + gn];
                    ((float*)Cv)[(size_t)gm*ldc + gn] = vv;
                } else if (OMODE == 1){
                    ((u16*)Cv)[(size_t)gm*ldc + gn] = f2b(vv);
                } else if (OMODE == 5){ // merged QKV
                    u16* base = (u16*)Cv;
                    if (gn < 512){
                        size_t idx = (size_t)gm*512 + gn;
                        base[idx]              = f2b((vv + posu[gn])*0.125f);
                        base[idx + (2u<<20)]   = f2b((vv + posv[gn])*0.125f);
                    } else if (gn < 1024){
                        base[(4u<<20) + (size_t)gm*512 + (gn-512)] = f2b(vv);
                    } else {
                        int gnp = gn - 1024;
                        int bb = gm >> 10, tt2 = gm & 1023;
                        size_t idx = (((size_t)(bb*8 + (gnp>>6)))*64 + (gnp&63))*1024 + tt2;
                        base[(6u<<20) + idx] = f2b(vv);
                    }
                } else { // 6: interleaved (a,g) bf16 pairs for dwconv
                    u16* base = (u16*)Cv;
                    size_t idx = (gn < 512)
                        ? ((size_t)gm*512 + gn)*2
                        : ((size_t)gm*512 + (gn-512))*2 + 1;
                    base[idx] = f2b(vv);
                }
            }
        }
    }
}

// ================= 64x64-tile MFMA GEMM, BK=64 (N=512, K=512 shapes) ========
// OMODE 0: f32 out (+bias, *alpha, +resid)   1: bf16 out (+bias)
template<int OMODE>
__global__ __launch_bounds__(256) void bgemm64(
    const u16* __restrict__ A, int lda,
    const u16* __restrict__ B, int ldb,
    void* __restrict__ Cv, int ldc, int K,
    const float* __restrict__ bias, float alpha,
    const float* __restrict__ resid)
{
    int n0 = blockIdx.x * 64;
    int m0 = blockIdx.y * 64;

    __shared__ u16 As[64*64];
    __shared__ u16 Bs[64*64];

    int t = threadIdx.x;
    int w = t >> 6, l = t & 63;
    int lrow = l >> 3, lslot = l & 7;
    int kswz = (lslot ^ lrow) * 8;
    int wm = w >> 1, wn = w & 1;
    int lr = l & 15, lk = l >> 4;

    f32x4 acc[2][2] = {};

    for (int k0 = 0; k0 < K; k0 += 64){
        #pragma unroll
        for (int it = 0; it < 2; ++it){
            int rb = it*32 + w*8;
            gld16(A + (size_t)(m0 + rb + lrow)*lda + k0 + kswz, &As[rb*64]);
            gld16(B + (size_t)(n0 + rb + lrow)*ldb + k0 + kswz, &Bs[rb*64]);
        }
        __syncthreads();

        s8v af[2][2], bf[2][2];
        #pragma unroll
        for (int kh = 0; kh < 2; ++kh){
            int sl = (kh*4 + lk) ^ (lr & 7);
            #pragma unroll
            for (int mi = 0; mi < 2; ++mi)
                af[kh][mi] = *(const s8v*)&As[(wm*32 + mi*16 + lr)*64 + sl*8];
            #pragma unroll
            for (int ni = 0; ni < 2; ++ni)
                bf[kh][ni] = *(const s8v*)&Bs[(wn*32 + ni*16 + lr)*64 + sl*8];
        }
        #pragma unroll
        for (int kh = 0; kh < 2; ++kh)
            #pragma unroll
            for (int mi = 0; mi < 2; ++mi)
                #pragma unroll
                for (int ni = 0; ni < 2; ++ni)
                    acc[mi][ni] = __builtin_amdgcn_mfma_f32_16x16x32_bf16(
                        af[kh][mi], bf[kh][ni], acc[mi][ni], 0, 0, 0);
        __syncthreads();
    }

    #pragma unroll
    for (int mi = 0; mi < 2; ++mi){
        #pragma unroll
        for (int ni = 0; ni < 2; ++ni){
            int gn = n0 + wn*32 + ni*16 + lr;
            float bval = bias ? bias[gn] : 0.0f;
            #pragma unroll
            for (int r = 0; r < 4; ++r){
                int gm = m0 + wm*32 + mi*16 + lk*4 + r;
                float vv = acc[mi][ni][r] + bval;
                if (OMODE == 0){
                    vv *= alpha;
                    if (resid) vv += resid[(size_t)gm*ldc + gn];
                    ((float*)Cv)[(size_t)gm*ldc + gn] = vv;
                } else {
                    ((u16*)Cv)[(size_t)gm*ldc + gn] = f2b(vv);
                }
            }
        }
    }
}

// ================= 64x64-tile MFMA GEMM, BK=128 (K=2048 shapes) ==============
// f32 out (+bias, *alpha, +resid). 16-slot XOR swizzle, half the barriers.
__global__ __launch_bounds__(256) void bgemm64k(
    const u16* __restrict__ A, int lda,
    const u16* __restrict__ B, int ldb,
    float* __restrict__ C, int ldc, int K,
    const float* __restrict__ bias, float alpha,
    const float* __restrict__ resid)
{
    int n0 = blockIdx.x * 64;
    int m0 = blockIdx.y * 64;

    __shared__ u16 As[64*128];    // 16 KB
    __shared__ u16 Bs[64*128];    // 16 KB

    int t = threadIdx.x;
    int w = t >> 6, l = t & 63;
    int r4 = l >> 4;              // 0..3: row within wave's 4-row slab
    int s16 = l & 15;             // 16B slot within 256B row
    int kswz = (s16 ^ (w*4 + r4)) * 8;   // pre-swizzled global k offset
    int wm = w >> 1, wn = w & 1;
    int lr = l & 15, lk = l >> 4;

    f32x4 acc[2][2] = {};

    for (int k0 = 0; k0 < K; k0 += 128){
        #pragma unroll
        for (int cb = 0; cb < 4; ++cb){
            int rowu = cb*16 + w*4;               // wave-uniform base row
            gld16(A + (size_t)(m0 + rowu + r4)*lda + k0 + kswz, &As[rowu*128]);
            gld16(B + (size_t)(n0 + rowu + r4)*ldb + k0 + kswz, &Bs[rowu*128]);
        }
        __syncthreads();

        #pragma unroll
        for (int kh = 0; kh < 4; ++kh){
            int sl = ((kh*4 + lk) ^ lr) * 8;
            s8v af[2], bf[2];
            #pragma unroll
            for (int mi = 0; mi < 2; ++mi)
                af[mi] = *(const s8v*)&As[(wm*32 + mi*16 + lr)*128 + sl];
            #pragma unroll
            for (int ni = 0; ni < 2; ++ni)
                bf[ni] = *(const s8v*)&Bs[(wn*32 + ni*16 + lr)*128 + sl];
            #pragma unroll
            for (int mi = 0; mi < 2; ++mi)
                #pragma unroll
                for (int ni = 0; ni < 2; ++ni)
                    acc[mi][ni] = __builtin_amdgcn_mfma_f32_16x16x32_bf16(
                        af[mi], bf[ni], acc[mi][ni], 0, 0, 0);
        }
        __syncthreads();
    }

    #pragma unroll
    for (int mi = 0; mi < 2; ++mi){
        #pragma unroll
        for (int ni = 0; ni < 2; ++ni){
            int gn = n0 + wn*32 + ni*16 + lr;
            float bval = bias ? bias[gn] : 0.0f;
            #pragma unroll
            for (int r = 0; r < 4; ++r){
                int gm = m0 + wm*32 + mi*16 + lk*4 + r;
                float vv = (acc[mi][ni][r] + bval) * alpha;
                if (resid) vv += resid[(size_t)gm*ldc + gn];
                C[(size_t)gm*ldc + gn] = vv;
            }
        }
    }
}

// ================= fused rel-pos flash attention =================
// grid (16, 32): i0 = blockIdx.x*64, z = blockIdx.y (b*8+h). Lockstep j-loop.
// K and V double-buffered, P in a 3-chunk ring: ONE barrier per iteration;
// all prefetches get a full-iteration landing window. q pre-scaled by 0.125.
__global__ __launch_bounds__(256) void attn_fused(
    const u16* __restrict__ qub, const u16* __restrict__ qvb,
    const u16* __restrict__ kb,  const u16* __restrict__ vt,
    const u16* __restrict__ pp,  u16* __restrict__ out)
{
    int z = blockIdx.y;
    int b = z >> 3, hh = z & 7;
    int i0 = blockIdx.x * 64;

    __shared__ u16 Kb2[2][64*64];     // 16 KB
    __shared__ u16 Vb2[2][64*64];     // 16 KB
    __shared__ u16 Pring[3][64*64];   // 24 KB
    __shared__ u16 PT[64*64];         //  8 KB (P-tilde; qu staging in prologue)
    __shared__ float Band[64*64];     // 16 KB (band; qv staging in prologue)

    int t = threadIdx.x;
    int w = t >> 6, l = t & 63;
    int lrow = l >> 3, lslot = l & 7;
    int kswz = (lslot ^ lrow) * 8;
    int lr = l & 15, lk = l >> 4;

    // ---- prologue: qu -> PT, qv -> Band (as u16), frags to regs ----
    #pragma unroll
    for (int it = 0; it < 2; ++it){
        int rb = it*32 + w*8;
        gld16(qub + (size_t)(b*TT + i0 + rb + lrow)*DD + hh*64 + kswz, &PT[rb*64]);
        gld16(qvb + (size_t)(b*TT + i0 + rb + lrow)*DD + hh*64 + kswz,
              (u16*)Band + rb*64);
    }
    __syncthreads();
    s8v af_u[2], af_v[2];
    #pragma unroll
    for (int kh = 0; kh < 2; ++kh){
        int sl = (kh*4 + lk) ^ (lr & 7);
        af_u[kh] = *(const s8v*)&PT[(w*16 + lr)*64 + sl*8];
        af_v[kh] = *(const s8v*)((const u16*)Band + (w*16 + lr)*64 + sl*8);
    }
    // stage K_0 -> Kb2[0], V_0 -> Vb2[0], P chunks 0,1 -> ring
    #pragma unroll
    for (int it = 0; it < 2; ++it){
        int rb = it*32 + w*8;
        gld16(kb + (size_t)(b*TT +        rb + lrow)*DD + hh*64 + kswz, &Kb2[0][rb*64]);
        gld16(vt + ((size_t)z*64 + rb + lrow)*TT +                kswz, &Vb2[0][rb*64]);
        gld16(pp + (size_t)(960  - i0 +   rb + lrow)*DD + hh*64 + kswz, &Pring[0][rb*64]);
        gld16(pp + (size_t)(1024 - i0 +   rb + lrow)*DD + hh*64 + kswz, &Pring[1][rb*64]);
    }

    f32x4 o_[4] = {};
    float M_[4], L_[4];
    #pragma unroll
    for (int r = 0; r < 4; ++r){ M_[r] = -3e38f; L_[r] = 0.0f; }

    int nbase = 3 - w;   // band-intersecting P sub-tiles: nn in [3-w, 7-w]
    int s0 = 0, s1 = 1, s2 = 2;

    for (int jt = 0; jt < 16; ++jt){
        int cur = jt & 1;
        __syncthreads();  // all staged loads for THIS iter have landed

        // issue next-iter staging (full-iteration landing window)
        if (jt < 15){
            #pragma unroll
            for (int it = 0; it < 2; ++it){
                int rb = it*32 + w*8;
                gld16(kb + (size_t)(b*TT + (jt+1)*64 + rb + lrow)*DD + hh*64 + kswz,
                      &Kb2[cur^1][rb*64]);
                gld16(vt + ((size_t)z*64 + rb + lrow)*TT + (jt+1)*64 + kswz,
                      &Vb2[cur^1][rb*64]);
                gld16(pp + (size_t)(960 + (jt+2)*64 - i0 + rb + lrow)*DD + hh*64 + kswz,
                      &Pring[s2][rb*64]);
            }
        }

        // ---- S_ac (16x64) and band G (16x80) per wave ----
        f32x4 sac[4] = {};
        f32x4 g[5] = {};
        #pragma unroll
        for (int kh = 0; kh < 2; ++kh){
            int sl = (kh*4 + lk) ^ (lr & 7);
            #pragma unroll
            for (int n = 0; n < 4; ++n){
                s8v bK = *(const s8v*)&Kb2[cur][(n*16 + lr)*64 + sl*8];
                sac[n] = __builtin_amdgcn_mfma_f32_16x16x32_bf16(af_u[kh], bK, sac[n], 0,0,0);
            }
            #pragma unroll
            for (int n = 0; n < 5; ++n){
                int nn = nbase + n;
                const u16* pc = (nn & 4) ? &Pring[s1][0] : &Pring[s0][0];
                s8v bP = *(const s8v*)&pc[(((nn&3)*16) + lr)*64 + sl*8];
                g[n] = __builtin_amdgcn_mfma_f32_16x16x32_bf16(af_v[kh], bP, g[n], 0,0,0);
            }
        }
        // band write (f32, rotate swizzle, wave-local rows -> no barrier)
        #pragma unroll
        for (int n = 0; n < 5; ++n){
            int nn = nbase + n;
            #pragma unroll
            for (int r = 0; r < 4; ++r){
                int ii = w*16 + lk*4 + r;
                int jj = nn*16 + lr - 63 + ii;
                if (jj >= 0 && jj < 64)
                    Band[ii*64 + ((jj + 4*ii) & 63)] = g[n][r];
            }
        }

        // ---- combine band + online softmax (wave-local) ----
        float p_[4][4], sc_[4];
        #pragma unroll
        for (int r = 0; r < 4; ++r){
            int ii = w*16 + lk*4 + r;
            float sv[4]; float mx = -3e38f;
            #pragma unroll
            for (int n = 0; n < 4; ++n){
                int jj = n*16 + lr;
                float vvv = sac[n][r] + Band[ii*64 + ((jj + 4*ii) & 63)];
                sv[n] = vvv; mx = fmaxf(mx, vvv);
            }
            #pragma unroll
            for (int msk = 1; msk < 16; msk <<= 1) mx = fmaxf(mx, __shfl_xor(mx, msk));
            float nm = fmaxf(M_[r], mx);
            float scale = __expf(M_[r] - nm);
            float rs = 0.0f;
            #pragma unroll
            for (int n = 0; n < 4; ++n){ p_[n][r] = __expf(sv[n] - nm); rs += p_[n][r]; }
            #pragma unroll
            for (int msk = 1; msk < 16; msk <<= 1) rs += __shfl_xor(rs, msk);
            L_[r] = L_[r]*scale + rs;
            M_[r] = nm;
            sc_[r] = scale;
        }
        #pragma unroll
        for (int n = 0; n < 4; ++n)
            #pragma unroll
            for (int r = 0; r < 4; ++r)
                o_[n][r] *= sc_[r];

        // write P-tilde (swizzled bf16, wave-local rows; read by same wave only)
        #pragma unroll
        for (int n = 0; n < 4; ++n)
            #pragma unroll
            for (int r = 0; r < 4; ++r){
                int ii  = w*16 + lk*4 + r;
                int col = n*16 + lr;
                int sl  = (col>>3) ^ (ii&7);
                PT[ii*64 + sl*8 + (col&7)] = f2b(p_[n][r]);
            }

        // ---- PV (V_jt landed at this iter's top barrier) ----
        #pragma unroll
        for (int kh = 0; kh < 2; ++kh){
            int sl = (kh*4 + lk) ^ (lr & 7);
            s8v ap = *(const s8v*)&PT[(w*16 + lr)*64 + sl*8];
            #pragma unroll
            for (int n = 0; n < 4; ++n){
                s8v bV = *(const s8v*)&Vb2[cur][(n*16 + lr)*64 + sl*8];
                o_[n] = __builtin_amdgcn_mfma_f32_16x16x32_bf16(ap, bV, o_[n], 0,0,0);
            }
        }
        int tmp = s0; s0 = s1; s1 = s2; s2 = tmp;
    }

    #pragma unroll
    for (int n = 0; n < 4; ++n)
        #pragma unroll
        for (int r = 0; r < 4; ++r){
            int i  = i0 + w*16 + lk*4 + r;
            int dk = n*16 + lr;
            out[(size_t)(b*TT + i)*DD + hh*64 + dk] = f2b(o_[n][r] / L_[r]);
        }
}

// ================= LayerNorm: wave per row, shuffle reduce, no barriers =====
template<int OB>
__global__ __launch_bounds__(256) void ln_kernel(const float* __restrict__ in,
    const float* __restrict__ g, const float* __restrict__ b, void* __restrict__ outv)
{
    int w = threadIdx.x >> 6, l = threadIdx.x & 63;
    int row = blockIdx.x*4 + w;
    const float4* xr = (const float4*)(in + (size_t)row*DD);
    float4 v0 = xr[l], v1 = xr[64 + l];
    float s = v0.x+v0.y+v0.z+v0.w + v1.x+v1.y+v1.z+v1.w;
    float q = v0.x*v0.x+v0.y*v0.y+v0.z*v0.z+v0.w*v0.w
            + v1.x*v1.x+v1.y*v1.y+v1.z*v1.z+v1.w*v1.w;
    #pragma unroll
    for (int msk = 1; msk < 64; msk <<= 1){
        s += __shfl_xor(s, msk);
        q += __shfl_xor(q, msk);
    }
    float mean = s*(1.0f/DD);
    float var  = q*(1.0f/DD) - mean*mean;
    float inv  = rsqrtf(var+EPSF);
    float4 g0 = ((const float4*)g)[l], g1 = ((const float4*)g)[64+l];
    float4 b0 = ((const float4*)b)[l], b1 = ((const float4*)b)[64+l];
    float y0x=(v0.x-mean)*inv*g0.x+b0.x, y0y=(v0.y-mean)*inv*g0.y+b0.y;
    float y0z=(v0.z-mean)*inv*g0.z+b0.z, y0w=(v0.w-mean)*inv*g0.w+b0.w;
    float y1x=(v1.x-mean)*inv*g1.x+b1.x, y1y=(v1.y-mean)*inv*g1.y+b1.y;
    float y1z=(v1.z-mean)*inv*g1.z+b1.z, y1w=(v1.w-mean)*inv*g1.w+b1.w;
    if (OB){
        us4 o0 = { f2b(y0x), f2b(y0y), f2b(y0z), f2b(y0w) };
        us4 o1 = { f2b(y1x), f2b(y1y), f2b(y1z), f2b(y1w) };
        us4* op = (us4*)((u16*)outv + (size_t)row*DD);
        op[l] = o0; op[64+l] = o1;
    } else {
        float4 o0 = { y0x, y0y, y0z, y0w };
        float4 o1 = { y1x, y1y, y1z, y1w };
        float4* op = (float4*)((float*)outv + (size_t)row*DD);
        op[l] = o0; op[64+l] = o1;
    }
}

// ================= consolidated weight prep =================
struct Prep9 {
    const float* s[9];
    u16* d[9];
    int R[9], C[9];
    int t0[10];
};

__global__ __launch_bounds__(256) void prep_transpose(Prep9 P)
{
    __shared__ float tile[32][33];
    int bid = blockIdx.x;
    int j = 0;
    #pragma unroll
    for (int e=1; e<9; e++) if (bid >= P.t0[e]) j = e;
    int lb = bid - P.t0[j];
    int nx = P.C[j] >> 5;
    int c0 = (lb % nx) << 5;
    int r0 = (lb / nx) << 5;
    const float* in = P.s[j];
    u16* out = P.d[j];
    int R = P.R[j], C = P.C[j];
    int tx = threadIdx.x & 31, ty = threadIdx.x >> 5;
    #pragma unroll
    for (int i=0;i<4;i++){
        int rr = ty + i*8;
        tile[rr][tx] = in[(size_t)(r0+rr)*C + c0+tx];
    }
    __syncthreads();
    #pragma unroll
    for (int i=0;i<4;i++){
        int cc = ty + i*8;
        out[(size_t)(c0+cc)*R + r0+tx] = f2b(tile[tx][cc]);
    }
}

__global__ __launch_bounds__(256) void prep_convert(
    const float* __restrict__ pw1_w, const float* __restrict__ pw2_w,
    const float* __restrict__ pos_emb, const float* __restrict__ dw_w,
    const float* __restrict__ bq, const float* __restrict__ bk,
    const float* __restrict__ bv,
    u16* __restrict__ pw1b, u16* __restrict__ pw2b,
    u16* __restrict__ posb, float* __restrict__ wt, float* __restrict__ bqkv)
{
    int i = blockIdx.x*256 + threadIdx.x;
    if (i < 524288) { pw1b[i] = f2b(pw1_w[i]); return; }
    i -= 524288;
    if (i < 262144) { pw2b[i] = f2b(pw2_w[i]); return; }
    i -= 262144;
    if (i < 1048576) { posb[i] = (i < 2047*512) ? f2b(pos_emb[i]) : (u16)0; return; }
    i -= 1048576;
    if (i < 15872) { int kk = i >> 9, d = i & 511; wt[i] = dw_w[d*31+kk]; return; }
    i -= 15872;
    if (i < 1536) bqkv[i] = (i < 512) ? bq[i] : (i < 1024 ? bk[i-512] : bv[i-1024]);
}

// ================= conv-module =================
// depthwise conv K=31, GLU fused: reads interleaved (a,g) bf16 pairs as u32
__global__ __launch_bounds__(256) void dwconv_kernel(const unsigned int* __restrict__ t2i,
    const float* __restrict__ wt, const float* __restrict__ bias, u16* __restrict__ z)
{
    int d  = blockIdx.x*256 + threadIdx.x;   // gridDim.x = 2
    int c  = blockIdx.y;                     // 0..511
    int b  = c >> 7;
    int t0 = (c & 127) << 3;
    const unsigned int* pa = t2i + (size_t)b*TT*512 + d;
    float wv[31];
    #pragma unroll
    for (int kk=0;kk<31;kk++) wv[kk] = wt[kk*512 + d];
    float xv[38];
    #pragma unroll
    for (int e=0;e<38;e++){
        int tp = t0 - 15 + e;
        if (tp >= 0 && tp < TT){
            unsigned int pv = pa[(size_t)tp*512];
            float a  = b2f((u16)(pv & 0xffffu));
            float gg = b2f((u16)(pv >> 16));
            xv[e] = a * sigmoidf_(gg);
        } else xv[e] = 0.0f;
    }
    float bsv = bias[d];
    #pragma unroll
    for (int j=0;j<8;j++){
        float sum = bsv;
        #pragma unroll
        for (int kk=0;kk<31;kk++) sum = fmaf(xv[j+kk], wv[kk], sum);
        z[(size_t)(b*TT+t0+j)*DD + d] = f2b(sum);
    }
}

// BN stats: coalesced row-block reduce + f32 atomics into zeroed stats[1024]
__global__ __launch_bounds__(256) void bn_reduce2(const u16* __restrict__ z,
    float* __restrict__ stats)
{
    int bi = blockIdx.x;          // 256 blocks x 16 rows
    int t  = threadIdx.x;
    float s0=0.f,q0=0.f,s1=0.f,q1=0.f;
    #pragma unroll
    for (int r=0;r<16;r++){
        size_t row = (size_t)(bi*16 + r)*DD;
        float v0 = b2f(z[row + t]);
        float v1 = b2f(z[row + t + 256]);
        s0 += v0; q0 += v0*v0;
        s1 += v1; q1 += v1*v1;
    }
    atomicAdd(&stats[t],        s0);
    atomicAdd(&stats[512 + t],  q0);
    atomicAdd(&stats[t + 256],      s1);
    atomicAdd(&stats[512 + t + 256], q1);
}

__global__ __launch_bounds__(256) void bn_apply_kernel(const u16* __restrict__ z,
    const float* __restrict__ stats, const float* __restrict__ g, const float* __restrict__ b,
    u16* __restrict__ out)
{
    int idx = blockIdx.x*256 + threadIdx.x;
    int c = idx & (DD-1);
    float m   = stats[c]*(1.0f/NTOK);
    float var = stats[DD+c]*(1.0f/NTOK) - m*m;
    float vv  = (b2f(z[idx])-m)*rsqrtf(var+EPSF)*g[c] + b[c];
    out[idx]  = f2b(vv*sigmoidf_(vv));
}

extern "C" void kernel_launch(void* const* d_in, const int* in_sizes, int n_in,
                              void* d_out, int out_size, void* d_ws, size_t ws_size,
                              hipStream_t stream)
{
    const float* x       = (const float*)d_in[0];
    const float* pos_emb = (const float*)d_in[1];
    const float* ln1_g=(const float*)d_in[2],  *ln1_b=(const float*)d_in[3];
    const float* ln2_g=(const float*)d_in[4],  *ln2_b=(const float*)d_in[5];
    const float* ln3_g=(const float*)d_in[6],  *ln3_b=(const float*)d_in[7];
    const float* ln4_g=(const float*)d_in[8],  *ln4_b=(const float*)d_in[9];
    const float* ln5_g=(const float*)d_in[10], *ln5_b=(const float*)d_in[11];
    const float* ff1_w1=(const float*)d_in[12], *ff1_b1=(const float*)d_in[13];
    const float* ff1_w2=(const float*)d_in[14], *ff1_b2=(const float*)d_in[15];
    const float* wq=(const float*)d_in[16], *bq=(const float*)d_in[17];
    const float* wk=(const float*)d_in[18], *bk=(const float*)d_in[19];
    const float* wv=(const float*)d_in[20], *bv=(const float*)d_in[21];
    const float* wp=(const float*)d_in[22];
    const float* wo=(const float*)d_in[23], *bo=(const float*)d_in[24];
    const float* pos_u=(const float*)d_in[25], *pos_v=(const float*)d_in[26];
    const float* pw1_w=(const float*)d_in[27], *pw1_b=(const float*)d_in[28];
    const float* dw_w=(const float*)d_in[29],  *dw_b=(const float*)d_in[30];
    const float* bn_g=(const float*)d_in[31],  *bn_b=(const float*)d_in[32];
    const float* pw2_w=(const float*)d_in[33], *pw2_b=(const float*)d_in[34];
    const float* ff2_w1=(const float*)d_in[35], *ff2_b1=(const float*)d_in[36];
    const float* ff2_w2=(const float*)d_in[37], *ff2_b2=(const float*)d_in[38];

    char* W = (char*)d_ws;
    float* h    = (float*)(W);                  // 8 MB f32
    u16*  xn    = (u16*) (W + (size_t) 8*MB);   // 4 MB (ln out / attn out)
    u16*  wall  = (u16*) (W + (size_t)12*MB);   // 16 MB prepped weights
    u16*  qub   = (u16*) (W + (size_t)28*MB);   // qub/qvb/kb/vt contiguous (OMODE5)
    u16*  qvb   = (u16*) (W + (size_t)32*MB);
    u16*  kb    = (u16*) (W + (size_t)36*MB);
    u16*  vt    = (u16*) (W + (size_t)40*MB);   // (B,H,DK,T)
    u16*  pproj = (u16*) (W + (size_t)44*MB);   // 2048x512
    char* big   = W + (size_t)48*MB;            // shared region
    u16*  ffh   = (u16*)big;                    // 16 MB FFN hidden
    unsigned int* t2i = (unsigned int*)big;     // 8 MB conv (a,g) pairs
    u16*  t3u   = (u16*)(big + (size_t)8*MB);   // 4 MB dwconv out (bf16)
    float* stats= (float*)(W + (size_t)112*MB); // 4 KB (atomics, zeroed per call)
    float* wt   = stats + 4096;                 // (31,512) f32
    float* bqkv = wt + 15872;                   // 1536 f32

    u16* ff1w1T = wall;
    u16* ff1w2T = wall + 1048576;
    u16* wqT    = wall + 2097152;   // wq/wk/wv contiguous -> N=1536 merged GEMM
    u16* wkT    = wall + 2359296;
    u16* wvT    = wall + 2621440;
    u16* wpT    = wall + 2883584;
    u16* woT    = wall + 3145728;
    u16* ff2w1T = wall + 3407872;
    u16* ff2w2T = wall + 4456448;
    u16* pw1b   = wall + 5505024;
    u16* pw2b   = wall + 6029312;
    u16* posb   = wall + 6291456;

    dim3 blk(256);

    // ---------------- weight prep (2 launches) ----------------
    Prep9 P;
    P.s[0]=ff1_w1; P.d[0]=ff1w1T; P.R[0]=512;  P.C[0]=2048;
    P.s[1]=ff1_w2; P.d[1]=ff1w2T; P.R[1]=2048; P.C[1]=512;
    P.s[2]=wq;     P.d[2]=wqT;    P.R[2]=512;  P.C[2]=512;
    P.s[3]=wk;     P.d[3]=wkT;    P.R[3]=512;  P.C[3]=512;
    P.s[4]=wv;     P.d[4]=wvT;    P.R[4]=512;  P.C[4]=512;
    P.s[5]=wp;     P.d[5]=wpT;    P.R[5]=512;  P.C[5]=512;
    P.s[6]=wo;     P.d[6]=woT;    P.R[6]=512;  P.C[6]=512;
    P.s[7]=ff2_w1; P.d[7]=ff2w1T; P.R[7]=512;  P.C[7]=2048;
    P.s[8]=ff2_w2; P.d[8]=ff2w2T; P.R[8]=2048; P.C[8]=512;
    int tc[9] = {1024,1024,256,256,256,256,256,1024,1024};
    P.t0[0]=0; for (int e=0;e<9;e++) P.t0[e+1]=P.t0[e]+tc[e];
    prep_transpose<<<dim3(5376), blk, 0, stream>>>(P);
    prep_convert<<<dim3(7236), blk, 0, stream>>>(pw1_w, pw2_w, pos_emb, dw_w,
                                                 bq, bk, bv,
                                                 pw1b, pw2b, posb, wt, bqkv);

    // ---------------- FFN1: h = x + 0.5*ffn(ln1(x)) ----------------
    ln_kernel<1><<<dim3(NTOK/4), blk, 0, stream>>>(x, ln1_g, ln1_b, xn);
    bgemm128<1><<<dim3(16,32), blk, 0, stream>>>(xn,512, ff1w1T,512,
        ffh,2048, 512, ff1_b1,1,1.f, nullptr,nullptr,nullptr);
    bgemm64k<<<dim3(8,64), blk, 0, stream>>>(ffh,2048, ff1w2T,2048,
        h,512, 2048, ff1_b2,0.5f, x);

    // ---------------- Attention: h = h + attn(ln2(h)) ----------------
    ln_kernel<1><<<dim3(NTOK/4), blk, 0, stream>>>(h, ln2_g, ln2_b, xn);
    bgemm128<5><<<dim3(12,32), blk, 0, stream>>>(xn,512, wqT,512,
        qub,512, 512, bqkv,0,1.f, nullptr,pos_u,pos_v);
    bgemm64<1><<<dim3(8,32), blk, 0, stream>>>(posb,512, wpT,512,
        pproj,512, 512, nullptr,1.f, nullptr);

    attn_fused<<<dim3(16,32), blk, 0, stream>>>(qub, qvb, kb, vt, pproj, xn);

    bgemm64<0><<<dim3(8,64), blk, 0, stream>>>(xn,512, woT,512,
        h,512, 512, bo,1.f, h);

    // ---------------- Conv module ----------------
    ln_kernel<1><<<dim3(NTOK/4), blk, 0, stream>>>(h, ln3_g, ln3_b, xn);
    bgemm128<6><<<dim3(8,32), blk, 0, stream>>>(xn,512, pw1b,512,
        t2i,1024, 512, pw1_b,0,1.f, nullptr,nullptr,nullptr);
    dwconv_kernel<<<dim3(2,512), blk, 0, stream>>>(t2i, wt, dw_b, t3u);
    hipMemsetAsync(stats, 0, 4096, stream);
    bn_reduce2<<<dim3(256), blk, 0, stream>>>(t3u, stats);
    bn_apply_kernel<<<dim3(NTOK*DD/256), blk, 0, stream>>>(t3u, stats, bn_g, bn_b, xn);
    bgemm64<0><<<dim3(8,64), blk, 0, stream>>>(xn,512, pw2b,512,
        h,512, 512, pw2_b,1.f, h);

    // ---------------- FFN2 ----------------
    ln_kernel<1><<<dim3(NTOK/4), blk, 0, stream>>>(h, ln4_g, ln4_b, xn);
    bgemm128<1><<<dim3(16,32), blk, 0, stream>>>(xn,512, ff2w1T,512,
        ffh,2048, 512, ff2_b1,1,1.f, nullptr,nullptr,nullptr);
    bgemm64k<<<dim3(8,64), blk, 0, stream>>>(ffh,2048, ff2w2T,2048,
        h,512, 2048, ff2_b2,0.5f, h);

    // ---------------- Final LN ----------------
    ln_kernel<0><<<dim3(NTOK/4), blk, 0, stream>>>(h, ln5_g, ln5_b, (float*)d_out);
}

// Round 9
// 279.124 us; speedup vs baseline: 1.6310x; 1.0440x over previous
//
#include <hip/hip_runtime.h>
#include <math.h>

#define TT   1024
#define BBZ  4
#define DD   512
#define DFF_ 2048
#define HH   8
#define DKK  64
#define NTOK 4096
#define EPSF 1e-5f
#define MB   1048576
// 0.125 * log2(e): scores produced directly in log2 domain
#define QSCALE 0.18033688011112042f
#define M0OFF  24.0f

typedef unsigned short u16;
typedef __attribute__((ext_vector_type(8))) short s8v;    // 8 bf16 (4 VGPRs)
typedef __attribute__((ext_vector_type(4))) float f32x4;
typedef __attribute__((ext_vector_type(4))) unsigned short us4;

__device__ __forceinline__ float b2f(u16 v){
    union { unsigned int u; float f; } x; x.u = ((unsigned int)v) << 16; return x.f;
}
__device__ __forceinline__ u16 f2b(float f){
    union { float f; unsigned int u; } x; x.f = f;
    unsigned int r = x.u + 0x7fffu + ((x.u >> 16) & 1u);
    return (u16)(r >> 16);
}
__device__ __forceinline__ float sigmoidf_(float x){ return 1.0f/(1.0f+__expf(-x)); }

__device__ __forceinline__ void gld16(const u16* g, u16* l){
    __builtin_amdgcn_global_load_lds(
        (const __attribute__((address_space(1))) unsigned int*)g,
        (__attribute__((address_space(3))) unsigned int*)l, 16, 0, 0);
}

// ================= 128x128-tile MFMA GEMM (wide N) =================
// C = epilogue(A @ B^T_view), A:(M,K) bf16 row-major, B:(N,K) bf16 row-major.
// OMODE 0: f32 out (+bias, act, *alpha, +resid)   1: bf16 out (+bias, act)
// OMODE 5: merged QKV epilogue (q scaled by QSCALE, dual +posu/+posv).
// OMODE 6: interleaved GLU-pair bf16 store: (row, d, a/g) for dwconv.
template<int OMODE>
__global__ __launch_bounds__(256) void bgemm128(
    const u16* __restrict__ A, int lda,
    const u16* __restrict__ B, int ldb,
    void* __restrict__ Cv, int ldc, int K,
    const float* __restrict__ bias, int act, float alpha,
    const float* __restrict__ resid,
    const float* __restrict__ posu, const float* __restrict__ posv)
{
    int n0 = blockIdx.x * 128;
    int m0 = blockIdx.y * 128;

    __shared__ u16 As[128*64];
    __shared__ u16 Bs[128*64];

    int t = threadIdx.x;
    int w = t >> 6, l = t & 63;
    int lrow = l >> 3, lslot = l & 7;
    int kswz = (lslot ^ lrow) * 8;
    int wm = w >> 1, wn = w & 1;
    int lr = l & 15, lk = l >> 4;

    f32x4 acc[4][4] = {};

    for (int k0 = 0; k0 < K; k0 += 64){
        #pragma unroll
        for (int it = 0; it < 4; ++it){
            int rb = it*32 + w*8;
            gld16(A + (size_t)(m0 + rb + lrow)*lda + k0 + kswz, &As[rb*64]);
            gld16(B + (size_t)(n0 + rb + lrow)*ldb + k0 + kswz, &Bs[rb*64]);
        }
        __syncthreads();

        s8v af[2][4], bf[2][4];
        #pragma unroll
        for (int kh = 0; kh < 2; ++kh){
            int sl = (kh*4 + lk) ^ (lr & 7);
            #pragma unroll
            for (int mi = 0; mi < 4; ++mi)
                af[kh][mi] = *(const s8v*)&As[(wm*64 + mi*16 + lr)*64 + sl*8];
            #pragma unroll
            for (int ni = 0; ni < 4; ++ni)
                bf[kh][ni] = *(const s8v*)&Bs[(wn*64 + ni*16 + lr)*64 + sl*8];
        }
        #pragma unroll
        for (int kh = 0; kh < 2; ++kh)
            #pragma unroll
            for (int mi = 0; mi < 4; ++mi)
                #pragma unroll
                for (int ni = 0; ni < 4; ++ni)
                    acc[mi][ni] = __builtin_amdgcn_mfma_f32_16x16x32_bf16(
                        af[kh][mi], bf[kh][ni], acc[mi][ni], 0, 0, 0);
        __syncthreads();
    }

    #pragma unroll
    for (int mi = 0; mi < 4; ++mi){
        #pragma unroll
        for (int ni = 0; ni < 4; ++ni){
            int gn = n0 + wn*64 + ni*16 + lr;
            float bval = bias ? bias[gn] : 0.0f;
            #pragma unroll
            for (int r = 0; r < 4; ++r){
                int gm = m0 + wm*64 + mi*16 + lk*4 + r;
                float vv = acc[mi][ni][r] + bval;
                if (act) vv = vv * sigmoidf_(vv);
                if (OMODE == 0){
                    vv *= alpha;
                    if (resid) vv += resid[(size_t)gm*ldc + gn];
                    ((float*)Cv)[(size_t)gm*ldc + gn] = vv;
                } else if (OMODE == 1){
                    ((u16*)Cv)[(size_t)gm*ldc + gn] = f2b(vv);
                } else if (OMODE == 5){ // merged QKV
                    u16* base = (u16*)Cv;
                    if (gn < 512){
                        size_t idx = (size_t)gm*512 + gn;
                        base[idx]              = f2b((vv + posu[gn])*QSCALE);
                        base[idx + (2u<<20)]   = f2b((vv + posv[gn])*QSCALE);
                    } else if (gn < 1024){
                        base[(4u<<20) + (size_t)gm*512 + (gn-512)] = f2b(vv);
                    } else {
                        int gnp = gn - 1024;
                        int bb = gm >> 10, tt2 = gm & 1023;
                        size_t idx = (((size_t)(bb*8 + (gnp>>6)))*64 + (gnp&63))*1024 + tt2;
                        base[(6u<<20) + idx] = f2b(vv);
                    }
                } else { // 6: interleaved (a,g) bf16 pairs for dwconv
                    u16* base = (u16*)Cv;
                    size_t idx = (gn < 512)
                        ? ((size_t)gm*512 + gn)*2
                        : ((size_t)gm*512 + (gn-512))*2 + 1;
                    base[idx] = f2b(vv);
                }
            }
        }
    }
}

// ================= 64x64-tile MFMA GEMM, BK=64 (N=512, K=512 shapes) ========
// OMODE 0: f32 out (+bias, *alpha, +resid)   1: bf16 out (+bias)
template<int OMODE>
__global__ __launch_bounds__(256) void bgemm64(
    const u16* __restrict__ A, int lda,
    const u16* __restrict__ B, int ldb,
    void* __restrict__ Cv, int ldc, int K,
    const float* __restrict__ bias, float alpha,
    const float* __restrict__ resid)
{
    int n0 = blockIdx.x * 64;
    int m0 = blockIdx.y * 64;

    __shared__ u16 As[64*64];
    __shared__ u16 Bs[64*64];

    int t = threadIdx.x;
    int w = t >> 6, l = t & 63;
    int lrow = l >> 3, lslot = l & 7;
    int kswz = (lslot ^ lrow) * 8;
    int wm = w >> 1, wn = w & 1;
    int lr = l & 15, lk = l >> 4;

    f32x4 acc[2][2] = {};

    for (int k0 = 0; k0 < K; k0 += 64){
        #pragma unroll
        for (int it = 0; it < 2; ++it){
            int rb = it*32 + w*8;
            gld16(A + (size_t)(m0 + rb + lrow)*lda + k0 + kswz, &As[rb*64]);
            gld16(B + (size_t)(n0 + rb + lrow)*ldb + k0 + kswz, &Bs[rb*64]);
        }
        __syncthreads();

        s8v af[2][2], bf[2][2];
        #pragma unroll
        for (int kh = 0; kh < 2; ++kh){
            int sl = (kh*4 + lk) ^ (lr & 7);
            #pragma unroll
            for (int mi = 0; mi < 2; ++mi)
                af[kh][mi] = *(const s8v*)&As[(wm*32 + mi*16 + lr)*64 + sl*8];
            #pragma unroll
            for (int ni = 0; ni < 2; ++ni)
                bf[kh][ni] = *(const s8v*)&Bs[(wn*32 + ni*16 + lr)*64 + sl*8];
        }
        #pragma unroll
        for (int kh = 0; kh < 2; ++kh)
            #pragma unroll
            for (int mi = 0; mi < 2; ++mi)
                #pragma unroll
                for (int ni = 0; ni < 2; ++ni)
                    acc[mi][ni] = __builtin_amdgcn_mfma_f32_16x16x32_bf16(
                        af[kh][mi], bf[kh][ni], acc[mi][ni], 0, 0, 0);
        __syncthreads();
    }

    #pragma unroll
    for (int mi = 0; mi < 2; ++mi){
        #pragma unroll
        for (int ni = 0; ni < 2; ++ni){
            int gn = n0 + wn*32 + ni*16 + lr;
            float bval = bias ? bias[gn] : 0.0f;
            #pragma unroll
            for (int r = 0; r < 4; ++r){
                int gm = m0 + wm*32 + mi*16 + lk*4 + r;
                float vv = acc[mi][ni][r] + bval;
                if (OMODE == 0){
                    vv *= alpha;
                    if (resid) vv += resid[(size_t)gm*ldc + gn];
                    ((float*)Cv)[(size_t)gm*ldc + gn] = vv;
                } else {
                    ((u16*)Cv)[(size_t)gm*ldc + gn] = f2b(vv);
                }
            }
        }
    }
}

// ================= 64x64-tile MFMA GEMM, BK=128 (K=2048 shapes) ==============
// f32 out (+bias, *alpha, +resid). 16-slot XOR swizzle, half the barriers.
__global__ __launch_bounds__(256) void bgemm64k(
    const u16* __restrict__ A, int lda,
    const u16* __restrict__ B, int ldb,
    float* __restrict__ C, int ldc, int K,
    const float* __restrict__ bias, float alpha,
    const float* __restrict__ resid)
{
    int n0 = blockIdx.x * 64;
    int m0 = blockIdx.y * 64;

    __shared__ u16 As[64*128];    // 16 KB
    __shared__ u16 Bs[64*128];    // 16 KB

    int t = threadIdx.x;
    int w = t >> 6, l = t & 63;
    int r4 = l >> 4;
    int s16 = l & 15;
    int kswz = (s16 ^ (w*4 + r4)) * 8;
    int wm = w >> 1, wn = w & 1;
    int lr = l & 15, lk = l >> 4;

    f32x4 acc[2][2] = {};

    for (int k0 = 0; k0 < K; k0 += 128){
        #pragma unroll
        for (int cb = 0; cb < 4; ++cb){
            int rowu = cb*16 + w*4;
            gld16(A + (size_t)(m0 + rowu + r4)*lda + k0 + kswz, &As[rowu*128]);
            gld16(B + (size_t)(n0 + rowu + r4)*ldb + k0 + kswz, &Bs[rowu*128]);
        }
        __syncthreads();

        #pragma unroll
        for (int kh = 0; kh < 4; ++kh){
            int sl = ((kh*4 + lk) ^ lr) * 8;
            s8v af[2], bf[2];
            #pragma unroll
            for (int mi = 0; mi < 2; ++mi)
                af[mi] = *(const s8v*)&As[(wm*32 + mi*16 + lr)*128 + sl];
            #pragma unroll
            for (int ni = 0; ni < 2; ++ni)
                bf[ni] = *(const s8v*)&Bs[(wn*32 + ni*16 + lr)*128 + sl];
            #pragma unroll
            for (int mi = 0; mi < 2; ++mi)
                #pragma unroll
                for (int ni = 0; ni < 2; ++ni)
                    acc[mi][ni] = __builtin_amdgcn_mfma_f32_16x16x32_bf16(
                        af[mi], bf[ni], acc[mi][ni], 0, 0, 0);
        }
        __syncthreads();
    }

    #pragma unroll
    for (int mi = 0; mi < 2; ++mi){
        #pragma unroll
        for (int ni = 0; ni < 2; ++ni){
            int gn = n0 + wn*32 + ni*16 + lr;
            float bval = bias ? bias[gn] : 0.0f;
            #pragma unroll
            for (int r = 0; r < 4; ++r){
                int gm = m0 + wm*32 + mi*16 + lk*4 + r;
                float vv = (acc[mi][ni][r] + bval) * alpha;
                if (resid) vv += resid[(size_t)gm*ldc + gn];
                C[(size_t)gm*ldc + gn] = vv;
            }
        }
    }
}

// ================= fused rel-pos flash attention =================
// grid (16, 32). Fixed-offset base-2 softmax: q pre-scaled by 0.125*log2(e),
// p = exp2(s2 - 24) exactly (softmax is shift/base invariant); per-lane L
// partials reduced ONCE after the j-loop. No max tracking, no o-rescale,
// no per-iter shuffles. K/V double-buffered, P 3-chunk ring, 1 barrier/iter.
__global__ __launch_bounds__(256) void attn_fused(
    const u16* __restrict__ qub, const u16* __restrict__ qvb,
    const u16* __restrict__ kb,  const u16* __restrict__ vt,
    const u16* __restrict__ pp,  u16* __restrict__ out)
{
    int z = blockIdx.y;
    int b = z >> 3, hh = z & 7;
    int i0 = blockIdx.x * 64;

    __shared__ u16 Kb2[2][64*64];     // 16 KB
    __shared__ u16 Vb2[2][64*64];     // 16 KB
    __shared__ u16 Pring[3][64*64];   // 24 KB
    __shared__ u16 PT[64*64];         //  8 KB (P-tilde; qu staging in prologue)
    __shared__ float Band[64*64];     // 16 KB (band; qv staging in prologue)

    int t = threadIdx.x;
    int w = t >> 6, l = t & 63;
    int lrow = l >> 3, lslot = l & 7;
    int kswz = (lslot ^ lrow) * 8;
    int lr = l & 15, lk = l >> 4;

    // ---- prologue: qu -> PT, qv -> Band (as u16), frags to regs ----
    #pragma unroll
    for (int it = 0; it < 2; ++it){
        int rb = it*32 + w*8;
        gld16(qub + (size_t)(b*TT + i0 + rb + lrow)*DD + hh*64 + kswz, &PT[rb*64]);
        gld16(qvb + (size_t)(b*TT + i0 + rb + lrow)*DD + hh*64 + kswz,
              (u16*)Band + rb*64);
    }
    __syncthreads();
    s8v af_u[2], af_v[2];
    #pragma unroll
    for (int kh = 0; kh < 2; ++kh){
        int sl = (kh*4 + lk) ^ (lr & 7);
        af_u[kh] = *(const s8v*)&PT[(w*16 + lr)*64 + sl*8];
        af_v[kh] = *(const s8v*)((const u16*)Band + (w*16 + lr)*64 + sl*8);
    }
    // stage K_0 -> Kb2[0], V_0 -> Vb2[0], P chunks 0,1 -> ring
    #pragma unroll
    for (int it = 0; it < 2; ++it){
        int rb = it*32 + w*8;
        gld16(kb + (size_t)(b*TT +        rb + lrow)*DD + hh*64 + kswz, &Kb2[0][rb*64]);
        gld16(vt + ((size_t)z*64 + rb + lrow)*TT +                kswz, &Vb2[0][rb*64]);
        gld16(pp + (size_t)(960  - i0 +   rb + lrow)*DD + hh*64 + kswz, &Pring[0][rb*64]);
        gld16(pp + (size_t)(1024 - i0 +   rb + lrow)*DD + hh*64 + kswz, &Pring[1][rb*64]);
    }

    f32x4 o_[4] = {};
    float Lp[4] = {0.f, 0.f, 0.f, 0.f};   // per-lane partial denominators

    int nbase = 3 - w;   // band-intersecting P sub-tiles: nn in [3-w, 7-w]
    int s0 = 0, s1 = 1, s2 = 2;

    for (int jt = 0; jt < 16; ++jt){
        int cur = jt & 1;
        __syncthreads();  // all staged loads for THIS iter have landed

        // issue next-iter staging (full-iteration landing window)
        if (jt < 15){
            #pragma unroll
            for (int it = 0; it < 2; ++it){
                int rb = it*32 + w*8;
                gld16(kb + (size_t)(b*TT + (jt+1)*64 + rb + lrow)*DD + hh*64 + kswz,
                      &Kb2[cur^1][rb*64]);
                gld16(vt + ((size_t)z*64 + rb + lrow)*TT + (jt+1)*64 + kswz,
                      &Vb2[cur^1][rb*64]);
                gld16(pp + (size_t)(960 + (jt+2)*64 - i0 + rb + lrow)*DD + hh*64 + kswz,
                      &Pring[s2][rb*64]);
            }
        }

        // ---- S_ac (16x64) and band G (16x80) per wave ----
        f32x4 sac[4] = {};
        f32x4 g[5] = {};
        __builtin_amdgcn_s_setprio(1);
        #pragma unroll
        for (int kh = 0; kh < 2; ++kh){
            int sl = (kh*4 + lk) ^ (lr & 7);
            #pragma unroll
            for (int n = 0; n < 4; ++n){
                s8v bK = *(const s8v*)&Kb2[cur][(n*16 + lr)*64 + sl*8];
                sac[n] = __builtin_amdgcn_mfma_f32_16x16x32_bf16(af_u[kh], bK, sac[n], 0,0,0);
            }
            #pragma unroll
            for (int n = 0; n < 5; ++n){
                int nn = nbase + n;
                const u16* pc = (nn & 4) ? &Pring[s1][0] : &Pring[s0][0];
                s8v bP = *(const s8v*)&pc[(((nn&3)*16) + lr)*64 + sl*8];
                g[n] = __builtin_amdgcn_mfma_f32_16x16x32_bf16(af_v[kh], bP, g[n], 0,0,0);
            }
        }
        __builtin_amdgcn_s_setprio(0);
        // band write (f32, rotate swizzle, wave-local rows -> no barrier)
        #pragma unroll
        for (int n = 0; n < 5; ++n){
            int nn = nbase + n;
            #pragma unroll
            for (int r = 0; r < 4; ++r){
                int ii = w*16 + lk*4 + r;
                int jj = nn*16 + lr - 63 + ii;
                if (jj >= 0 && jj < 64)
                    Band[ii*64 + ((jj + 4*ii) & 63)] = g[n][r];
            }
        }

        // ---- combine band + fixed-offset exp2 (wave-local, no shuffles) ----
        float p_[4][4];
        #pragma unroll
        for (int r = 0; r < 4; ++r){
            int ii = w*16 + lk*4 + r;
            float rs = 0.0f;
            #pragma unroll
            for (int n = 0; n < 4; ++n){
                int jj = n*16 + lr;
                float s2 = sac[n][r] + Band[ii*64 + ((jj + 4*ii) & 63)];
                float pv = __builtin_amdgcn_exp2f(s2 - M0OFF);
                p_[n][r] = pv; rs += pv;
            }
            Lp[r] += rs;
        }

        // write P-tilde (swizzled bf16, wave-local rows; read by same wave only)
        #pragma unroll
        for (int n = 0; n < 4; ++n)
            #pragma unroll
            for (int r = 0; r < 4; ++r){
                int ii  = w*16 + lk*4 + r;
                int col = n*16 + lr;
                int sl  = (col>>3) ^ (ii&7);
                PT[ii*64 + sl*8 + (col&7)] = f2b(p_[n][r]);
            }

        // ---- PV (V_jt landed at this iter's top barrier) ----
        __builtin_amdgcn_s_setprio(1);
        #pragma unroll
        for (int kh = 0; kh < 2; ++kh){
            int sl = (kh*4 + lk) ^ (lr & 7);
            s8v ap = *(const s8v*)&PT[(w*16 + lr)*64 + sl*8];
            #pragma unroll
            for (int n = 0; n < 4; ++n){
                s8v bV = *(const s8v*)&Vb2[cur][(n*16 + lr)*64 + sl*8];
                o_[n] = __builtin_amdgcn_mfma_f32_16x16x32_bf16(ap, bV, o_[n], 0,0,0);
            }
        }
        __builtin_amdgcn_s_setprio(0);
        int tmp = s0; s0 = s1; s1 = s2; s2 = tmp;
    }

    // ---- one-time L reduction across the 16-lane col group ----
    float Lr[4];
    #pragma unroll
    for (int r = 0; r < 4; ++r){
        float Lv = Lp[r];
        #pragma unroll
        for (int msk = 1; msk < 16; msk <<= 1) Lv += __shfl_xor(Lv, msk);
        Lr[r] = 1.0f / Lv;
    }

    #pragma unroll
    for (int n = 0; n < 4; ++n)
        #pragma unroll
        for (int r = 0; r < 4; ++r){
            int i  = i0 + w*16 + lk*4 + r;
            int dk = n*16 + lr;
            out[(size_t)(b*TT + i)*DD + hh*64 + dk] = f2b(o_[n][r] * Lr[r]);
        }
}

// ================= LayerNorm: wave per row, shuffle reduce, no barriers =====
template<int OB>
__global__ __launch_bounds__(256) void ln_kernel(const float* __restrict__ in,
    const float* __restrict__ g, const float* __restrict__ b, void* __restrict__ outv)
{
    int w = threadIdx.x >> 6, l = threadIdx.x & 63;
    int row = blockIdx.x*4 + w;
    const float4* xr = (const float4*)(in + (size_t)row*DD);
    float4 v0 = xr[l], v1 = xr[64 + l];
    float s = v0.x+v0.y+v0.z+v0.w + v1.x+v1.y+v1.z+v1.w;
    float q = v0.x*v0.x+v0.y*v0.y+v0.z*v0.z+v0.w*v0.w
            + v1.x*v1.x+v1.y*v1.y+v1.z*v1.z+v1.w*v1.w;
    #pragma unroll
    for (int msk = 1; msk < 64; msk <<= 1){
        s += __shfl_xor(s, msk);
        q += __shfl_xor(q, msk);
    }
    float mean = s*(1.0f/DD);
    float var  = q*(1.0f/DD) - mean*mean;
    float inv  = rsqrtf(var+EPSF);
    float4 g0 = ((const float4*)g)[l], g1 = ((const float4*)g)[64+l];
    float4 b0 = ((const float4*)b)[l], b1 = ((const float4*)b)[64+l];
    float y0x=(v0.x-mean)*inv*g0.x+b0.x, y0y=(v0.y-mean)*inv*g0.y+b0.y;
    float y0z=(v0.z-mean)*inv*g0.z+b0.z, y0w=(v0.w-mean)*inv*g0.w+b0.w;
    float y1x=(v1.x-mean)*inv*g1.x+b1.x, y1y=(v1.y-mean)*inv*g1.y+b1.y;
    float y1z=(v1.z-mean)*inv*g1.z+b1.z, y1w=(v1.w-mean)*inv*g1.w+b1.w;
    if (OB){
        us4 o0 = { f2b(y0x), f2b(y0y), f2b(y0z), f2b(y0w) };
        us4 o1 = { f2b(y1x), f2b(y1y), f2b(y1z), f2b(y1w) };
        us4* op = (us4*)((u16*)outv + (size_t)row*DD);
        op[l] = o0; op[64+l] = o1;
    } else {
        float4 o0 = { y0x, y0y, y0z, y0w };
        float4 o1 = { y1x, y1y, y1z, y1w };
        float4* op = (float4*)((float*)outv + (size_t)row*DD);
        op[l] = o0; op[64+l] = o1;
    }
}

// ================= consolidated weight prep =================
struct Prep9 {
    const float* s[9];
    u16* d[9];
    int R[9], C[9];
    int t0[10];
};

__global__ __launch_bounds__(256) void prep_transpose(Prep9 P)
{
    __shared__ float tile[32][33];
    int bid = blockIdx.x;
    int j = 0;
    #pragma unroll
    for (int e=1; e<9; e++) if (bid >= P.t0[e]) j = e;
    int lb = bid - P.t0[j];
    int nx = P.C[j] >> 5;
    int c0 = (lb % nx) << 5;
    int r0 = (lb / nx) << 5;
    const float* in = P.s[j];
    u16* out = P.d[j];
    int R = P.R[j], C = P.C[j];
    int tx = threadIdx.x & 31, ty = threadIdx.x >> 5;
    #pragma unroll
    for (int i=0;i<4;i++){
        int rr = ty + i*8;
        tile[rr][tx] = in[(size_t)(r0+rr)*C + c0+tx];
    }
    __syncthreads();
    #pragma unroll
    for (int i=0;i<4;i++){
        int cc = ty + i*8;
        out[(size_t)(c0+cc)*R + r0+tx] = f2b(tile[tx][cc]);
    }
}

__global__ __launch_bounds__(256) void prep_convert(
    const float* __restrict__ pw1_w, const float* __restrict__ pw2_w,
    const float* __restrict__ pos_emb, const float* __restrict__ dw_w,
    const float* __restrict__ bq, const float* __restrict__ bk,
    const float* __restrict__ bv,
    u16* __restrict__ pw1b, u16* __restrict__ pw2b,
    u16* __restrict__ posb, float* __restrict__ wt, float* __restrict__ bqkv)
{
    int i = blockIdx.x*256 + threadIdx.x;
    if (i < 524288) { pw1b[i] = f2b(pw1_w[i]); return; }
    i -= 524288;
    if (i < 262144) { pw2b[i] = f2b(pw2_w[i]); return; }
    i -= 262144;
    if (i < 1048576) { posb[i] = (i < 2047*512) ? f2b(pos_emb[i]) : (u16)0; return; }
    i -= 1048576;
    if (i < 15872) { int kk = i >> 9, d = i & 511; wt[i] = dw_w[d*31+kk]; return; }
    i -= 15872;
    if (i < 1536) bqkv[i] = (i < 512) ? bq[i] : (i < 1024 ? bk[i-512] : bv[i-1024]);
}

// ================= conv-module =================
// depthwise conv K=31, GLU fused: reads interleaved (a,g) bf16 pairs as u32
__global__ __launch_bounds__(256) void dwconv_kernel(const unsigned int* __restrict__ t2i,
    const float* __restrict__ wt, const float* __restrict__ bias, u16* __restrict__ z)
{
    int d  = blockIdx.x*256 + threadIdx.x;   // gridDim.x = 2
    int c  = blockIdx.y;                     // 0..511
    int b  = c >> 7;
    int t0 = (c & 127) << 3;
    const unsigned int* pa = t2i + (size_t)b*TT*512 + d;
    float wv[31];
    #pragma unroll
    for (int kk=0;kk<31;kk++) wv[kk] = wt[kk*512 + d];
    float xv[38];
    #pragma unroll
    for (int e=0;e<38;e++){
        int tp = t0 - 15 + e;
        if (tp >= 0 && tp < TT){
            unsigned int pv = pa[(size_t)tp*512];
            float a  = b2f((u16)(pv & 0xffffu));
            float gg = b2f((u16)(pv >> 16));
            xv[e] = a * sigmoidf_(gg);
        } else xv[e] = 0.0f;
    }
    float bsv = bias[d];
    #pragma unroll
    for (int j=0;j<8;j++){
        float sum = bsv;
        #pragma unroll
        for (int kk=0;kk<31;kk++) sum = fmaf(xv[j+kk], wv[kk], sum);
        z[(size_t)(b*TT+t0+j)*DD + d] = f2b(sum);
    }
}

// BN stats: coalesced row-block reduce + f32 atomics into zeroed stats[1024]
__global__ __launch_bounds__(256) void bn_reduce2(const u16* __restrict__ z,
    float* __restrict__ stats)
{
    int bi = blockIdx.x;          // 256 blocks x 16 rows
    int t  = threadIdx.x;
    float s0=0.f,q0=0.f,s1=0.f,q1=0.f;
    #pragma unroll
    for (int r=0;r<16;r++){
        size_t row = (size_t)(bi*16 + r)*DD;
        float v0 = b2f(z[row + t]);
        float v1 = b2f(z[row + t + 256]);
        s0 += v0; q0 += v0*v0;
        s1 += v1; q1 += v1*v1;
    }
    atomicAdd(&stats[t],        s0);
    atomicAdd(&stats[512 + t],  q0);
    atomicAdd(&stats[t + 256],      s1);
    atomicAdd(&stats[512 + t + 256], q1);
}

__global__ __launch_bounds__(256) void bn_apply_kernel(const u16* __restrict__ z,
    const float* __restrict__ stats, const float* __restrict__ g, const float* __restrict__ b,
    u16* __restrict__ out)
{
    int idx = blockIdx.x*256 + threadIdx.x;
    int c = idx & (DD-1);
    float m   = stats[c]*(1.0f/NTOK);
    float var = stats[DD+c]*(1.0f/NTOK) - m*m;
    float vv  = (b2f(z[idx])-m)*rsqrtf(var+EPSF)*g[c] + b[c];
    out[idx]  = f2b(vv*sigmoidf_(vv));
}

extern "C" void kernel_launch(void* const* d_in, const int* in_sizes, int n_in,
                              void* d_out, int out_size, void* d_ws, size_t ws_size,
                              hipStream_t stream)
{
    const float* x       = (const float*)d_in[0];
    const float* pos_emb = (const float*)d_in[1];
    const float* ln1_g=(const float*)d_in[2],  *ln1_b=(const float*)d_in[3];
    const float* ln2_g=(const float*)d_in[4],  *ln2_b=(const float*)d_in[5];
    const float* ln3_g=(const float*)d_in[6],  *ln3_b=(const float*)d_in[7];
    const float* ln4_g=(const float*)d_in[8],  *ln4_b=(const float*)d_in[9];
    const float* ln5_g=(const float*)d_in[10], *ln5_b=(const float*)d_in[11];
    const float* ff1_w1=(const float*)d_in[12], *ff1_b1=(const float*)d_in[13];
    const float* ff1_w2=(const float*)d_in[14], *ff1_b2=(const float*)d_in[15];
    const float* wq=(const float*)d_in[16], *bq=(const float*)d_in[17];
    const float* wk=(const float*)d_in[18], *bk=(const float*)d_in[19];
    const float* wv=(const float*)d_in[20], *bv=(const float*)d_in[21];
    const float* wp=(const float*)d_in[22];
    const float* wo=(const float*)d_in[23], *bo=(const float*)d_in[24];
    const float* pos_u=(const float*)d_in[25], *pos_v=(const float*)d_in[26];
    const float* pw1_w=(const float*)d_in[27], *pw1_b=(const float*)d_in[28];
    const float* dw_w=(const float*)d_in[29],  *dw_b=(const float*)d_in[30];
    const float* bn_g=(const float*)d_in[31],  *bn_b=(const float*)d_in[32];
    const float* pw2_w=(const float*)d_in[33], *pw2_b=(const float*)d_in[34];
    const float* ff2_w1=(const float*)d_in[35], *ff2_b1=(const float*)d_in[36];
    const float* ff2_w2=(const float*)d_in[37], *ff2_b2=(const float*)d_in[38];

    char* W = (char*)d_ws;
    float* h    = (float*)(W);                  // 8 MB f32
    u16*  xn    = (u16*) (W + (size_t) 8*MB);   // 4 MB (ln out / attn out)
    u16*  wall  = (u16*) (W + (size_t)12*MB);   // 16 MB prepped weights
    u16*  qub   = (u16*) (W + (size_t)28*MB);   // qub/qvb/kb/vt contiguous (OMODE5)
    u16*  qvb   = (u16*) (W + (size_t)32*MB);
    u16*  kb    = (u16*) (W + (size_t)36*MB);
    u16*  vt    = (u16*) (W + (size_t)40*MB);   // (B,H,DK,T)
    u16*  pproj = (u16*) (W + (size_t)44*MB);   // 2048x512
    char* big   = W + (size_t)48*MB;            // shared region
    u16*  ffh   = (u16*)big;                    // 16 MB FFN hidden
    unsigned int* t2i = (unsigned int*)big;     // 8 MB conv (a,g) pairs
    u16*  t3u   = (u16*)(big + (size_t)8*MB);   // 4 MB dwconv out (bf16)
    float* stats= (float*)(W + (size_t)112*MB); // 4 KB (atomics, zeroed per call)
    float* wt   = stats + 4096;                 // (31,512) f32
    float* bqkv = wt + 15872;                   // 1536 f32

    u16* ff1w1T = wall;
    u16* ff1w2T = wall + 1048576;
    u16* wqT    = wall + 2097152;   // wq/wk/wv contiguous -> N=1536 merged GEMM
    u16* wkT    = wall + 2359296;
    u16* wvT    = wall + 2621440;
    u16* wpT    = wall + 2883584;
    u16* woT    = wall + 3145728;
    u16* ff2w1T = wall + 3407872;
    u16* ff2w2T = wall + 4456448;
    u16* pw1b   = wall + 5505024;
    u16* pw2b   = wall + 6029312;
    u16* posb   = wall + 6291456;

    dim3 blk(256);

    // ---------------- weight prep (2 launches) ----------------
    Prep9 P;
    P.s[0]=ff1_w1; P.d[0]=ff1w1T; P.R[0]=512;  P.C[0]=2048;
    P.s[1]=ff1_w2; P.d[1]=ff1w2T; P.R[1]=2048; P.C[1]=512;
    P.s[2]=wq;     P.d[2]=wqT;    P.R[2]=512;  P.C[2]=512;
    P.s[3]=wk;     P.d[3]=wkT;    P.R[3]=512;  P.C[3]=512;
    P.s[4]=wv;     P.d[4]=wvT;    P.R[4]=512;  P.C[4]=512;
    P.s[5]=wp;     P.d[5]=wpT;    P.R[5]=512;  P.C[5]=512;
    P.s[6]=wo;     P.d[6]=woT;    P.R[6]=512;  P.C[6]=512;
    P.s[7]=ff2_w1; P.d[7]=ff2w1T; P.R[7]=512;  P.C[7]=2048;
    P.s[8]=ff2_w2; P.d[8]=ff2w2T; P.R[8]=2048; P.C[8]=512;
    int tc[9] = {1024,1024,256,256,256,256,256,1024,1024};
    P.t0[0]=0; for (int e=0;e<9;e++) P.t0[e+1]=P.t0[e]+tc[e];
    prep_transpose<<<dim3(5376), blk, 0, stream>>>(P);
    prep_convert<<<dim3(7236), blk, 0, stream>>>(pw1_w, pw2_w, pos_emb, dw_w,
                                                 bq, bk, bv,
                                                 pw1b, pw2b, posb, wt, bqkv);

    // ---------------- FFN1: h = x + 0.5*ffn(ln1(x)) ----------------
    ln_kernel<1><<<dim3(NTOK/4), blk, 0, stream>>>(x, ln1_g, ln1_b, xn);
    bgemm128<1><<<dim3(16,32), blk, 0, stream>>>(xn,512, ff1w1T,512,
        ffh,2048, 512, ff1_b1,1,1.f, nullptr,nullptr,nullptr);
    bgemm64k<<<dim3(8,64), blk, 0, stream>>>(ffh,2048, ff1w2T,2048,
        h,512, 2048, ff1_b2,0.5f, x);

    // ---------------- Attention: h = h + attn(ln2(h)) ----------------
    ln_kernel<1><<<dim3(NTOK/4), blk, 0, stream>>>(h, ln2_g, ln2_b, xn);
    bgemm128<5><<<dim3(12,32), blk, 0, stream>>>(xn,512, wqT,512,
        qub,512, 512, bqkv,0,1.f, nullptr,pos_u,pos_v);
    bgemm64<1><<<dim3(8,32), blk, 0, stream>>>(posb,512, wpT,512,
        pproj,512, 512, nullptr,1.f, nullptr);

    attn_fused<<<dim3(16,32), blk, 0, stream>>>(qub, qvb, kb, vt, pproj, xn);

    bgemm64<0><<<dim3(8,64), blk, 0, stream>>>(xn,512, woT,512,
        h,512, 512, bo,1.f, h);

    // ---------------- Conv module ----------------
    ln_kernel<1><<<dim3(NTOK/4), blk, 0, stream>>>(h, ln3_g, ln3_b, xn);
    bgemm128<6><<<dim3(8,32), blk, 0, stream>>>(xn,512, pw1b,512,
        t2i,1024, 512, pw1_b,0,1.f, nullptr,nullptr,nullptr);
    dwconv_kernel<<<dim3(2,512), blk, 0, stream>>>(t2i, wt, dw_b, t3u);
    hipMemsetAsync(stats, 0, 4096, stream);
    bn_reduce2<<<dim3(256), blk, 0, stream>>>(t3u, stats);
    bn_apply_kernel<<<dim3(NTOK*DD/256), blk, 0, stream>>>(t3u, stats, bn_g, bn_b, xn);
    bgemm64<0><<<dim3(8,64), blk, 0, stream>>>(xn,512, pw2b,512,
        h,512, 512, pw2_b,1.f, h);

    // ---------------- FFN2 ----------------
    ln_kernel<1><<<dim3(NTOK/4), blk, 0, stream>>>(h, ln4_g, ln4_b, xn);
    bgemm128<1><<<dim3(16,32), blk, 0, stream>>>(xn,512, ff2w1T,512,
        ffh,2048, 512, ff2_b1,1,1.f, nullptr,nullptr,nullptr);
    bgemm64k<<<dim3(8,64), blk, 0, stream>>>(ffh,2048, ff2w2T,2048,
        h,512, 2048, ff2_b2,0.5f, h);

    // ---------------- Final LN ----------------
    ln_kernel<0><<<dim3(NTOK/4), blk, 0, stream>>>(h, ln5_g, ln5_b, (float*)d_out);
}

// Round 11
// 276.659 us; speedup vs baseline: 1.6456x; 1.0089x over previous
//
#include <hip/hip_runtime.h>
#include <math.h>

#define TT   1024
#define BBZ  4
#define DD   512
#define DFF_ 2048
#define HH   8
#define DKK  64
#define NTOK 4096
#define EPSF 1e-5f
#define MB   1048576
// 0.125 * log2(e): scores produced directly in log2 domain
#define QSCALE 0.18033688011112042f
#define M0OFF  24.0f

typedef unsigned short u16;
typedef __attribute__((ext_vector_type(8))) short s8v;    // 8 bf16 (4 VGPRs)
typedef __attribute__((ext_vector_type(4))) float f32x4;
typedef __attribute__((ext_vector_type(4))) unsigned short us4;
typedef __attribute__((ext_vector_type(8))) unsigned short us8;

__device__ __forceinline__ float b2f(u16 v){
    union { unsigned int u; float f; } x; x.u = ((unsigned int)v) << 16; return x.f;
}
__device__ __forceinline__ u16 f2b(float f){
    union { float f; unsigned int u; } x; x.f = f;
    unsigned int r = x.u + 0x7fffu + ((x.u >> 16) & 1u);
    return (u16)(r >> 16);
}
__device__ __forceinline__ float sigmoidf_(float x){ return 1.0f/(1.0f+__expf(-x)); }

__device__ __forceinline__ void gld16(const u16* g, u16* l){
    __builtin_amdgcn_global_load_lds(
        (const __attribute__((address_space(1))) unsigned int*)g,
        (__attribute__((address_space(3))) unsigned int*)l, 16, 0, 0);
}

// ================= 128x128-tile MFMA GEMM (wide N) =================
// C = epilogue(A @ B^T_view), A:(M,K) bf16 row-major, B:(N,K) bf16 row-major.
// OMODE 1: bf16 out (+bias, act)
// OMODE 5: merged QKV epilogue (q scaled by QSCALE, dual +posu/+posv).
// OMODE 6: interleaved GLU-pair bf16 store: (row, d, a/g) for dwconv.
template<int OMODE>
__global__ __launch_bounds__(256) void bgemm128(
    const u16* __restrict__ A, int lda,
    const u16* __restrict__ B, int ldb,
    void* __restrict__ Cv, int ldc, int K,
    const float* __restrict__ bias, int act,
    const float* __restrict__ posu, const float* __restrict__ posv)
{
    int n0 = blockIdx.x * 128;
    int m0 = blockIdx.y * 128;

    __shared__ u16 As[128*64];
    __shared__ u16 Bs[128*64];

    int t = threadIdx.x;
    int w = t >> 6, l = t & 63;
    int lrow = l >> 3, lslot = l & 7;
    int kswz = (lslot ^ lrow) * 8;
    int wm = w >> 1, wn = w & 1;
    int lr = l & 15, lk = l >> 4;

    f32x4 acc[4][4] = {};

    for (int k0 = 0; k0 < K; k0 += 64){
        #pragma unroll
        for (int it = 0; it < 4; ++it){
            int rb = it*32 + w*8;
            gld16(A + (size_t)(m0 + rb + lrow)*lda + k0 + kswz, &As[rb*64]);
            gld16(B + (size_t)(n0 + rb + lrow)*ldb + k0 + kswz, &Bs[rb*64]);
        }
        __syncthreads();

        s8v af[2][4], bf[2][4];
        #pragma unroll
        for (int kh = 0; kh < 2; ++kh){
            int sl = (kh*4 + lk) ^ (lr & 7);
            #pragma unroll
            for (int mi = 0; mi < 4; ++mi)
                af[kh][mi] = *(const s8v*)&As[(wm*64 + mi*16 + lr)*64 + sl*8];
            #pragma unroll
            for (int ni = 0; ni < 4; ++ni)
                bf[kh][ni] = *(const s8v*)&Bs[(wn*64 + ni*16 + lr)*64 + sl*8];
        }
        #pragma unroll
        for (int kh = 0; kh < 2; ++kh)
            #pragma unroll
            for (int mi = 0; mi < 4; ++mi)
                #pragma unroll
                for (int ni = 0; ni < 4; ++ni)
                    acc[mi][ni] = __builtin_amdgcn_mfma_f32_16x16x32_bf16(
                        af[kh][mi], bf[kh][ni], acc[mi][ni], 0, 0, 0);
        __syncthreads();
    }

    #pragma unroll
    for (int mi = 0; mi < 4; ++mi){
        #pragma unroll
        for (int ni = 0; ni < 4; ++ni){
            int gn = n0 + wn*64 + ni*16 + lr;
            float bval = bias ? bias[gn] : 0.0f;
            #pragma unroll
            for (int r = 0; r < 4; ++r){
                int gm = m0 + wm*64 + mi*16 + lk*4 + r;
                float vv = acc[mi][ni][r] + bval;
                if (act) vv = vv * sigmoidf_(vv);
                if (OMODE == 1){
                    ((u16*)Cv)[(size_t)gm*ldc + gn] = f2b(vv);
                } else if (OMODE == 5){ // merged QKV
                    u16* base = (u16*)Cv;
                    if (gn < 512){
                        size_t idx = (size_t)gm*512 + gn;
                        base[idx]              = f2b((vv + posu[gn])*QSCALE);
                        base[idx + (2u<<20)]   = f2b((vv + posv[gn])*QSCALE);
                    } else if (gn < 1024){
                        base[(4u<<20) + (size_t)gm*512 + (gn-512)] = f2b(vv);
                    } else {
                        int gnp = gn - 1024;
                        int bb = gm >> 10, tt2 = gm & 1023;
                        size_t idx = (((size_t)(bb*8 + (gnp>>6)))*64 + (gnp&63))*1024 + tt2;
                        base[(6u<<20) + idx] = f2b(vv);
                    }
                } else { // 6: interleaved (a,g) bf16 pairs for dwconv
                    u16* base = (u16*)Cv;
                    size_t idx = (gn < 512)
                        ? ((size_t)gm*512 + gn)*2
                        : ((size_t)gm*512 + (gn-512))*2 + 1;
                    base[idx] = f2b(vv);
                }
            }
        }
    }
}

// ================= 64x64-tile MFMA GEMM, BK=64 (N=512, K=512 shapes) ========
// OMODE 0: bf16 out (+bias, *alpha, +bf16 resid)   1: bf16 out (+bias)
template<int OMODE>
__global__ __launch_bounds__(256) void bgemm64(
    const u16* __restrict__ A, int lda,
    const u16* __restrict__ B, int ldb,
    u16* __restrict__ C, int ldc, int K,
    const float* __restrict__ bias, float alpha,
    const u16* __restrict__ resid)
{
    int n0 = blockIdx.x * 64;
    int m0 = blockIdx.y * 64;

    __shared__ u16 As[64*64];
    __shared__ u16 Bs[64*64];

    int t = threadIdx.x;
    int w = t >> 6, l = t & 63;
    int lrow = l >> 3, lslot = l & 7;
    int kswz = (lslot ^ lrow) * 8;
    int wm = w >> 1, wn = w & 1;
    int lr = l & 15, lk = l >> 4;

    f32x4 acc[2][2] = {};

    for (int k0 = 0; k0 < K; k0 += 64){
        #pragma unroll
        for (int it = 0; it < 2; ++it){
            int rb = it*32 + w*8;
            gld16(A + (size_t)(m0 + rb + lrow)*lda + k0 + kswz, &As[rb*64]);
            gld16(B + (size_t)(n0 + rb + lrow)*ldb + k0 + kswz, &Bs[rb*64]);
        }
        __syncthreads();

        s8v af[2][2], bf[2][2];
        #pragma unroll
        for (int kh = 0; kh < 2; ++kh){
            int sl = (kh*4 + lk) ^ (lr & 7);
            #pragma unroll
            for (int mi = 0; mi < 2; ++mi)
                af[kh][mi] = *(const s8v*)&As[(wm*32 + mi*16 + lr)*64 + sl*8];
            #pragma unroll
            for (int ni = 0; ni < 2; ++ni)
                bf[kh][ni] = *(const s8v*)&Bs[(wn*32 + ni*16 + lr)*64 + sl*8];
        }
        #pragma unroll
        for (int kh = 0; kh < 2; ++kh)
            #pragma unroll
            for (int mi = 0; mi < 2; ++mi)
                #pragma unroll
                for (int ni = 0; ni < 2; ++ni)
                    acc[mi][ni] = __builtin_amdgcn_mfma_f32_16x16x32_bf16(
                        af[kh][mi], bf[kh][ni], acc[mi][ni], 0, 0, 0);
        __syncthreads();
    }

    #pragma unroll
    for (int mi = 0; mi < 2; ++mi){
        #pragma unroll
        for (int ni = 0; ni < 2; ++ni){
            int gn = n0 + wn*32 + ni*16 + lr;
            float bval = bias ? bias[gn] : 0.0f;
            #pragma unroll
            for (int r = 0; r < 4; ++r){
                int gm = m0 + wm*32 + mi*16 + lk*4 + r;
                float vv = acc[mi][ni][r] + bval;
                if (OMODE == 0){
                    vv *= alpha;
                    if (resid) vv += b2f(resid[(size_t)gm*ldc + gn]);
                }
                C[(size_t)gm*ldc + gn] = f2b(vv);
            }
        }
    }
}

// ================= 64x64-tile MFMA GEMM, BK=128 (K=2048 shapes) ==============
// bf16 out: (acc+bias)*alpha + (f32 residF | bf16 residB).
__global__ __launch_bounds__(256) void bgemm64k(
    const u16* __restrict__ A, int lda,
    const u16* __restrict__ B, int ldb,
    u16* __restrict__ C, int ldc, int K,
    const float* __restrict__ bias, float alpha,
    const float* __restrict__ residF, const u16* __restrict__ residB)
{
    int n0 = blockIdx.x * 64;
    int m0 = blockIdx.y * 64;

    __shared__ u16 As[64*128];    // 16 KB
    __shared__ u16 Bs[64*128];    // 16 KB

    int t = threadIdx.x;
    int w = t >> 6, l = t & 63;
    int r4 = l >> 4;
    int s16 = l & 15;
    int kswz = (s16 ^ (w*4 + r4)) * 8;
    int wm = w >> 1, wn = w & 1;
    int lr = l & 15, lk = l >> 4;

    f32x4 acc[2][2] = {};

    for (int k0 = 0; k0 < K; k0 += 128){
        #pragma unroll
        for (int cb = 0; cb < 4; ++cb){
            int rowu = cb*16 + w*4;
            gld16(A + (size_t)(m0 + rowu + r4)*lda + k0 + kswz, &As[rowu*128]);
            gld16(B + (size_t)(n0 + rowu + r4)*ldb + k0 + kswz, &Bs[rowu*128]);
        }
        __syncthreads();

        #pragma unroll
        for (int kh = 0; kh < 4; ++kh){
            int sl = ((kh*4 + lk) ^ lr) * 8;
            s8v af[2], bf[2];
            #pragma unroll
            for (int mi = 0; mi < 2; ++mi)
                af[mi] = *(const s8v*)&As[(wm*32 + mi*16 + lr)*128 + sl];
            #pragma unroll
            for (int ni = 0; ni < 2; ++ni)
                bf[ni] = *(const s8v*)&Bs[(wn*32 + ni*16 + lr)*128 + sl];
            #pragma unroll
            for (int mi = 0; mi < 2; ++mi)
                #pragma unroll
                for (int ni = 0; ni < 2; ++ni)
                    acc[mi][ni] = __builtin_amdgcn_mfma_f32_16x16x32_bf16(
                        af[mi], bf[ni], acc[mi][ni], 0, 0, 0);
        }
        __syncthreads();
    }

    #pragma unroll
    for (int mi = 0; mi < 2; ++mi){
        #pragma unroll
        for (int ni = 0; ni < 2; ++ni){
            int gn = n0 + wn*32 + ni*16 + lr;
            float bval = bias ? bias[gn] : 0.0f;
            #pragma unroll
            for (int r = 0; r < 4; ++r){
                int gm = m0 + wm*32 + mi*16 + lk*4 + r;
                float vv = (acc[mi][ni][r] + bval) * alpha;
                size_t idx = (size_t)gm*ldc + gn;
                if (residF) vv += residF[idx];
                if (residB) vv += b2f(residB[idx]);
                C[idx] = f2b(vv);
            }
        }
    }
}

// ================= fused rel-pos flash attention =================
// grid (16, 32). Fixed-offset base-2 softmax (p = exp2(s2 - 24)); per-lane L
// partials reduced once after the loop. Band stored DIAGONAL-major: producer
// lane's 4 acc rows share one diagonal -> 4 aligned b128 writes replace 20
// predicated b32 writes. K/V double-buffered, P 3-chunk ring, 1 barrier/iter.
__global__ __launch_bounds__(256) void attn_fused(
    const u16* __restrict__ qub, const u16* __restrict__ qvb,
    const u16* __restrict__ kb,  const u16* __restrict__ vt,
    const u16* __restrict__ pp,  u16* __restrict__ out)
{
    int z = blockIdx.y;
    int b = z >> 3, hh = z & 7;
    int i0 = blockIdx.x * 64;

    __shared__ u16 Kb2[2][64*64];     // 16 KB
    __shared__ u16 Vb2[2][64*64];     // 16 KB
    __shared__ u16 Pring[3][64*64];   // 24 KB
    __shared__ u16 PT[64*64];         //  8 KB (P-tilde; qu staging in prologue)
    __shared__ float Bandd[4][1024];  // 16 KB per-wave [64 diag][16 swz rows]

    int t = threadIdx.x;
    int w = t >> 6, l = t & 63;
    int lrow = l >> 3, lslot = l & 7;
    int kswz = (lslot ^ lrow) * 8;
    int lr = l & 15, lk = l >> 4;

    // ---- prologue: qu -> PT, qv -> Bandd (as u16), frags to regs ----
    #pragma unroll
    for (int it = 0; it < 2; ++it){
        int rb = it*32 + w*8;
        gld16(qub + (size_t)(b*TT + i0 + rb + lrow)*DD + hh*64 + kswz, &PT[rb*64]);
        gld16(qvb + (size_t)(b*TT + i0 + rb + lrow)*DD + hh*64 + kswz,
              (u16*)&Bandd[0][0] + rb*64);
    }
    __syncthreads();
    s8v af_u[2], af_v[2];
    #pragma unroll
    for (int kh = 0; kh < 2; ++kh){
        int sl = (kh*4 + lk) ^ (lr & 7);
        af_u[kh] = *(const s8v*)&PT[(w*16 + lr)*64 + sl*8];
        af_v[kh] = *(const s8v*)((const u16*)&Bandd[0][0] + (w*16 + lr)*64 + sl*8);
    }
    // stage K_0 -> Kb2[0], V_0 -> Vb2[0], P chunks 0,1 -> ring
    #pragma unroll
    for (int it = 0; it < 2; ++it){
        int rb = it*32 + w*8;
        gld16(kb + (size_t)(b*TT +        rb + lrow)*DD + hh*64 + kswz, &Kb2[0][rb*64]);
        gld16(vt + ((size_t)z*64 + rb + lrow)*TT +                kswz, &Vb2[0][rb*64]);
        gld16(pp + (size_t)(960  - i0 +   rb + lrow)*DD + hh*64 + kswz, &Pring[0][rb*64]);
        gld16(pp + (size_t)(1024 - i0 +   rb + lrow)*DD + hh*64 + kswz, &Pring[1][rb*64]);
    }

    f32x4 o_[4] = {};
    float Lp[4] = {0.f, 0.f, 0.f, 0.f};   // per-lane partial denominators

    int s0 = 0, s1 = 1, s2 = 2;

    for (int jt = 0; jt < 16; ++jt){
        int cur = jt & 1;
        __syncthreads();  // all staged loads for THIS iter have landed

        // issue next-iter staging (full-iteration landing window)
        if (jt < 15){
            #pragma unroll
            for (int it = 0; it < 2; ++it){
                int rb = it*32 + w*8;
                gld16(kb + (size_t)(b*TT + (jt+1)*64 + rb + lrow)*DD + hh*64 + kswz,
                      &Kb2[cur^1][rb*64]);
                gld16(vt + ((size_t)z*64 + rb + lrow)*TT + (jt+1)*64 + kswz,
                      &Vb2[cur^1][rb*64]);
                gld16(pp + (size_t)(960 + (jt+2)*64 - i0 + rb + lrow)*DD + hh*64 + kswz,
                      &Pring[s2][rb*64]);
            }
        }

        // ---- S_ac (16x64) and band G (16x80) per wave ----
        f32x4 sac[4] = {};
        f32x4 g[5] = {};
        __builtin_amdgcn_s_setprio(1);
        #pragma unroll
        for (int kh = 0; kh < 2; ++kh){
            int sl = (kh*4 + lk) ^ (lr & 7);
            #pragma unroll
            for (int n = 0; n < 4; ++n){
                s8v bK = *(const s8v*)&Kb2[cur][(n*16 + lr)*64 + sl*8];
                sac[n] = __builtin_amdgcn_mfma_f32_16x16x32_bf16(af_u[kh], bK, sac[n], 0,0,0);
            }
            #pragma unroll
            for (int n = 0; n < 5; ++n){
                int nn = (3 - w) + n;
                const u16* pc = (nn & 4) ? &Pring[s1][0] : &Pring[s0][0];
                s8v bP = *(const s8v*)&pc[(((nn&3)*16) + lr)*64 + sl*8];
                g[n] = __builtin_amdgcn_mfma_f32_16x16x32_bf16(af_v[kh], bP, g[n], 0,0,0);
            }
        }
        __builtin_amdgcn_s_setprio(0);

        // ---- band write: diagonal-major, packed b128 (wave-local) ----
        // pair n=0 (c0) / n=4 (c0+64): same diag slot; exactly one valid per row
        {
            int c0 = (3 - w)*16 + lr;
            int d  = (c0 - 63) & 63;
            int sb = (lk*4 + ((d >> 1) & 3)*4) & 15;
            f32x4 vv;
            #pragma unroll
            for (int r = 0; r < 4; ++r){
                int iia = w*16 + lk*4 + r;
                vv[r] = (iia >= 63 - c0) ? g[0][r] : g[4][r];
            }
            *(f32x4*)&Bandd[w][d*16 + sb] = vv;
        }
        #pragma unroll
        for (int n = 1; n < 4; ++n){   // middle subtiles: always in-band
            int c = (3 - w + n)*16 + lr;
            int d = (c - 63) & 63;
            int sb = (lk*4 + ((d >> 1) & 3)*4) & 15;
            *(f32x4*)&Bandd[w][d*16 + sb] = g[n];
        }

        // ---- combine band + fixed-offset exp2 (wave-local, no shuffles) ----
        float p_[4][4];
        #pragma unroll
        for (int r = 0; r < 4; ++r){
            int ii_l = lk*4 + r;
            float rs = 0.0f;
            #pragma unroll
            for (int n = 0; n < 4; ++n){
                int jj = n*16 + lr;
                int d  = (jj - 16*w - ii_l) & 63;
                float bd = Bandd[w][d*16 + ((ii_l + ((d>>1)&3)*4) & 15)];
                float pv = __builtin_amdgcn_exp2f(sac[n][r] + bd - M0OFF);
                p_[n][r] = pv; rs += pv;
            }
            Lp[r] += rs;
        }

        // write P-tilde (swizzled bf16, wave-local rows; read by same wave only)
        #pragma unroll
        for (int n = 0; n < 4; ++n)
            #pragma unroll
            for (int r = 0; r < 4; ++r){
                int ii  = w*16 + lk*4 + r;
                int col = n*16 + lr;
                int sl  = (col>>3) ^ (ii&7);
                PT[ii*64 + sl*8 + (col&7)] = f2b(p_[n][r]);
            }

        // ---- PV (V_jt landed at this iter's top barrier) ----
        __builtin_amdgcn_s_setprio(1);
        #pragma unroll
        for (int kh = 0; kh < 2; ++kh){
            int sl = (kh*4 + lk) ^ (lr & 7);
            s8v ap = *(const s8v*)&PT[(w*16 + lr)*64 + sl*8];
            #pragma unroll
            for (int n = 0; n < 4; ++n){
                s8v bV = *(const s8v*)&Vb2[cur][(n*16 + lr)*64 + sl*8];
                o_[n] = __builtin_amdgcn_mfma_f32_16x16x32_bf16(ap, bV, o_[n], 0,0,0);
            }
        }
        __builtin_amdgcn_s_setprio(0);
        int tmp = s0; s0 = s1; s1 = s2; s2 = tmp;
    }

    // ---- one-time L reduction across the 16-lane col group ----
    float Lr[4];
    #pragma unroll
    for (int r = 0; r < 4; ++r){
        float Lv = Lp[r];
        #pragma unroll
        for (int msk = 1; msk < 16; msk <<= 1) Lv += __shfl_xor(Lv, msk);
        Lr[r] = 1.0f / Lv;
    }

    #pragma unroll
    for (int n = 0; n < 4; ++n)
        #pragma unroll
        for (int r = 0; r < 4; ++r){
            int i  = i0 + w*16 + lk*4 + r;
            int dk = n*16 + lr;
            out[(size_t)(b*TT + i)*DD + hh*64 + dk] = f2b(o_[n][r] * Lr[r]);
        }
}

// ================= LayerNorm: wave per row, shuffle reduce =====
// IB: 1 = bf16 input, 0 = f32 input.  OB: 1 = bf16 out, 0 = f32 out.
template<int IB, int OB>
__global__ __launch_bounds__(256) void ln_kernel(const void* __restrict__ inp,
    const float* __restrict__ g, const float* __restrict__ b, void* __restrict__ outv)
{
    int w = threadIdx.x >> 6, l = threadIdx.x & 63;
    int row = blockIdx.x*4 + w;
    float v[8];
    if (IB){
        us8 xv = ((const us8*)((const u16*)inp + (size_t)row*DD))[l];
        #pragma unroll
        for (int e=0;e<8;e++) v[e] = b2f(xv[e]);
    } else {
        const float4* xr = (const float4*)((const float*)inp + (size_t)row*DD);
        float4 a = xr[2*l], c = xr[2*l+1];
        v[0]=a.x; v[1]=a.y; v[2]=a.z; v[3]=a.w;
        v[4]=c.x; v[5]=c.y; v[6]=c.z; v[7]=c.w;
    }
    float s = 0.f, q = 0.f;
    #pragma unroll
    for (int e=0;e<8;e++){ s += v[e]; q += v[e]*v[e]; }
    #pragma unroll
    for (int msk = 1; msk < 64; msk <<= 1){
        s += __shfl_xor(s, msk);
        q += __shfl_xor(q, msk);
    }
    float mean = s*(1.0f/DD);
    float var  = q*(1.0f/DD) - mean*mean;
    float rinv = rsqrtf(var+EPSF);
    float4 g0 = ((const float4*)g)[2*l], g1 = ((const float4*)g)[2*l+1];
    float4 b0 = ((const float4*)b)[2*l], b1 = ((const float4*)b)[2*l+1];
    float gv[8] = {g0.x,g0.y,g0.z,g0.w,g1.x,g1.y,g1.z,g1.w};
    float bv[8] = {b0.x,b0.y,b0.z,b0.w,b1.x,b1.y,b1.z,b1.w};
    float y[8];
    #pragma unroll
    for (int e=0;e<8;e++) y[e] = (v[e]-mean)*rinv*gv[e] + bv[e];
    if (OB){
        us8 o;
        #pragma unroll
        for (int e=0;e<8;e++) o[e] = f2b(y[e]);
        ((us8*)((u16*)outv + (size_t)row*DD))[l] = o;
    } else {
        float4 o0 = {y[0],y[1],y[2],y[3]};
        float4 o1 = {y[4],y[5],y[6],y[7]};
        float4* op = (float4*)((float*)outv + (size_t)row*DD);
        op[2*l] = o0; op[2*l+1] = o1;
    }
}

// ================= consolidated weight prep (ONE kernel) =================
struct Prep9 {
    const float* s[9];
    u16* d[9];
    int R[9], C[9];
    int t0[10];
};

__global__ __launch_bounds__(256) void prep_all(Prep9 P,
    const float* __restrict__ pw1_w, const float* __restrict__ pw2_w,
    const float* __restrict__ pos_emb, const float* __restrict__ dw_w,
    const float* __restrict__ bq, const float* __restrict__ bk,
    const float* __restrict__ bv,
    u16* __restrict__ pw1b, u16* __restrict__ pw2b,
    u16* __restrict__ posb, float* __restrict__ wt, float* __restrict__ bqkv)
{
    __shared__ float tile[32][33];
    int bid = blockIdx.x;
    if (bid < 5376){
        int j = 0;
        #pragma unroll
        for (int e=1; e<9; e++) if (bid >= P.t0[e]) j = e;
        int lb = bid - P.t0[j];
        int nx = P.C[j] >> 5;
        int c0 = (lb % nx) << 5;
        int r0 = (lb / nx) << 5;
        const float* in = P.s[j];
        u16* out = P.d[j];
        int R = P.R[j], C = P.C[j];
        int tx = threadIdx.x & 31, ty = threadIdx.x >> 5;
        #pragma unroll
        for (int i=0;i<4;i++){
            int rr = ty + i*8;
            tile[rr][tx] = in[(size_t)(r0+rr)*C + c0+tx];
        }
        __syncthreads();
        #pragma unroll
        for (int i=0;i<4;i++){
            int cc = ty + i*8;
            out[(size_t)(c0+cc)*R + r0+tx] = f2b(tile[tx][cc]);
        }
        return;
    }
    int i = (bid - 5376)*256 + threadIdx.x;
    if (i < 524288) { pw1b[i] = f2b(pw1_w[i]); return; }
    i -= 524288;
    if (i < 262144) { pw2b[i] = f2b(pw2_w[i]); return; }
    i -= 262144;
    if (i < 1048576) { posb[i] = (i < 2047*512) ? f2b(pos_emb[i]) : (u16)0; return; }
    i -= 1048576;
    if (i < 15872) { int kk = i >> 9, d = i & 511; wt[i] = dw_w[d*31+kk]; return; }
    i -= 15872;
    if (i < 1536) bqkv[i] = (i < 512) ? bq[i] : (i < 1024 ? bk[i-512] : bv[i-1024]);
}

// ================= conv-module =================
// depthwise conv K=31, GLU fused: reads interleaved (a,g) bf16 pairs as u32
__global__ __launch_bounds__(256) void dwconv_kernel(const unsigned int* __restrict__ t2i,
    const float* __restrict__ wt, const float* __restrict__ bias, u16* __restrict__ z)
{
    int d  = blockIdx.x*256 + threadIdx.x;   // gridDim.x = 2
    int c  = blockIdx.y;                     // 0..511
    int b  = c >> 7;
    int t0 = (c & 127) << 3;
    const unsigned int* pa = t2i + (size_t)b*TT*512 + d;
    float wv[31];
    #pragma unroll
    for (int kk=0;kk<31;kk++) wv[kk] = wt[kk*512 + d];
    float xv[38];
    #pragma unroll
    for (int e=0;e<38;e++){
        int tp = t0 - 15 + e;
        if (tp >= 0 && tp < TT){
            unsigned int pv = pa[(size_t)tp*512];
            float a  = b2f((u16)(pv & 0xffffu));
            float gg = b2f((u16)(pv >> 16));
            xv[e] = a * sigmoidf_(gg);
        } else xv[e] = 0.0f;
    }
    float bsv = bias[d];
    #pragma unroll
    for (int j=0;j<8;j++){
        float sum = bsv;
        #pragma unroll
        for (int kk=0;kk<31;kk++) sum = fmaf(xv[j+kk], wv[kk], sum);
        z[(size_t)(b*TT+t0+j)*DD + d] = f2b(sum);
    }
}

// BN stats: coalesced row-block reduce + f32 atomics into zeroed stats[1024]
__global__ __launch_bounds__(256) void bn_reduce2(const u16* __restrict__ z,
    float* __restrict__ stats)
{
    int bi = blockIdx.x;          // 256 blocks x 16 rows
    int t  = threadIdx.x;
    float s0=0.f,q0=0.f,s1=0.f,q1=0.f;
    #pragma unroll
    for (int r=0;r<16;r++){
        size_t row = (size_t)(bi*16 + r)*DD;
        float v0 = b2f(z[row + t]);
        float v1 = b2f(z[row + t + 256]);
        s0 += v0; q0 += v0*v0;
        s1 += v1; q1 += v1*v1;
    }
    atomicAdd(&stats[t],        s0);
    atomicAdd(&stats[512 + t],  q0);
    atomicAdd(&stats[t + 256],      s1);
    atomicAdd(&stats[512 + t + 256], q1);
}

__global__ __launch_bounds__(256) void bn_apply_kernel(const u16* __restrict__ z,
    const float* __restrict__ stats, const float* __restrict__ g, const float* __restrict__ b,
    u16* __restrict__ out)
{
    int idx = blockIdx.x*256 + threadIdx.x;
    int c = idx & (DD-1);
    float m   = stats[c]*(1.0f/NTOK);
    float var = stats[DD+c]*(1.0f/NTOK) - m*m;
    float vv  = (b2f(z[idx])-m)*rsqrtf(var+EPSF)*g[c] + b[c];
    out[idx]  = f2b(vv*sigmoidf_(vv));
}

extern "C" void kernel_launch(void* const* d_in, const int* in_sizes, int n_in,
                              void* d_out, int out_size, void* d_ws, size_t ws_size,
                              hipStream_t stream)
{
    const float* x       = (const float*)d_in[0];
    const float* pos_emb = (const float*)d_in[1];
    const float* ln1_g=(const float*)d_in[2],  *ln1_b=(const float*)d_in[3];
    const float* ln2_g=(const float*)d_in[4],  *ln2_b=(const float*)d_in[5];
    const float* ln3_g=(const float*)d_in[6],  *ln3_b=(const float*)d_in[7];
    const float* ln4_g=(const float*)d_in[8],  *ln4_b=(const float*)d_in[9];
    const float* ln5_g=(const float*)d_in[10], *ln5_b=(const float*)d_in[11];
    const float* ff1_w1=(const float*)d_in[12], *ff1_b1=(const float*)d_in[13];
    const float* ff1_w2=(const float*)d_in[14], *ff1_b2=(const float*)d_in[15];
    const float* wq=(const float*)d_in[16], *bq=(const float*)d_in[17];
    const float* wk=(const float*)d_in[18], *bk=(const float*)d_in[19];
    const float* wv=(const float*)d_in[20], *bv=(const float*)d_in[21];
    const float* wp=(const float*)d_in[22];
    const float* wo=(const float*)d_in[23], *bo=(const float*)d_in[24];
    const float* pos_u=(const float*)d_in[25], *pos_v=(const float*)d_in[26];
    const float* pw1_w=(const float*)d_in[27], *pw1_b=(const float*)d_in[28];
    const float* dw_w=(const float*)d_in[29],  *dw_b=(const float*)d_in[30];
    const float* bn_g=(const float*)d_in[31],  *bn_b=(const float*)d_in[32];
    const float* pw2_w=(const float*)d_in[33], *pw2_b=(const float*)d_in[34];
    const float* ff2_w1=(const float*)d_in[35], *ff2_b1=(const float*)d_in[36];
    const float* ff2_w2=(const float*)d_in[37], *ff2_b2=(const float*)d_in[38];

    char* W = (char*)d_ws;
    u16*  h     = (u16*) (W);                   // 4 MB bf16 residual stream
    u16*  xn    = (u16*) (W + (size_t) 8*MB);   // 4 MB (ln out / attn out)
    u16*  wall  = (u16*) (W + (size_t)12*MB);   // 16 MB prepped weights
    u16*  qub   = (u16*) (W + (size_t)28*MB);   // qub/qvb/kb/vt contiguous (OMODE5)
    u16*  qvb   = (u16*) (W + (size_t)32*MB);
    u16*  kb    = (u16*) (W + (size_t)36*MB);
    u16*  vt    = (u16*) (W + (size_t)40*MB);   // (B,H,DK,T)
    u16*  pproj = (u16*) (W + (size_t)44*MB);   // 2048x512
    char* big   = W + (size_t)48*MB;            // shared region
    u16*  ffh   = (u16*)big;                    // 16 MB FFN hidden
    unsigned int* t2i = (unsigned int*)big;     // 8 MB conv (a,g) pairs
    u16*  t3u   = (u16*)(big + (size_t)8*MB);   // 4 MB dwconv out (bf16)
    float* stats= (float*)(W + (size_t)112*MB); // 4 KB (atomics, zeroed per call)
    float* wt   = stats + 4096;                 // (31,512) f32
    float* bqkv = wt + 15872;                   // 1536 f32

    u16* ff1w1T = wall;
    u16* ff1w2T = wall + 1048576;
    u16* wqT    = wall + 2097152;   // wq/wk/wv contiguous -> N=1536 merged GEMM
    u16* wkT    = wall + 2359296;
    u16* wvT    = wall + 2621440;
    u16* wpT    = wall + 2883584;
    u16* woT    = wall + 3145728;
    u16* ff2w1T = wall + 3407872;
    u16* ff2w2T = wall + 4456448;
    u16* pw1b   = wall + 5505024;
    u16* pw2b   = wall + 6029312;
    u16* posb   = wall + 6291456;

    dim3 blk(256);

    // ---------------- weight prep (1 launch) ----------------
    Prep9 P;
    P.s[0]=ff1_w1; P.d[0]=ff1w1T; P.R[0]=512;  P.C[0]=2048;
    P.s[1]=ff1_w2; P.d[1]=ff1w2T; P.R[1]=2048; P.C[1]=512;
    P.s[2]=wq;     P.d[2]=wqT;    P.R[2]=512;  P.C[2]=512;
    P.s[3]=wk;     P.d[3]=wkT;    P.R[3]=512;  P.C[3]=512;
    P.s[4]=wv;     P.d[4]=wvT;    P.R[4]=512;  P.C[4]=512;
    P.s[5]=wp;     P.d[5]=wpT;    P.R[5]=512;  P.C[5]=512;
    P.s[6]=wo;     P.d[6]=woT;    P.R[6]=512;  P.C[6]=512;
    P.s[7]=ff2_w1; P.d[7]=ff2w1T; P.R[7]=512;  P.C[7]=2048;
    P.s[8]=ff2_w2; P.d[8]=ff2w2T; P.R[8]=2048; P.C[8]=512;
    int tc[9] = {1024,1024,256,256,256,256,256,1024,1024};
    P.t0[0]=0; for (int e=0;e<9;e++) P.t0[e+1]=P.t0[e]+tc[e];
    prep_all<<<dim3(5376+7236), blk, 0, stream>>>(P, pw1_w, pw2_w, pos_emb, dw_w,
                                                  bq, bk, bv,
                                                  pw1b, pw2b, posb, wt, bqkv);

    // ---------------- FFN1: h = x + 0.5*ffn(ln1(x)) ----------------
    ln_kernel<0,1><<<dim3(NTOK/4), blk, 0, stream>>>(x, ln1_g, ln1_b, xn);
    bgemm128<1><<<dim3(16,32), blk, 0, stream>>>(xn,512, ff1w1T,512,
        ffh,2048, 512, ff1_b1,1, nullptr,nullptr);
    bgemm64k<<<dim3(8,64), blk, 0, stream>>>(ffh,2048, ff1w2T,2048,
        h,512, 2048, ff1_b2,0.5f, x, nullptr);

    // ---------------- Attention: h = h + attn(ln2(h)) ----------------
    ln_kernel<1,1><<<dim3(NTOK/4), blk, 0, stream>>>(h, ln2_g, ln2_b, xn);
    bgemm128<5><<<dim3(12,32), blk, 0, stream>>>(xn,512, wqT,512,
        qub,512, 512, bqkv,0, pos_u,pos_v);
    bgemm64<1><<<dim3(8,32), blk, 0, stream>>>(posb,512, wpT,512,
        pproj,512, 512, nullptr,1.f, nullptr);

    attn_fused<<<dim3(16,32), blk, 0, stream>>>(qub, qvb, kb, vt, pproj, xn);

    bgemm64<0><<<dim3(8,64), blk, 0, stream>>>(xn,512, woT,512,
        h,512, 512, bo,1.f, h);

    // ---------------- Conv module ----------------
    ln_kernel<1,1><<<dim3(NTOK/4), blk, 0, stream>>>(h, ln3_g, ln3_b, xn);
    bgemm128<6><<<dim3(8,32), blk, 0, stream>>>(xn,512, pw1b,512,
        t2i,1024, 512, pw1_b,0, nullptr,nullptr);
    dwconv_kernel<<<dim3(2,512), blk, 0, stream>>>(t2i, wt, dw_b, t3u);
    (void)hipMemsetAsync(stats, 0, 4096, stream);
    bn_reduce2<<<dim3(256), blk, 0, stream>>>(t3u, stats);
    bn_apply_kernel<<<dim3(NTOK*DD/256), blk, 0, stream>>>(t3u, stats, bn_g, bn_b, xn);
    bgemm64<0><<<dim3(8,64), blk, 0, stream>>>(xn,512, pw2b,512,
        h,512, 512, pw2_b,1.f, h);

    // ---------------- FFN2 ----------------
    ln_kernel<1,1><<<dim3(NTOK/4), blk, 0, stream>>>(h, ln4_g, ln4_b, xn);
    bgemm128<1><<<dim3(16,32), blk, 0, stream>>>(xn,512, ff2w1T,512,
        ffh,2048, 512, ff2_b1,1, nullptr,nullptr);
    bgemm64k<<<dim3(8,64), blk, 0, stream>>>(ffh,2048, ff2w2T,2048,
        h,512, 2048, ff2_b2,0.5f, nullptr, h);

    // ---------------- Final LN ----------------
    ln_kernel<1,0><<<dim3(NTOK/4), blk, 0, stream>>>(h, ln5_g, ln5_b, (float*)d_out);
}

// Round 12
// 265.476 us; speedup vs baseline: 1.7149x; 1.0421x over previous
//
#include <hip/hip_runtime.h>
#include <math.h>

#define TT   1024
#define BBZ  4
#define DD   512
#define DFF_ 2048
#define HH   8
#define DKK  64
#define NTOK 4096
#define EPSF 1e-5f
#define MB   1048576
// 0.125 * log2(e): scores produced directly in log2 domain
#define QSCALE 0.18033688011112042f
#define M0OFF  24.0f

typedef unsigned short u16;
typedef __attribute__((ext_vector_type(8))) short s8v;    // 8 bf16 (4 VGPRs)
typedef __attribute__((ext_vector_type(4))) float f32x4;
typedef __attribute__((ext_vector_type(4))) unsigned short us4;
typedef __attribute__((ext_vector_type(8))) unsigned short us8;

__device__ __forceinline__ float b2f(u16 v){
    union { unsigned int u; float f; } x; x.u = ((unsigned int)v) << 16; return x.f;
}
__device__ __forceinline__ u16 f2b(float f){
    union { float f; unsigned int u; } x; x.f = f;
    unsigned int r = x.u + 0x7fffu + ((x.u >> 16) & 1u);
    return (u16)(r >> 16);
}
__device__ __forceinline__ float sigmoidf_(float x){ return 1.0f/(1.0f+__expf(-x)); }

__device__ __forceinline__ void gld16(const u16* g, u16* l){
    __builtin_amdgcn_global_load_lds(
        (const __attribute__((address_space(1))) unsigned int*)g,
        (__attribute__((address_space(3))) unsigned int*)l, 16, 0, 0);
}

// ================= 128x128-tile MFMA GEMM (wide N) =================
// OMODE 1: bf16 out (+bias, act)
// OMODE 6: interleaved GLU-pair bf16 store: (row, d, a/g) for dwconv.
template<int OMODE>
__global__ __launch_bounds__(256) void bgemm128(
    const u16* __restrict__ A, int lda,
    const u16* __restrict__ B, int ldb,
    void* __restrict__ Cv, int ldc, int K,
    const float* __restrict__ bias, int act)
{
    int n0 = blockIdx.x * 128;
    int m0 = blockIdx.y * 128;

    __shared__ u16 As[128*64];
    __shared__ u16 Bs[128*64];

    int t = threadIdx.x;
    int w = t >> 6, l = t & 63;
    int lrow = l >> 3, lslot = l & 7;
    int kswz = (lslot ^ lrow) * 8;
    int wm = w >> 1, wn = w & 1;
    int lr = l & 15, lk = l >> 4;

    f32x4 acc[4][4] = {};

    for (int k0 = 0; k0 < K; k0 += 64){
        #pragma unroll
        for (int it = 0; it < 4; ++it){
            int rb = it*32 + w*8;
            gld16(A + (size_t)(m0 + rb + lrow)*lda + k0 + kswz, &As[rb*64]);
            gld16(B + (size_t)(n0 + rb + lrow)*ldb + k0 + kswz, &Bs[rb*64]);
        }
        __syncthreads();

        s8v af[2][4], bf[2][4];
        #pragma unroll
        for (int kh = 0; kh < 2; ++kh){
            int sl = (kh*4 + lk) ^ (lr & 7);
            #pragma unroll
            for (int mi = 0; mi < 4; ++mi)
                af[kh][mi] = *(const s8v*)&As[(wm*64 + mi*16 + lr)*64 + sl*8];
            #pragma unroll
            for (int ni = 0; ni < 4; ++ni)
                bf[kh][ni] = *(const s8v*)&Bs[(wn*64 + ni*16 + lr)*64 + sl*8];
        }
        #pragma unroll
        for (int kh = 0; kh < 2; ++kh)
            #pragma unroll
            for (int mi = 0; mi < 4; ++mi)
                #pragma unroll
                for (int ni = 0; ni < 4; ++ni)
                    acc[mi][ni] = __builtin_amdgcn_mfma_f32_16x16x32_bf16(
                        af[kh][mi], bf[kh][ni], acc[mi][ni], 0, 0, 0);
        __syncthreads();
    }

    #pragma unroll
    for (int mi = 0; mi < 4; ++mi){
        #pragma unroll
        for (int ni = 0; ni < 4; ++ni){
            int gn = n0 + wn*64 + ni*16 + lr;
            float bval = bias ? bias[gn] : 0.0f;
            #pragma unroll
            for (int r = 0; r < 4; ++r){
                int gm = m0 + wm*64 + mi*16 + lk*4 + r;
                float vv = acc[mi][ni][r] + bval;
                if (act) vv = vv * sigmoidf_(vv);
                if (OMODE == 1){
                    ((u16*)Cv)[(size_t)gm*ldc + gn] = f2b(vv);
                } else { // 6: interleaved (a,g) bf16 pairs for dwconv
                    u16* base = (u16*)Cv;
                    size_t idx = (gn < 512)
                        ? ((size_t)gm*512 + gn)*2
                        : ((size_t)gm*512 + (gn-512))*2 + 1;
                    base[idx] = f2b(vv);
                }
            }
        }
    }
}

// ================= fused QKV + P-projection GEMM (one dispatch) =============
// grid (16, 32): x<12 -> QKV (OMODE5 epilogue, q scaled, dual +posu/+posv);
// x>=12 -> pproj (posb @ wpT -> pproj), active only for y<16 (M=2048).
__global__ __launch_bounds__(256) void qkvp_gemm(
    const u16* __restrict__ xn, const u16* __restrict__ wqT,
    const u16* __restrict__ posb, const u16* __restrict__ wpT,
    u16* __restrict__ qkvbase, u16* __restrict__ pproj,
    const float* __restrict__ bqkv,
    const float* __restrict__ posu, const float* __restrict__ posv)
{
    bool isP = (blockIdx.x >= 12);
    if (isP && blockIdx.y >= 16) return;
    const u16* A = isP ? posb : xn;
    const u16* B = isP ? wpT : wqT;
    int n0 = isP ? (blockIdx.x - 12)*128 : blockIdx.x*128;
    int m0 = blockIdx.y * 128;

    __shared__ u16 As[128*64];
    __shared__ u16 Bs[128*64];

    int t = threadIdx.x;
    int w = t >> 6, l = t & 63;
    int lrow = l >> 3, lslot = l & 7;
    int kswz = (lslot ^ lrow) * 8;
    int wm = w >> 1, wn = w & 1;
    int lr = l & 15, lk = l >> 4;

    f32x4 acc[4][4] = {};

    for (int k0 = 0; k0 < 512; k0 += 64){
        #pragma unroll
        for (int it = 0; it < 4; ++it){
            int rb = it*32 + w*8;
            gld16(A + (size_t)(m0 + rb + lrow)*512 + k0 + kswz, &As[rb*64]);
            gld16(B + (size_t)(n0 + rb + lrow)*512 + k0 + kswz, &Bs[rb*64]);
        }
        __syncthreads();

        s8v af[2][4], bf[2][4];
        #pragma unroll
        for (int kh = 0; kh < 2; ++kh){
            int sl = (kh*4 + lk) ^ (lr & 7);
            #pragma unroll
            for (int mi = 0; mi < 4; ++mi)
                af[kh][mi] = *(const s8v*)&As[(wm*64 + mi*16 + lr)*64 + sl*8];
            #pragma unroll
            for (int ni = 0; ni < 4; ++ni)
                bf[kh][ni] = *(const s8v*)&Bs[(wn*64 + ni*16 + lr)*64 + sl*8];
        }
        #pragma unroll
        for (int kh = 0; kh < 2; ++kh)
            #pragma unroll
            for (int mi = 0; mi < 4; ++mi)
                #pragma unroll
                for (int ni = 0; ni < 4; ++ni)
                    acc[mi][ni] = __builtin_amdgcn_mfma_f32_16x16x32_bf16(
                        af[kh][mi], bf[kh][ni], acc[mi][ni], 0, 0, 0);
        __syncthreads();
    }

    #pragma unroll
    for (int mi = 0; mi < 4; ++mi){
        #pragma unroll
        for (int ni = 0; ni < 4; ++ni){
            int gn = n0 + wn*64 + ni*16 + lr;
            float bval = isP ? 0.0f : bqkv[gn];
            #pragma unroll
            for (int r = 0; r < 4; ++r){
                int gm = m0 + wm*64 + mi*16 + lk*4 + r;
                float vv = acc[mi][ni][r] + bval;
                if (isP){
                    pproj[(size_t)gm*512 + gn] = f2b(vv);
                } else {
                    u16* base = qkvbase;
                    if (gn < 512){
                        size_t idx = (size_t)gm*512 + gn;
                        base[idx]              = f2b((vv + posu[gn])*QSCALE);
                        base[idx + (2u<<20)]   = f2b((vv + posv[gn])*QSCALE);
                    } else if (gn < 1024){
                        base[(4u<<20) + (size_t)gm*512 + (gn-512)] = f2b(vv);
                    } else {
                        int gnp = gn - 1024;
                        int bb = gm >> 10, tt2 = gm & 1023;
                        size_t idx = (((size_t)(bb*8 + (gnp>>6)))*64 + (gnp&63))*1024 + tt2;
                        base[(6u<<20) + idx] = f2b(vv);
                    }
                }
            }
        }
    }
}

// ================= 64x64-tile MFMA GEMM, BK=64 (N=512, K=512 shapes) ========
// bf16 out (+bias, *alpha, +bf16 resid)
__global__ __launch_bounds__(256) void bgemm64(
    const u16* __restrict__ A, int lda,
    const u16* __restrict__ B, int ldb,
    u16* __restrict__ C, int ldc, int K,
    const float* __restrict__ bias, float alpha,
    const u16* __restrict__ resid)
{
    int n0 = blockIdx.x * 64;
    int m0 = blockIdx.y * 64;

    __shared__ u16 As[64*64];
    __shared__ u16 Bs[64*64];

    int t = threadIdx.x;
    int w = t >> 6, l = t & 63;
    int lrow = l >> 3, lslot = l & 7;
    int kswz = (lslot ^ lrow) * 8;
    int wm = w >> 1, wn = w & 1;
    int lr = l & 15, lk = l >> 4;

    f32x4 acc[2][2] = {};

    for (int k0 = 0; k0 < K; k0 += 64){
        #pragma unroll
        for (int it = 0; it < 2; ++it){
            int rb = it*32 + w*8;
            gld16(A + (size_t)(m0 + rb + lrow)*lda + k0 + kswz, &As[rb*64]);
            gld16(B + (size_t)(n0 + rb + lrow)*ldb + k0 + kswz, &Bs[rb*64]);
        }
        __syncthreads();

        s8v af[2][2], bf[2][2];
        #pragma unroll
        for (int kh = 0; kh < 2; ++kh){
            int sl = (kh*4 + lk) ^ (lr & 7);
            #pragma unroll
            for (int mi = 0; mi < 2; ++mi)
                af[kh][mi] = *(const s8v*)&As[(wm*32 + mi*16 + lr)*64 + sl*8];
            #pragma unroll
            for (int ni = 0; ni < 2; ++ni)
                bf[kh][ni] = *(const s8v*)&Bs[(wn*32 + ni*16 + lr)*64 + sl*8];
        }
        #pragma unroll
        for (int kh = 0; kh < 2; ++kh)
            #pragma unroll
            for (int mi = 0; mi < 2; ++mi)
                #pragma unroll
                for (int ni = 0; ni < 2; ++ni)
                    acc[mi][ni] = __builtin_amdgcn_mfma_f32_16x16x32_bf16(
                        af[kh][mi], bf[kh][ni], acc[mi][ni], 0, 0, 0);
        __syncthreads();
    }

    #pragma unroll
    for (int mi = 0; mi < 2; ++mi){
        #pragma unroll
        for (int ni = 0; ni < 2; ++ni){
            int gn = n0 + wn*32 + ni*16 + lr;
            float bval = bias ? bias[gn] : 0.0f;
            #pragma unroll
            for (int r = 0; r < 4; ++r){
                int gm = m0 + wm*32 + mi*16 + lk*4 + r;
                float vv = (acc[mi][ni][r] + bval) * alpha;
                if (resid) vv += b2f(resid[(size_t)gm*ldc + gn]);
                C[(size_t)gm*ldc + gn] = f2b(vv);
            }
        }
    }
}

// ================= 64x64-tile MFMA GEMM, BK=128 (K=2048 shapes) ==============
// bf16 out: (acc+bias)*alpha + (f32 residF | bf16 residB).
__global__ __launch_bounds__(256) void bgemm64k(
    const u16* __restrict__ A, int lda,
    const u16* __restrict__ B, int ldb,
    u16* __restrict__ C, int ldc, int K,
    const float* __restrict__ bias, float alpha,
    const float* __restrict__ residF, const u16* __restrict__ residB)
{
    int n0 = blockIdx.x * 64;
    int m0 = blockIdx.y * 64;

    __shared__ u16 As[64*128];    // 16 KB
    __shared__ u16 Bs[64*128];    // 16 KB

    int t = threadIdx.x;
    int w = t >> 6, l = t & 63;
    int r4 = l >> 4;
    int s16 = l & 15;
    int kswz = (s16 ^ (w*4 + r4)) * 8;
    int wm = w >> 1, wn = w & 1;
    int lr = l & 15, lk = l >> 4;

    f32x4 acc[2][2] = {};

    for (int k0 = 0; k0 < K; k0 += 128){
        #pragma unroll
        for (int cb = 0; cb < 4; ++cb){
            int rowu = cb*16 + w*4;
            gld16(A + (size_t)(m0 + rowu + r4)*lda + k0 + kswz, &As[rowu*128]);
            gld16(B + (size_t)(n0 + rowu + r4)*ldb + k0 + kswz, &Bs[rowu*128]);
        }
        __syncthreads();

        #pragma unroll
        for (int kh = 0; kh < 4; ++kh){
            int sl = ((kh*4 + lk) ^ lr) * 8;
            s8v af[2], bf[2];
            #pragma unroll
            for (int mi = 0; mi < 2; ++mi)
                af[mi] = *(const s8v*)&As[(wm*32 + mi*16 + lr)*128 + sl];
            #pragma unroll
            for (int ni = 0; ni < 2; ++ni)
                bf[ni] = *(const s8v*)&Bs[(wn*32 + ni*16 + lr)*128 + sl];
            #pragma unroll
            for (int mi = 0; mi < 2; ++mi)
                #pragma unroll
                for (int ni = 0; ni < 2; ++ni)
                    acc[mi][ni] = __builtin_amdgcn_mfma_f32_16x16x32_bf16(
                        af[mi], bf[ni], acc[mi][ni], 0, 0, 0);
        }
        __syncthreads();
    }

    #pragma unroll
    for (int mi = 0; mi < 2; ++mi){
        #pragma unroll
        for (int ni = 0; ni < 2; ++ni){
            int gn = n0 + wn*32 + ni*16 + lr;
            float bval = bias ? bias[gn] : 0.0f;
            #pragma unroll
            for (int r = 0; r < 4; ++r){
                int gm = m0 + wm*32 + mi*16 + lk*4 + r;
                float vv = (acc[mi][ni][r] + bval) * alpha;
                size_t idx = (size_t)gm*ldc + gn;
                if (residF) vv += residF[idx];
                if (residB) vv += b2f(residB[idx]);
                C[idx] = f2b(vv);
            }
        }
    }
}

// ================= fused rel-pos flash attention =================
// grid (16, 32). Fixed-offset base-2 softmax; per-lane L reduced once after
// the loop. Band diagonal-major with bank-hashed intra-row placement:
// slot=(lk+d)&3, elem=r^((d>>2)&3) -> reads spread over all 32 banks (~2-way).
__global__ __launch_bounds__(256) void attn_fused(
    const u16* __restrict__ qub, const u16* __restrict__ qvb,
    const u16* __restrict__ kb,  const u16* __restrict__ vt,
    const u16* __restrict__ pp,  u16* __restrict__ out)
{
    int z = blockIdx.y;
    int b = z >> 3, hh = z & 7;
    int i0 = blockIdx.x * 64;

    __shared__ u16 Kb2[2][64*64];     // 16 KB
    __shared__ u16 Vb2[2][64*64];     // 16 KB
    __shared__ u16 Pring[3][64*64];   // 24 KB
    __shared__ u16 PT[64*64];         //  8 KB (P-tilde; qu staging in prologue)
    __shared__ float Bandd[4][1024];  // 16 KB per-wave [64 diag][16 hashed]

    int t = threadIdx.x;
    int w = t >> 6, l = t & 63;
    int lrow = l >> 3, lslot = l & 7;
    int kswz = (lslot ^ lrow) * 8;
    int lr = l & 15, lk = l >> 4;

    // ---- prologue: qu -> PT, qv -> Bandd (as u16), frags to regs ----
    #pragma unroll
    for (int it = 0; it < 2; ++it){
        int rb = it*32 + w*8;
        gld16(qub + (size_t)(b*TT + i0 + rb + lrow)*DD + hh*64 + kswz, &PT[rb*64]);
        gld16(qvb + (size_t)(b*TT + i0 + rb + lrow)*DD + hh*64 + kswz,
              (u16*)&Bandd[0][0] + rb*64);
    }
    __syncthreads();
    s8v af_u[2], af_v[2];
    #pragma unroll
    for (int kh = 0; kh < 2; ++kh){
        int sl = (kh*4 + lk) ^ (lr & 7);
        af_u[kh] = *(const s8v*)&PT[(w*16 + lr)*64 + sl*8];
        af_v[kh] = *(const s8v*)((const u16*)&Bandd[0][0] + (w*16 + lr)*64 + sl*8);
    }
    // stage K_0 -> Kb2[0], V_0 -> Vb2[0], P chunks 0,1 -> ring
    #pragma unroll
    for (int it = 0; it < 2; ++it){
        int rb = it*32 + w*8;
        gld16(kb + (size_t)(b*TT +        rb + lrow)*DD + hh*64 + kswz, &Kb2[0][rb*64]);
        gld16(vt + ((size_t)z*64 + rb + lrow)*TT +                kswz, &Vb2[0][rb*64]);
        gld16(pp + (size_t)(960  - i0 +   rb + lrow)*DD + hh*64 + kswz, &Pring[0][rb*64]);
        gld16(pp + (size_t)(1024 - i0 +   rb + lrow)*DD + hh*64 + kswz, &Pring[1][rb*64]);
    }

    f32x4 o_[4] = {};
    float Lp[4] = {0.f, 0.f, 0.f, 0.f};   // per-lane partial denominators

    int s0 = 0, s1 = 1, s2 = 2;

    for (int jt = 0; jt < 16; ++jt){
        int cur = jt & 1;
        __syncthreads();  // all staged loads for THIS iter have landed

        // issue next-iter staging (full-iteration landing window)
        if (jt < 15){
            #pragma unroll
            for (int it = 0; it < 2; ++it){
                int rb = it*32 + w*8;
                gld16(kb + (size_t)(b*TT + (jt+1)*64 + rb + lrow)*DD + hh*64 + kswz,
                      &Kb2[cur^1][rb*64]);
                gld16(vt + ((size_t)z*64 + rb + lrow)*TT + (jt+1)*64 + kswz,
                      &Vb2[cur^1][rb*64]);
                gld16(pp + (size_t)(960 + (jt+2)*64 - i0 + rb + lrow)*DD + hh*64 + kswz,
                      &Pring[s2][rb*64]);
            }
        }

        // ---- S_ac (16x64) and band G (16x80) per wave ----
        f32x4 sac[4] = {};
        f32x4 g[5] = {};
        __builtin_amdgcn_s_setprio(1);
        #pragma unroll
        for (int kh = 0; kh < 2; ++kh){
            int sl = (kh*4 + lk) ^ (lr & 7);
            #pragma unroll
            for (int n = 0; n < 4; ++n){
                s8v bK = *(const s8v*)&Kb2[cur][(n*16 + lr)*64 + sl*8];
                sac[n] = __builtin_amdgcn_mfma_f32_16x16x32_bf16(af_u[kh], bK, sac[n], 0,0,0);
            }
            #pragma unroll
            for (int n = 0; n < 5; ++n){
                int nn = (3 - w) + n;
                const u16* pc = (nn & 4) ? &Pring[s1][0] : &Pring[s0][0];
                s8v bP = *(const s8v*)&pc[(((nn&3)*16) + lr)*64 + sl*8];
                g[n] = __builtin_amdgcn_mfma_f32_16x16x32_bf16(af_v[kh], bP, g[n], 0,0,0);
            }
        }
        __builtin_amdgcn_s_setprio(0);

        // ---- band write: diagonal-major, bank-hashed, packed b128 ----
        #pragma unroll
        for (int n = 0; n < 4; ++n){
            int c = (3 - w + n)*16 + lr;
            int d = (c - 63) & 63;
            int rho = (d >> 2) & 3;
            f32x4 vv;
            if (n == 0){
                #pragma unroll
                for (int r = 0; r < 4; ++r){
                    int iia = w*16 + lk*4 + r;
                    vv[r] = (iia >= 63 - c) ? g[0][r] : g[4][r];
                }
            } else {
                vv = g[n];
            }
            // vvp[k] = vv[k ^ rho] via two conditional swap stages
            bool sw1 = rho & 1, sw2 = rho & 2;
            float b0 = sw1 ? vv[1] : vv[0];
            float b1 = sw1 ? vv[0] : vv[1];
            float b2 = sw1 ? vv[3] : vv[2];
            float b3 = sw1 ? vv[2] : vv[3];
            f32x4 vvp;
            vvp[0] = sw2 ? b2 : b0;
            vvp[1] = sw2 ? b3 : b1;
            vvp[2] = sw2 ? b0 : b2;
            vvp[3] = sw2 ? b1 : b3;
            *(f32x4*)&Bandd[w][d*16 + ((lk + d) & 3)*4] = vvp;
        }

        // ---- combine band + fixed-offset exp2 (wave-local, no shuffles) ----
        float p_[4][4];
        #pragma unroll
        for (int r = 0; r < 4; ++r){
            int ii_l = lk*4 + r;
            float rs = 0.0f;
            #pragma unroll
            for (int n = 0; n < 4; ++n){
                int jj = n*16 + lr;
                int d  = (jj - 16*w - ii_l) & 63;
                float bd = Bandd[w][d*16 + (((ii_l>>2) + d) & 3)*4
                                         + ((ii_l ^ (d>>2)) & 3)];
                float pv = __builtin_amdgcn_exp2f(sac[n][r] + bd - M0OFF);
                p_[n][r] = pv; rs += pv;
            }
            Lp[r] += rs;
        }

        // write P-tilde (swizzled bf16, wave-local rows; read by same wave only)
        #pragma unroll
        for (int n = 0; n < 4; ++n)
            #pragma unroll
            for (int r = 0; r < 4; ++r){
                int ii  = w*16 + lk*4 + r;
                int col = n*16 + lr;
                int sl  = (col>>3) ^ (ii&7);
                PT[ii*64 + sl*8 + (col&7)] = f2b(p_[n][r]);
            }

        // ---- PV (V_jt landed at this iter's top barrier) ----
        __builtin_amdgcn_s_setprio(1);
        #pragma unroll
        for (int kh = 0; kh < 2; ++kh){
            int sl = (kh*4 + lk) ^ (lr & 7);
            s8v ap = *(const s8v*)&PT[(w*16 + lr)*64 + sl*8];
            #pragma unroll
            for (int n = 0; n < 4; ++n){
                s8v bV = *(const s8v*)&Vb2[cur][(n*16 + lr)*64 + sl*8];
                o_[n] = __builtin_amdgcn_mfma_f32_16x16x32_bf16(ap, bV, o_[n], 0,0,0);
            }
        }
        __builtin_amdgcn_s_setprio(0);
        int tmp = s0; s0 = s1; s1 = s2; s2 = tmp;
    }

    // ---- one-time L reduction across the 16-lane col group ----
    float Lr[4];
    #pragma unroll
    for (int r = 0; r < 4; ++r){
        float Lv = Lp[r];
        #pragma unroll
        for (int msk = 1; msk < 16; msk <<= 1) Lv += __shfl_xor(Lv, msk);
        Lr[r] = 1.0f / Lv;
    }

    #pragma unroll
    for (int n = 0; n < 4; ++n)
        #pragma unroll
        for (int r = 0; r < 4; ++r){
            int i  = i0 + w*16 + lk*4 + r;
            int dk = n*16 + lr;
            out[(size_t)(b*TT + i)*DD + hh*64 + dk] = f2b(o_[n][r] * Lr[r]);
        }
}

// ================= LayerNorm: wave per row, shuffle reduce =====
// IB: 1 = bf16 input, 0 = f32 input.  OB: 1 = bf16 out, 0 = f32 out.
template<int IB, int OB>
__global__ __launch_bounds__(256) void ln_kernel(const void* __restrict__ inp,
    const float* __restrict__ g, const float* __restrict__ b, void* __restrict__ outv)
{
    int w = threadIdx.x >> 6, l = threadIdx.x & 63;
    int row = blockIdx.x*4 + w;
    float v[8];
    if (IB){
        us8 xv = ((const us8*)((const u16*)inp + (size_t)row*DD))[l];
        #pragma unroll
        for (int e=0;e<8;e++) v[e] = b2f(xv[e]);
    } else {
        const float4* xr = (const float4*)((const float*)inp + (size_t)row*DD);
        float4 a = xr[2*l], c = xr[2*l+1];
        v[0]=a.x; v[1]=a.y; v[2]=a.z; v[3]=a.w;
        v[4]=c.x; v[5]=c.y; v[6]=c.z; v[7]=c.w;
    }
    float s = 0.f, q = 0.f;
    #pragma unroll
    for (int e=0;e<8;e++){ s += v[e]; q += v[e]*v[e]; }
    #pragma unroll
    for (int msk = 1; msk < 64; msk <<= 1){
        s += __shfl_xor(s, msk);
        q += __shfl_xor(q, msk);
    }
    float mean = s*(1.0f/DD);
    float var  = q*(1.0f/DD) - mean*mean;
    float rinv = rsqrtf(var+EPSF);
    float4 g0 = ((const float4*)g)[2*l], g1 = ((const float4*)g)[2*l+1];
    float4 b0 = ((const float4*)b)[2*l], b1 = ((const float4*)b)[2*l+1];
    float gv[8] = {g0.x,g0.y,g0.z,g0.w,g1.x,g1.y,g1.z,g1.w};
    float bv[8] = {b0.x,b0.y,b0.z,b0.w,b1.x,b1.y,b1.z,b1.w};
    float y[8];
    #pragma unroll
    for (int e=0;e<8;e++) y[e] = (v[e]-mean)*rinv*gv[e] + bv[e];
    if (OB){
        us8 o;
        #pragma unroll
        for (int e=0;e<8;e++) o[e] = f2b(y[e]);
        ((us8*)((u16*)outv + (size_t)row*DD))[l] = o;
    } else {
        float4 o0 = {y[0],y[1],y[2],y[3]};
        float4 o1 = {y[4],y[5],y[6],y[7]};
        float4* op = (float4*)((float*)outv + (size_t)row*DD);
        op[2*l] = o0; op[2*l+1] = o1;
    }
}

// ================= consolidated weight prep (ONE kernel) =================
struct Prep9 {
    const float* s[9];
    u16* d[9];
    int R[9], C[9];
    int t0[10];
};

__global__ __launch_bounds__(256) void prep_all(Prep9 P,
    const float* __restrict__ pw1_w, const float* __restrict__ pw2_w,
    const float* __restrict__ pos_emb, const float* __restrict__ dw_w,
    const float* __restrict__ bq, const float* __restrict__ bk,
    const float* __restrict__ bv,
    u16* __restrict__ pw1b, u16* __restrict__ pw2b,
    u16* __restrict__ posb, float* __restrict__ wt, float* __restrict__ bqkv)
{
    __shared__ float tile[32][33];
    int bid = blockIdx.x;
    if (bid < 5376){
        int j = 0;
        #pragma unroll
        for (int e=1; e<9; e++) if (bid >= P.t0[e]) j = e;
        int lb = bid - P.t0[j];
        int nx = P.C[j] >> 5;
        int c0 = (lb % nx) << 5;
        int r0 = (lb / nx) << 5;
        const float* in = P.s[j];
        u16* out = P.d[j];
        int R = P.R[j], C = P.C[j];
        int tx = threadIdx.x & 31, ty = threadIdx.x >> 5;
        #pragma unroll
        for (int i=0;i<4;i++){
            int rr = ty + i*8;
            tile[rr][tx] = in[(size_t)(r0+rr)*C + c0+tx];
        }
        __syncthreads();
        #pragma unroll
        for (int i=0;i<4;i++){
            int cc = ty + i*8;
            out[(size_t)(c0+cc)*R + r0+tx] = f2b(tile[tx][cc]);
        }
        return;
    }
    int i = (bid - 5376)*256 + threadIdx.x;
    if (i < 524288) { pw1b[i] = f2b(pw1_w[i]); return; }
    i -= 524288;
    if (i < 262144) { pw2b[i] = f2b(pw2_w[i]); return; }
    i -= 262144;
    if (i < 1048576) { posb[i] = (i < 2047*512) ? f2b(pos_emb[i]) : (u16)0; return; }
    i -= 1048576;
    if (i < 15872) { int kk = i >> 9, d = i & 511; wt[i] = dw_w[d*31+kk]; return; }
    i -= 15872;
    if (i < 1536) bqkv[i] = (i < 512) ? bq[i] : (i < 1024 ? bk[i-512] : bv[i-1024]);
}

// ================= conv-module =================
// depthwise conv K=31, GLU fused, BN-stats fused (f32 atomics into zeroed stats)
__global__ __launch_bounds__(256) void dwconv_kernel(const unsigned int* __restrict__ t2i,
    const float* __restrict__ wt, const float* __restrict__ bias, u16* __restrict__ z,
    float* __restrict__ stats)
{
    int d  = blockIdx.x*256 + threadIdx.x;   // gridDim.x = 2
    int c  = blockIdx.y;                     // 0..511
    int b  = c >> 7;
    int t0 = (c & 127) << 3;
    const unsigned int* pa = t2i + (size_t)b*TT*512 + d;
    float wv[31];
    #pragma unroll
    for (int kk=0;kk<31;kk++) wv[kk] = wt[kk*512 + d];
    float xv[38];
    #pragma unroll
    for (int e=0;e<38;e++){
        int tp = t0 - 15 + e;
        if (tp >= 0 && tp < TT){
            unsigned int pv = pa[(size_t)tp*512];
            float a  = b2f((u16)(pv & 0xffffu));
            float gg = b2f((u16)(pv >> 16));
            xv[e] = a * sigmoidf_(gg);
        } else xv[e] = 0.0f;
    }
    float bsv = bias[d];
    float s = 0.f, q = 0.f;
    #pragma unroll
    for (int j=0;j<8;j++){
        float sum = bsv;
        #pragma unroll
        for (int kk=0;kk<31;kk++) sum = fmaf(xv[j+kk], wv[kk], sum);
        z[(size_t)(b*TT+t0+j)*DD + d] = f2b(sum);
        s += sum; q += sum*sum;
    }
    atomicAdd(&stats[d],       s);
    atomicAdd(&stats[512 + d], q);
}

__global__ __launch_bounds__(256) void bn_apply_kernel(const u16* __restrict__ z,
    const float* __restrict__ stats, const float* __restrict__ g, const float* __restrict__ b,
    u16* __restrict__ out)
{
    int idx = blockIdx.x*256 + threadIdx.x;
    int c = idx & (DD-1);
    float m   = stats[c]*(1.0f/NTOK);
    float var = stats[DD+c]*(1.0f/NTOK) - m*m;
    float vv  = (b2f(z[idx])-m)*rsqrtf(var+EPSF)*g[c] + b[c];
    out[idx]  = f2b(vv*sigmoidf_(vv));
}

extern "C" void kernel_launch(void* const* d_in, const int* in_sizes, int n_in,
                              void* d_out, int out_size, void* d_ws, size_t ws_size,
                              hipStream_t stream)
{
    const float* x       = (const float*)d_in[0];
    const float* pos_emb = (const float*)d_in[1];
    const float* ln1_g=(const float*)d_in[2],  *ln1_b=(const float*)d_in[3];
    const float* ln2_g=(const float*)d_in[4],  *ln2_b=(const float*)d_in[5];
    const float* ln3_g=(const float*)d_in[6],  *ln3_b=(const float*)d_in[7];
    const float* ln4_g=(const float*)d_in[8],  *ln4_b=(const float*)d_in[9];
    const float* ln5_g=(const float*)d_in[10], *ln5_b=(const float*)d_in[11];
    const float* ff1_w1=(const float*)d_in[12], *ff1_b1=(const float*)d_in[13];
    const float* ff1_w2=(const float*)d_in[14], *ff1_b2=(const float*)d_in[15];
    const float* wq=(const float*)d_in[16], *bq=(const float*)d_in[17];
    const float* wk=(const float*)d_in[18], *bk=(const float*)d_in[19];
    const float* wv=(const float*)d_in[20], *bv=(const float*)d_in[21];
    const float* wp=(const float*)d_in[22];
    const float* wo=(const float*)d_in[23], *bo=(const float*)d_in[24];
    const float* pos_u=(const float*)d_in[25], *pos_v=(const float*)d_in[26];
    const float* pw1_w=(const float*)d_in[27], *pw1_b=(const float*)d_in[28];
    const float* dw_w=(const float*)d_in[29],  *dw_b=(const float*)d_in[30];
    const float* bn_g=(const float*)d_in[31],  *bn_b=(const float*)d_in[32];
    const float* pw2_w=(const float*)d_in[33], *pw2_b=(const float*)d_in[34];
    const float* ff2_w1=(const float*)d_in[35], *ff2_b1=(const float*)d_in[36];
    const float* ff2_w2=(const float*)d_in[37], *ff2_b2=(const float*)d_in[38];

    char* W = (char*)d_ws;
    u16*  h     = (u16*) (W);                   // 4 MB bf16 residual stream
    u16*  xn    = (u16*) (W + (size_t) 8*MB);   // 4 MB (ln out / attn out)
    u16*  wall  = (u16*) (W + (size_t)12*MB);   // 16 MB prepped weights
    u16*  qub   = (u16*) (W + (size_t)28*MB);   // qub/qvb/kb/vt contiguous
    u16*  qvb   = (u16*) (W + (size_t)32*MB);
    u16*  kb    = (u16*) (W + (size_t)36*MB);
    u16*  vt    = (u16*) (W + (size_t)40*MB);   // (B,H,DK,T)
    u16*  pproj = (u16*) (W + (size_t)44*MB);   // 2048x512
    char* big   = W + (size_t)48*MB;            // shared region
    u16*  ffh   = (u16*)big;                    // 16 MB FFN hidden
    unsigned int* t2i = (unsigned int*)big;     // 8 MB conv (a,g) pairs
    u16*  t3u   = (u16*)(big + (size_t)8*MB);   // 4 MB dwconv out (bf16)
    float* stats= (float*)(W + (size_t)112*MB); // 4 KB (atomics, zeroed per call)
    float* wt   = stats + 4096;                 // (31,512) f32
    float* bqkv = wt + 15872;                   // 1536 f32

    u16* ff1w1T = wall;
    u16* ff1w2T = wall + 1048576;
    u16* wqT    = wall + 2097152;   // wq/wk/wv contiguous -> N=1536 merged GEMM
    u16* wkT    = wall + 2359296;
    u16* wvT    = wall + 2621440;
    u16* wpT    = wall + 2883584;
    u16* woT    = wall + 3145728;
    u16* ff2w1T = wall + 3407872;
    u16* ff2w2T = wall + 4456448;
    u16* pw1b   = wall + 5505024;
    u16* pw2b   = wall + 6029312;
    u16* posb   = wall + 6291456;

    dim3 blk(256);

    // ---------------- weight prep (1 launch) ----------------
    Prep9 P;
    P.s[0]=ff1_w1; P.d[0]=ff1w1T; P.R[0]=512;  P.C[0]=2048;
    P.s[1]=ff1_w2; P.d[1]=ff1w2T; P.R[1]=2048; P.C[1]=512;
    P.s[2]=wq;     P.d[2]=wqT;    P.R[2]=512;  P.C[2]=512;
    P.s[3]=wk;     P.d[3]=wkT;    P.R[3]=512;  P.C[3]=512;
    P.s[4]=wv;     P.d[4]=wvT;    P.R[4]=512;  P.C[4]=512;
    P.s[5]=wp;     P.d[5]=wpT;    P.R[5]=512;  P.C[5]=512;
    P.s[6]=wo;     P.d[6]=woT;    P.R[6]=512;  P.C[6]=512;
    P.s[7]=ff2_w1; P.d[7]=ff2w1T; P.R[7]=512;  P.C[7]=2048;
    P.s[8]=ff2_w2; P.d[8]=ff2w2T; P.R[8]=2048; P.C[8]=512;
    int tc[9] = {1024,1024,256,256,256,256,256,1024,1024};
    P.t0[0]=0; for (int e=0;e<9;e++) P.t0[e+1]=P.t0[e]+tc[e];
    prep_all<<<dim3(5376+7236), blk, 0, stream>>>(P, pw1_w, pw2_w, pos_emb, dw_w,
                                                  bq, bk, bv,
                                                  pw1b, pw2b, posb, wt, bqkv);

    // ---------------- FFN1: h = x + 0.5*ffn(ln1(x)) ----------------
    ln_kernel<0,1><<<dim3(NTOK/4), blk, 0, stream>>>(x, ln1_g, ln1_b, xn);
    bgemm128<1><<<dim3(16,32), blk, 0, stream>>>(xn,512, ff1w1T,512,
        ffh,2048, 512, ff1_b1,1);
    bgemm64k<<<dim3(8,64), blk, 0, stream>>>(ffh,2048, ff1w2T,2048,
        h,512, 2048, ff1_b2,0.5f, x, nullptr);

    // ---------------- Attention: h = h + attn(ln2(h)) ----------------
    ln_kernel<1,1><<<dim3(NTOK/4), blk, 0, stream>>>(h, ln2_g, ln2_b, xn);
    qkvp_gemm<<<dim3(16,32), blk, 0, stream>>>(xn, wqT, posb, wpT,
        qub, pproj, bqkv, pos_u, pos_v);

    attn_fused<<<dim3(16,32), blk, 0, stream>>>(qub, qvb, kb, vt, pproj, xn);

    bgemm64<<<dim3(8,64), blk, 0, stream>>>(xn,512, woT,512,
        h,512, 512, bo,1.f, h);

    // ---------------- Conv module ----------------
    ln_kernel<1,1><<<dim3(NTOK/4), blk, 0, stream>>>(h, ln3_g, ln3_b, xn);
    bgemm128<6><<<dim3(8,32), blk, 0, stream>>>(xn,512, pw1b,512,
        t2i,1024, 512, pw1_b,0);
    (void)hipMemsetAsync(stats, 0, 4096, stream);
    dwconv_kernel<<<dim3(2,512), blk, 0, stream>>>(t2i, wt, dw_b, t3u, stats);
    bn_apply_kernel<<<dim3(NTOK*DD/256), blk, 0, stream>>>(t3u, stats, bn_g, bn_b, xn);
    bgemm64<<<dim3(8,64), blk, 0, stream>>>(xn,512, pw2b,512,
        h,512, 512, pw2_b,1.f, h);

    // ---------------- FFN2 ----------------
    ln_kernel<1,1><<<dim3(NTOK/4), blk, 0, stream>>>(h, ln4_g, ln4_b, xn);
    bgemm128<1><<<dim3(16,32), blk, 0, stream>>>(xn,512, ff2w1T,512,
        ffh,2048, 512, ff2_b1,1);
    bgemm64k<<<dim3(8,64), blk, 0, stream>>>(ffh,2048, ff2w2T,2048,
        h,512, 2048, ff2_b2,0.5f, nullptr, h);

    // ---------------- Final LN ----------------
    ln_kernel<1,0><<<dim3(NTOK/4), blk, 0, stream>>>(h, ln5_g, ln5_b, (float*)d_out);
}

// Round 13
// 261.390 us; speedup vs baseline: 1.7417x; 1.0156x over previous
//
#include <hip/hip_runtime.h>
#include <math.h>

#define TT   1024
#define BBZ  4
#define DD   512
#define DFF_ 2048
#define HH   8
#define DKK  64
#define NTOK 4096
#define EPSF 1e-5f
#define MB   1048576
// 0.125 * log2(e): scores produced directly in log2 domain
#define QSCALE 0.18033688011112042f
#define M0OFF  24.0f

typedef unsigned short u16;
typedef __attribute__((ext_vector_type(8))) short s8v;    // 8 bf16 (4 VGPRs)
typedef __attribute__((ext_vector_type(4))) float f32x4;
typedef __attribute__((ext_vector_type(4))) unsigned short us4;
typedef __attribute__((ext_vector_type(8))) unsigned short us8;

__device__ __forceinline__ float b2f(u16 v){
    union { unsigned int u; float f; } x; x.u = ((unsigned int)v) << 16; return x.f;
}
__device__ __forceinline__ u16 f2b(float f){
    union { float f; unsigned int u; } x; x.f = f;
    unsigned int r = x.u + 0x7fffu + ((x.u >> 16) & 1u);
    return (u16)(r >> 16);
}
__device__ __forceinline__ float sigmoidf_(float x){ return 1.0f/(1.0f+__expf(-x)); }

__device__ __forceinline__ void gld16(const u16* g, u16* l){
    __builtin_amdgcn_global_load_lds(
        (const __attribute__((address_space(1))) unsigned int*)g,
        (__attribute__((address_space(3))) unsigned int*)l, 16, 0, 0);
}

// ================= 128x128-tile MFMA GEMM (wide N) =================
// OMODE 1: bf16 out (+bias, act)
// OMODE 6: interleaved GLU-pair bf16 store: (row, d, a/g) for dwconv.
template<int OMODE>
__global__ __launch_bounds__(256) void bgemm128(
    const u16* __restrict__ A, int lda,
    const u16* __restrict__ B, int ldb,
    void* __restrict__ Cv, int ldc, int K,
    const float* __restrict__ bias, int act)
{
    int n0 = blockIdx.x * 128;
    int m0 = blockIdx.y * 128;

    __shared__ u16 As[128*64];
    __shared__ u16 Bs[128*64];

    int t = threadIdx.x;
    int w = t >> 6, l = t & 63;
    int lrow = l >> 3, lslot = l & 7;
    int kswz = (lslot ^ lrow) * 8;
    int wm = w >> 1, wn = w & 1;
    int lr = l & 15, lk = l >> 4;

    f32x4 acc[4][4] = {};

    for (int k0 = 0; k0 < K; k0 += 64){
        #pragma unroll
        for (int it = 0; it < 4; ++it){
            int rb = it*32 + w*8;
            gld16(A + (size_t)(m0 + rb + lrow)*lda + k0 + kswz, &As[rb*64]);
            gld16(B + (size_t)(n0 + rb + lrow)*ldb + k0 + kswz, &Bs[rb*64]);
        }
        __syncthreads();

        s8v af[2][4], bf[2][4];
        #pragma unroll
        for (int kh = 0; kh < 2; ++kh){
            int sl = (kh*4 + lk) ^ (lr & 7);
            #pragma unroll
            for (int mi = 0; mi < 4; ++mi)
                af[kh][mi] = *(const s8v*)&As[(wm*64 + mi*16 + lr)*64 + sl*8];
            #pragma unroll
            for (int ni = 0; ni < 4; ++ni)
                bf[kh][ni] = *(const s8v*)&Bs[(wn*64 + ni*16 + lr)*64 + sl*8];
        }
        #pragma unroll
        for (int kh = 0; kh < 2; ++kh)
            #pragma unroll
            for (int mi = 0; mi < 4; ++mi)
                #pragma unroll
                for (int ni = 0; ni < 4; ++ni)
                    acc[mi][ni] = __builtin_amdgcn_mfma_f32_16x16x32_bf16(
                        af[kh][mi], bf[kh][ni], acc[mi][ni], 0, 0, 0);
        __syncthreads();
    }

    #pragma unroll
    for (int mi = 0; mi < 4; ++mi){
        #pragma unroll
        for (int ni = 0; ni < 4; ++ni){
            int gn = n0 + wn*64 + ni*16 + lr;
            float bval = bias ? bias[gn] : 0.0f;
            #pragma unroll
            for (int r = 0; r < 4; ++r){
                int gm = m0 + wm*64 + mi*16 + lk*4 + r;
                float vv = acc[mi][ni][r] + bval;
                if (act) vv = vv * sigmoidf_(vv);
                if (OMODE == 1){
                    ((u16*)Cv)[(size_t)gm*ldc + gn] = f2b(vv);
                } else { // 6: interleaved (a,g) bf16 pairs for dwconv
                    u16* base = (u16*)Cv;
                    size_t idx = (gn < 512)
                        ? ((size_t)gm*512 + gn)*2
                        : ((size_t)gm*512 + (gn-512))*2 + 1;
                    base[idx] = f2b(vv);
                }
            }
        }
    }
}

// ================= fused QKV + P-projection GEMM (one dispatch) =============
__global__ __launch_bounds__(256) void qkvp_gemm(
    const u16* __restrict__ xn, const u16* __restrict__ wqT,
    const u16* __restrict__ posb, const u16* __restrict__ wpT,
    u16* __restrict__ qkvbase, u16* __restrict__ pproj,
    const float* __restrict__ bqkv,
    const float* __restrict__ posu, const float* __restrict__ posv)
{
    bool isP = (blockIdx.x >= 12);
    if (isP && blockIdx.y >= 16) return;
    const u16* A = isP ? posb : xn;
    const u16* B = isP ? wpT : wqT;
    int n0 = isP ? (blockIdx.x - 12)*128 : blockIdx.x*128;
    int m0 = blockIdx.y * 128;

    __shared__ u16 As[128*64];
    __shared__ u16 Bs[128*64];

    int t = threadIdx.x;
    int w = t >> 6, l = t & 63;
    int lrow = l >> 3, lslot = l & 7;
    int kswz = (lslot ^ lrow) * 8;
    int wm = w >> 1, wn = w & 1;
    int lr = l & 15, lk = l >> 4;

    f32x4 acc[4][4] = {};

    for (int k0 = 0; k0 < 512; k0 += 64){
        #pragma unroll
        for (int it = 0; it < 4; ++it){
            int rb = it*32 + w*8;
            gld16(A + (size_t)(m0 + rb + lrow)*512 + k0 + kswz, &As[rb*64]);
            gld16(B + (size_t)(n0 + rb + lrow)*512 + k0 + kswz, &Bs[rb*64]);
        }
        __syncthreads();

        s8v af[2][4], bf[2][4];
        #pragma unroll
        for (int kh = 0; kh < 2; ++kh){
            int sl = (kh*4 + lk) ^ (lr & 7);
            #pragma unroll
            for (int mi = 0; mi < 4; ++mi)
                af[kh][mi] = *(const s8v*)&As[(wm*64 + mi*16 + lr)*64 + sl*8];
            #pragma unroll
            for (int ni = 0; ni < 4; ++ni)
                bf[kh][ni] = *(const s8v*)&Bs[(wn*64 + ni*16 + lr)*64 + sl*8];
        }
        #pragma unroll
        for (int kh = 0; kh < 2; ++kh)
            #pragma unroll
            for (int mi = 0; mi < 4; ++mi)
                #pragma unroll
                for (int ni = 0; ni < 4; ++ni)
                    acc[mi][ni] = __builtin_amdgcn_mfma_f32_16x16x32_bf16(
                        af[kh][mi], bf[kh][ni], acc[mi][ni], 0, 0, 0);
        __syncthreads();
    }

    #pragma unroll
    for (int mi = 0; mi < 4; ++mi){
        #pragma unroll
        for (int ni = 0; ni < 4; ++ni){
            int gn = n0 + wn*64 + ni*16 + lr;
            float bval = isP ? 0.0f : bqkv[gn];
            #pragma unroll
            for (int r = 0; r < 4; ++r){
                int gm = m0 + wm*64 + mi*16 + lk*4 + r;
                float vv = acc[mi][ni][r] + bval;
                if (isP){
                    pproj[(size_t)gm*512 + gn] = f2b(vv);
                } else {
                    u16* base = qkvbase;
                    if (gn < 512){
                        size_t idx = (size_t)gm*512 + gn;
                        base[idx]              = f2b((vv + posu[gn])*QSCALE);
                        base[idx + (2u<<20)]   = f2b((vv + posv[gn])*QSCALE);
                    } else if (gn < 1024){
                        base[(4u<<20) + (size_t)gm*512 + (gn-512)] = f2b(vv);
                    } else {
                        int gnp = gn - 1024;
                        int bb = gm >> 10, tt2 = gm & 1023;
                        size_t idx = (((size_t)(bb*8 + (gnp>>6)))*64 + (gnp&63))*1024 + tt2;
                        base[(6u<<20) + idx] = f2b(vv);
                    }
                }
            }
        }
    }
}

// ================= 64x64-tile MFMA GEMM, BK=64 (N=512, K=512 shapes) ========
__global__ __launch_bounds__(256) void bgemm64(
    const u16* __restrict__ A, int lda,
    const u16* __restrict__ B, int ldb,
    u16* __restrict__ C, int ldc, int K,
    const float* __restrict__ bias, float alpha,
    const u16* __restrict__ resid)
{
    int n0 = blockIdx.x * 64;
    int m0 = blockIdx.y * 64;

    __shared__ u16 As[64*64];
    __shared__ u16 Bs[64*64];

    int t = threadIdx.x;
    int w = t >> 6, l = t & 63;
    int lrow = l >> 3, lslot = l & 7;
    int kswz = (lslot ^ lrow) * 8;
    int wm = w >> 1, wn = w & 1;
    int lr = l & 15, lk = l >> 4;

    f32x4 acc[2][2] = {};

    for (int k0 = 0; k0 < K; k0 += 64){
        #pragma unroll
        for (int it = 0; it < 2; ++it){
            int rb = it*32 + w*8;
            gld16(A + (size_t)(m0 + rb + lrow)*lda + k0 + kswz, &As[rb*64]);
            gld16(B + (size_t)(n0 + rb + lrow)*ldb + k0 + kswz, &Bs[rb*64]);
        }
        __syncthreads();

        s8v af[2][2], bf[2][2];
        #pragma unroll
        for (int kh = 0; kh < 2; ++kh){
            int sl = (kh*4 + lk) ^ (lr & 7);
            #pragma unroll
            for (int mi = 0; mi < 2; ++mi)
                af[kh][mi] = *(const s8v*)&As[(wm*32 + mi*16 + lr)*64 + sl*8];
            #pragma unroll
            for (int ni = 0; ni < 2; ++ni)
                bf[kh][ni] = *(const s8v*)&Bs[(wn*32 + ni*16 + lr)*64 + sl*8];
        }
        #pragma unroll
        for (int kh = 0; kh < 2; ++kh)
            #pragma unroll
            for (int mi = 0; mi < 2; ++mi)
                #pragma unroll
                for (int ni = 0; ni < 2; ++ni)
                    acc[mi][ni] = __builtin_amdgcn_mfma_f32_16x16x32_bf16(
                        af[kh][mi], bf[kh][ni], acc[mi][ni], 0, 0, 0);
        __syncthreads();
    }

    #pragma unroll
    for (int mi = 0; mi < 2; ++mi){
        #pragma unroll
        for (int ni = 0; ni < 2; ++ni){
            int gn = n0 + wn*32 + ni*16 + lr;
            float bval = bias ? bias[gn] : 0.0f;
            #pragma unroll
            for (int r = 0; r < 4; ++r){
                int gm = m0 + wm*32 + mi*16 + lk*4 + r;
                float vv = (acc[mi][ni][r] + bval) * alpha;
                if (resid) vv += b2f(resid[(size_t)gm*ldc + gn]);
                C[(size_t)gm*ldc + gn] = f2b(vv);
            }
        }
    }
}

// ================= 64x64-tile MFMA GEMM, BK=128 (K=2048 shapes) ==============
__global__ __launch_bounds__(256) void bgemm64k(
    const u16* __restrict__ A, int lda,
    const u16* __restrict__ B, int ldb,
    u16* __restrict__ C, int ldc, int K,
    const float* __restrict__ bias, float alpha,
    const float* __restrict__ residF, const u16* __restrict__ residB)
{
    int n0 = blockIdx.x * 64;
    int m0 = blockIdx.y * 64;

    __shared__ u16 As[64*128];    // 16 KB
    __shared__ u16 Bs[64*128];    // 16 KB

    int t = threadIdx.x;
    int w = t >> 6, l = t & 63;
    int r4 = l >> 4;
    int s16 = l & 15;
    int kswz = (s16 ^ (w*4 + r4)) * 8;
    int wm = w >> 1, wn = w & 1;
    int lr = l & 15, lk = l >> 4;

    f32x4 acc[2][2] = {};

    for (int k0 = 0; k0 < K; k0 += 128){
        #pragma unroll
        for (int cb = 0; cb < 4; ++cb){
            int rowu = cb*16 + w*4;
            gld16(A + (size_t)(m0 + rowu + r4)*lda + k0 + kswz, &As[rowu*128]);
            gld16(B + (size_t)(n0 + rowu + r4)*ldb + k0 + kswz, &Bs[rowu*128]);
        }
        __syncthreads();

        #pragma unroll
        for (int kh = 0; kh < 4; ++kh){
            int sl = ((kh*4 + lk) ^ lr) * 8;
            s8v af[2], bf[2];
            #pragma unroll
            for (int mi = 0; mi < 2; ++mi)
                af[mi] = *(const s8v*)&As[(wm*32 + mi*16 + lr)*128 + sl];
            #pragma unroll
            for (int ni = 0; ni < 2; ++ni)
                bf[ni] = *(const s8v*)&Bs[(wn*32 + ni*16 + lr)*128 + sl];
            #pragma unroll
            for (int mi = 0; mi < 2; ++mi)
                #pragma unroll
                for (int ni = 0; ni < 2; ++ni)
                    acc[mi][ni] = __builtin_amdgcn_mfma_f32_16x16x32_bf16(
                        af[mi], bf[ni], acc[mi][ni], 0, 0, 0);
        }
        __syncthreads();
    }

    #pragma unroll
    for (int mi = 0; mi < 2; ++mi){
        #pragma unroll
        for (int ni = 0; ni < 2; ++ni){
            int gn = n0 + wn*32 + ni*16 + lr;
            float bval = bias ? bias[gn] : 0.0f;
            #pragma unroll
            for (int r = 0; r < 4; ++r){
                int gm = m0 + wm*32 + mi*16 + lk*4 + r;
                float vv = (acc[mi][ni][r] + bval) * alpha;
                size_t idx = (size_t)gm*ldc + gn;
                if (residF) vv += residF[idx];
                if (residB) vv += b2f(residB[idx]);
                C[idx] = f2b(vv);
            }
        }
    }
}

// ================= fused rel-pos flash attention =================
// 1D grid 512, XCD-aware: s = xcd + 8*(zhi*16 + xx); all 16 i-blocks of a z
// (and the 4 z's sharing head hh=xcd per octave) land on one XCD -> K/V/P
// L2-resident. Fixed-offset base-2 softmax; diagonal band, bank-hashed.
__global__ __launch_bounds__(256) void attn_fused(
    const u16* __restrict__ qub, const u16* __restrict__ qvb,
    const u16* __restrict__ kb,  const u16* __restrict__ vt,
    const u16* __restrict__ pp,  u16* __restrict__ out)
{
    int s   = blockIdx.x;
    int xcd = s & 7;
    int k9  = s >> 3;            // 0..63
    int zhi = k9 >> 4;           // 0..3  = b
    int xx  = k9 & 15;           // i-block
    int z   = (zhi << 3) | xcd;  // b*8 + hh
    int b = zhi, hh = xcd;
    int i0 = xx * 64;

    __shared__ u16 Kb2[2][64*64];     // 16 KB
    __shared__ u16 Vb2[2][64*64];     // 16 KB
    __shared__ u16 Pring[3][64*64];   // 24 KB
    __shared__ u16 PT[64*64];         //  8 KB
    __shared__ float Bandd[4][1024];  // 16 KB per-wave [64 diag][16 hashed]

    int t = threadIdx.x;
    int w = t >> 6, l = t & 63;
    int lrow = l >> 3, lslot = l & 7;
    int kswz = (lslot ^ lrow) * 8;
    int lr = l & 15, lk = l >> 4;

    // ---- prologue: qu -> PT, qv -> Bandd (as u16), frags to regs ----
    #pragma unroll
    for (int it = 0; it < 2; ++it){
        int rb = it*32 + w*8;
        gld16(qub + (size_t)(b*TT + i0 + rb + lrow)*DD + hh*64 + kswz, &PT[rb*64]);
        gld16(qvb + (size_t)(b*TT + i0 + rb + lrow)*DD + hh*64 + kswz,
              (u16*)&Bandd[0][0] + rb*64);
    }
    __syncthreads();
    s8v af_u[2], af_v[2];
    #pragma unroll
    for (int kh = 0; kh < 2; ++kh){
        int sl = (kh*4 + lk) ^ (lr & 7);
        af_u[kh] = *(const s8v*)&PT[(w*16 + lr)*64 + sl*8];
        af_v[kh] = *(const s8v*)((const u16*)&Bandd[0][0] + (w*16 + lr)*64 + sl*8);
    }
    // stage K_0 -> Kb2[0], V_0 -> Vb2[0], P chunks 0,1 -> ring
    #pragma unroll
    for (int it = 0; it < 2; ++it){
        int rb = it*32 + w*8;
        gld16(kb + (size_t)(b*TT +        rb + lrow)*DD + hh*64 + kswz, &Kb2[0][rb*64]);
        gld16(vt + ((size_t)z*64 + rb + lrow)*TT +                kswz, &Vb2[0][rb*64]);
        gld16(pp + (size_t)(960  - i0 +   rb + lrow)*DD + hh*64 + kswz, &Pring[0][rb*64]);
        gld16(pp + (size_t)(1024 - i0 +   rb + lrow)*DD + hh*64 + kswz, &Pring[1][rb*64]);
    }

    f32x4 o_[4] = {};
    float Lp[4] = {0.f, 0.f, 0.f, 0.f};   // per-lane partial denominators

    int s0 = 0, s1 = 1, s2 = 2;

    for (int jt = 0; jt < 16; ++jt){
        int cur = jt & 1;
        __syncthreads();  // all staged loads for THIS iter have landed

        // issue next-iter staging (full-iteration landing window)
        if (jt < 15){
            #pragma unroll
            for (int it = 0; it < 2; ++it){
                int rb = it*32 + w*8;
                gld16(kb + (size_t)(b*TT + (jt+1)*64 + rb + lrow)*DD + hh*64 + kswz,
                      &Kb2[cur^1][rb*64]);
                gld16(vt + ((size_t)z*64 + rb + lrow)*TT + (jt+1)*64 + kswz,
                      &Vb2[cur^1][rb*64]);
                gld16(pp + (size_t)(960 + (jt+2)*64 - i0 + rb + lrow)*DD + hh*64 + kswz,
                      &Pring[s2][rb*64]);
            }
        }

        // ---- S_ac (16x64) and band G (16x80) per wave ----
        f32x4 sac[4] = {};
        f32x4 g[5] = {};
        __builtin_amdgcn_s_setprio(1);
        #pragma unroll
        for (int kh = 0; kh < 2; ++kh){
            int sl = (kh*4 + lk) ^ (lr & 7);
            #pragma unroll
            for (int n = 0; n < 4; ++n){
                s8v bK = *(const s8v*)&Kb2[cur][(n*16 + lr)*64 + sl*8];
                sac[n] = __builtin_amdgcn_mfma_f32_16x16x32_bf16(af_u[kh], bK, sac[n], 0,0,0);
            }
            #pragma unroll
            for (int n = 0; n < 5; ++n){
                int nn = (3 - w) + n;
                const u16* pc = (nn & 4) ? &Pring[s1][0] : &Pring[s0][0];
                s8v bP = *(const s8v*)&pc[(((nn&3)*16) + lr)*64 + sl*8];
                g[n] = __builtin_amdgcn_mfma_f32_16x16x32_bf16(af_v[kh], bP, g[n], 0,0,0);
            }
        }
        __builtin_amdgcn_s_setprio(0);

        // ---- band write: diagonal-major, bank-hashed, packed b128 ----
        #pragma unroll
        for (int n = 0; n < 4; ++n){
            int c = (3 - w + n)*16 + lr;
            int d = (c - 63) & 63;
            int rho = (d >> 2) & 3;
            f32x4 vv;
            if (n == 0){
                #pragma unroll
                for (int r = 0; r < 4; ++r){
                    int iia = w*16 + lk*4 + r;
                    vv[r] = (iia >= 63 - c) ? g[0][r] : g[4][r];
                }
            } else {
                vv = g[n];
            }
            bool sw1 = rho & 1, sw2 = rho & 2;
            float b0 = sw1 ? vv[1] : vv[0];
            float b1 = sw1 ? vv[0] : vv[1];
            float b2 = sw1 ? vv[3] : vv[2];
            float b3 = sw1 ? vv[2] : vv[3];
            f32x4 vvp;
            vvp[0] = sw2 ? b2 : b0;
            vvp[1] = sw2 ? b3 : b1;
            vvp[2] = sw2 ? b0 : b2;
            vvp[3] = sw2 ? b1 : b3;
            *(f32x4*)&Bandd[w][d*16 + ((lk + d) & 3)*4] = vvp;
        }

        // ---- combine band + fixed-offset exp2 (wave-local, no shuffles) ----
        float p_[4][4];
        #pragma unroll
        for (int r = 0; r < 4; ++r){
            int ii_l = lk*4 + r;
            float rs = 0.0f;
            #pragma unroll
            for (int n = 0; n < 4; ++n){
                int jj = n*16 + lr;
                int d  = (jj - 16*w - ii_l) & 63;
                float bd = Bandd[w][d*16 + (((ii_l>>2) + d) & 3)*4
                                         + ((ii_l ^ (d>>2)) & 3)];
                float pv = __builtin_amdgcn_exp2f(sac[n][r] + bd - M0OFF);
                p_[n][r] = pv; rs += pv;
            }
            Lp[r] += rs;
        }

        // write P-tilde (swizzled bf16, wave-local rows; read by same wave only)
        #pragma unroll
        for (int n = 0; n < 4; ++n)
            #pragma unroll
            for (int r = 0; r < 4; ++r){
                int ii  = w*16 + lk*4 + r;
                int col = n*16 + lr;
                int sl  = (col>>3) ^ (ii&7);
                PT[ii*64 + sl*8 + (col&7)] = f2b(p_[n][r]);
            }

        // ---- PV (V_jt landed at this iter's top barrier) ----
        __builtin_amdgcn_s_setprio(1);
        #pragma unroll
        for (int kh = 0; kh < 2; ++kh){
            int sl = (kh*4 + lk) ^ (lr & 7);
            s8v ap = *(const s8v*)&PT[(w*16 + lr)*64 + sl*8];
            #pragma unroll
            for (int n = 0; n < 4; ++n){
                s8v bV = *(const s8v*)&Vb2[cur][(n*16 + lr)*64 + sl*8];
                o_[n] = __builtin_amdgcn_mfma_f32_16x16x32_bf16(ap, bV, o_[n], 0,0,0);
            }
        }
        __builtin_amdgcn_s_setprio(0);
        int tmp = s0; s0 = s1; s1 = s2; s2 = tmp;
    }

    // ---- one-time L reduction across the 16-lane col group ----
    float Lr[4];
    #pragma unroll
    for (int r = 0; r < 4; ++r){
        float Lv = Lp[r];
        #pragma unroll
        for (int msk = 1; msk < 16; msk <<= 1) Lv += __shfl_xor(Lv, msk);
        Lr[r] = 1.0f / Lv;
    }

    #pragma unroll
    for (int n = 0; n < 4; ++n)
        #pragma unroll
        for (int r = 0; r < 4; ++r){
            int i  = i0 + w*16 + lk*4 + r;
            int dk = n*16 + lr;
            out[(size_t)(b*TT + i)*DD + hh*64 + dk] = f2b(o_[n][r] * Lr[r]);
        }
}

// ================= LayerNorm: wave per row, shuffle reduce =====
// IB: 1 = bf16 input, 0 = f32 input.  OB: 1 = bf16 out, 0 = f32 out.
template<int IB, int OB>
__global__ __launch_bounds__(256) void ln_kernel(const void* __restrict__ inp,
    const float* __restrict__ g, const float* __restrict__ b, void* __restrict__ outv)
{
    int w = threadIdx.x >> 6, l = threadIdx.x & 63;
    int row = blockIdx.x*4 + w;
    float v[8];
    if (IB){
        us8 xv = ((const us8*)((const u16*)inp + (size_t)row*DD))[l];
        #pragma unroll
        for (int e=0;e<8;e++) v[e] = b2f(xv[e]);
    } else {
        const float4* xr = (const float4*)((const float*)inp + (size_t)row*DD);
        float4 a = xr[2*l], c = xr[2*l+1];
        v[0]=a.x; v[1]=a.y; v[2]=a.z; v[3]=a.w;
        v[4]=c.x; v[5]=c.y; v[6]=c.z; v[7]=c.w;
    }
    float s = 0.f, q = 0.f;
    #pragma unroll
    for (int e=0;e<8;e++){ s += v[e]; q += v[e]*v[e]; }
    #pragma unroll
    for (int msk = 1; msk < 64; msk <<= 1){
        s += __shfl_xor(s, msk);
        q += __shfl_xor(q, msk);
    }
    float mean = s*(1.0f/DD);
    float var  = q*(1.0f/DD) - mean*mean;
    float rinv = rsqrtf(var+EPSF);
    float4 g0 = ((const float4*)g)[2*l], g1 = ((const float4*)g)[2*l+1];
    float4 b0 = ((const float4*)b)[2*l], b1 = ((const float4*)b)[2*l+1];
    float gv[8] = {g0.x,g0.y,g0.z,g0.w,g1.x,g1.y,g1.z,g1.w};
    float bv[8] = {b0.x,b0.y,b0.z,b0.w,b1.x,b1.y,b1.z,b1.w};
    float y[8];
    #pragma unroll
    for (int e=0;e<8;e++) y[e] = (v[e]-mean)*rinv*gv[e] + bv[e];
    if (OB){
        us8 o;
        #pragma unroll
        for (int e=0;e<8;e++) o[e] = f2b(y[e]);
        ((us8*)((u16*)outv + (size_t)row*DD))[l] = o;
    } else {
        float4 o0 = {y[0],y[1],y[2],y[3]};
        float4 o1 = {y[4],y[5],y[6],y[7]};
        float4* op = (float4*)((float*)outv + (size_t)row*DD);
        op[2*l] = o0; op[2*l+1] = o1;
    }
}

// ============ consolidated weight prep + ln1 + stats zero (ONE kernel) ======
struct Prep9 {
    const float* s[9];
    u16* d[9];
    int R[9], C[9];
    int t0[10];
};

__global__ __launch_bounds__(256) void prep_all(Prep9 P,
    const float* __restrict__ pw1_w, const float* __restrict__ pw2_w,
    const float* __restrict__ pos_emb, const float* __restrict__ dw_w,
    const float* __restrict__ bq, const float* __restrict__ bk,
    const float* __restrict__ bv,
    u16* __restrict__ pw1b, u16* __restrict__ pw2b,
    u16* __restrict__ posb, float* __restrict__ wt, float* __restrict__ bqkv,
    const float* __restrict__ x, const float* __restrict__ ln1_g,
    const float* __restrict__ ln1_b, u16* __restrict__ xn,
    float* __restrict__ stats)
{
    __shared__ float tile[32][33];
    int bid = blockIdx.x;
    if (bid < 5376){
        int j = 0;
        #pragma unroll
        for (int e=1; e<9; e++) if (bid >= P.t0[e]) j = e;
        int lb = bid - P.t0[j];
        int nx = P.C[j] >> 5;
        int c0 = (lb % nx) << 5;
        int r0 = (lb / nx) << 5;
        const float* in = P.s[j];
        u16* out = P.d[j];
        int R = P.R[j], C = P.C[j];
        int tx = threadIdx.x & 31, ty = threadIdx.x >> 5;
        #pragma unroll
        for (int i=0;i<4;i++){
            int rr = ty + i*8;
            tile[rr][tx] = in[(size_t)(r0+rr)*C + c0+tx];
        }
        __syncthreads();
        #pragma unroll
        for (int i=0;i<4;i++){
            int cc = ty + i*8;
            out[(size_t)(c0+cc)*R + r0+tx] = f2b(tile[tx][cc]);
        }
        return;
    }
    if (bid >= 12612 && bid < 13636){
        // ln1: wave per row over x (f32) -> xn (bf16)
        int w = threadIdx.x >> 6, l = threadIdx.x & 63;
        int row = (bid - 12612)*4 + w;
        const float4* xr = (const float4*)(x + (size_t)row*DD);
        float4 a = xr[2*l], c = xr[2*l+1];
        float v[8] = {a.x,a.y,a.z,a.w,c.x,c.y,c.z,c.w};
        float s = 0.f, q = 0.f;
        #pragma unroll
        for (int e=0;e<8;e++){ s += v[e]; q += v[e]*v[e]; }
        #pragma unroll
        for (int msk = 1; msk < 64; msk <<= 1){
            s += __shfl_xor(s, msk);
            q += __shfl_xor(q, msk);
        }
        float mean = s*(1.0f/DD);
        float var  = q*(1.0f/DD) - mean*mean;
        float rinv = rsqrtf(var+EPSF);
        float4 g0 = ((const float4*)ln1_g)[2*l], g1 = ((const float4*)ln1_g)[2*l+1];
        float4 b0 = ((const float4*)ln1_b)[2*l], b1 = ((const float4*)ln1_b)[2*l+1];
        float gv[8] = {g0.x,g0.y,g0.z,g0.w,g1.x,g1.y,g1.z,g1.w};
        float bv[8] = {b0.x,b0.y,b0.z,b0.w,b1.x,b1.y,b1.z,b1.w};
        us8 o;
        #pragma unroll
        for (int e=0;e<8;e++) o[e] = f2b((v[e]-mean)*rinv*gv[e] + bv[e]);
        ((us8*)(xn + (size_t)row*DD))[l] = o;
        return;
    }
    if (bid >= 13636){
        // zero BN stats (1024 f32)
        int i = threadIdx.x;
        stats[i] = 0.0f; stats[256+i] = 0.0f; stats[512+i] = 0.0f; stats[768+i] = 0.0f;
        return;
    }
    int i = (bid - 5376)*256 + threadIdx.x;
    if (i < 524288) { pw1b[i] = f2b(pw1_w[i]); return; }
    i -= 524288;
    if (i < 262144) { pw2b[i] = f2b(pw2_w[i]); return; }
    i -= 262144;
    if (i < 1048576) { posb[i] = (i < 2047*512) ? f2b(pos_emb[i]) : (u16)0; return; }
    i -= 1048576;
    if (i < 15872) { int kk = i >> 9, d = i & 511; wt[i] = dw_w[d*31+kk]; return; }
    i -= 15872;
    if (i < 1536) bqkv[i] = (i < 512) ? bq[i] : (i < 1024 ? bk[i-512] : bv[i-1024]);
}

// ================= conv-module =================
// depthwise conv K=31, GLU fused, BN-stats fused (f32 atomics into zeroed stats)
__global__ __launch_bounds__(256) void dwconv_kernel(const unsigned int* __restrict__ t2i,
    const float* __restrict__ wt, const float* __restrict__ bias, u16* __restrict__ z,
    float* __restrict__ stats)
{
    int d  = blockIdx.x*256 + threadIdx.x;   // gridDim.x = 2
    int c  = blockIdx.y;                     // 0..511
    int b  = c >> 7;
    int t0 = (c & 127) << 3;
    const unsigned int* pa = t2i + (size_t)b*TT*512 + d;
    float wv[31];
    #pragma unroll
    for (int kk=0;kk<31;kk++) wv[kk] = wt[kk*512 + d];
    float xv[38];
    #pragma unroll
    for (int e=0;e<38;e++){
        int tp = t0 - 15 + e;
        if (tp >= 0 && tp < TT){
            unsigned int pv = pa[(size_t)tp*512];
            float a  = b2f((u16)(pv & 0xffffu));
            float gg = b2f((u16)(pv >> 16));
            xv[e] = a * sigmoidf_(gg);
        } else xv[e] = 0.0f;
    }
    float bsv = bias[d];
    float s = 0.f, q = 0.f;
    #pragma unroll
    for (int j=0;j<8;j++){
        float sum = bsv;
        #pragma unroll
        for (int kk=0;kk<31;kk++) sum = fmaf(xv[j+kk], wv[kk], sum);
        z[(size_t)(b*TT+t0+j)*DD + d] = f2b(sum);
        s += sum; q += sum*sum;
    }
    atomicAdd(&stats[d],       s);
    atomicAdd(&stats[512 + d], q);
}

__global__ __launch_bounds__(256) void bn_apply_kernel(const u16* __restrict__ z,
    const float* __restrict__ stats, const float* __restrict__ g, const float* __restrict__ b,
    u16* __restrict__ out)
{
    int idx = blockIdx.x*256 + threadIdx.x;
    int c = idx & (DD-1);
    float m   = stats[c]*(1.0f/NTOK);
    float var = stats[DD+c]*(1.0f/NTOK) - m*m;
    float vv  = (b2f(z[idx])-m)*rsqrtf(var+EPSF)*g[c] + b[c];
    out[idx]  = f2b(vv*sigmoidf_(vv));
}

extern "C" void kernel_launch(void* const* d_in, const int* in_sizes, int n_in,
                              void* d_out, int out_size, void* d_ws, size_t ws_size,
                              hipStream_t stream)
{
    const float* x       = (const float*)d_in[0];
    const float* pos_emb = (const float*)d_in[1];
    const float* ln1_g=(const float*)d_in[2],  *ln1_b=(const float*)d_in[3];
    const float* ln2_g=(const float*)d_in[4],  *ln2_b=(const float*)d_in[5];
    const float* ln3_g=(const float*)d_in[6],  *ln3_b=(const float*)d_in[7];
    const float* ln4_g=(const float*)d_in[8],  *ln4_b=(const float*)d_in[9];
    const float* ln5_g=(const float*)d_in[10], *ln5_b=(const float*)d_in[11];
    const float* ff1_w1=(const float*)d_in[12], *ff1_b1=(const float*)d_in[13];
    const float* ff1_w2=(const float*)d_in[14], *ff1_b2=(const float*)d_in[15];
    const float* wq=(const float*)d_in[16], *bq=(const float*)d_in[17];
    const float* wk=(const float*)d_in[18], *bk=(const float*)d_in[19];
    const float* wv=(const float*)d_in[20], *bv=(const float*)d_in[21];
    const float* wp=(const float*)d_in[22];
    const float* wo=(const float*)d_in[23], *bo=(const float*)d_in[24];
    const float* pos_u=(const float*)d_in[25], *pos_v=(const float*)d_in[26];
    const float* pw1_w=(const float*)d_in[27], *pw1_b=(const float*)d_in[28];
    const float* dw_w=(const float*)d_in[29],  *dw_b=(const float*)d_in[30];
    const float* bn_g=(const float*)d_in[31],  *bn_b=(const float*)d_in[32];
    const float* pw2_w=(const float*)d_in[33], *pw2_b=(const float*)d_in[34];
    const float* ff2_w1=(const float*)d_in[35], *ff2_b1=(const float*)d_in[36];
    const float* ff2_w2=(const float*)d_in[37], *ff2_b2=(const float*)d_in[38];

    char* W = (char*)d_ws;
    u16*  h     = (u16*) (W);                   // 4 MB bf16 residual stream
    u16*  xn    = (u16*) (W + (size_t) 8*MB);   // 4 MB (ln out / attn out)
    u16*  wall  = (u16*) (W + (size_t)12*MB);   // 16 MB prepped weights
    u16*  qub   = (u16*) (W + (size_t)28*MB);   // qub/qvb/kb/vt contiguous
    u16*  qvb   = (u16*) (W + (size_t)32*MB);
    u16*  kb    = (u16*) (W + (size_t)36*MB);
    u16*  vt    = (u16*) (W + (size_t)40*MB);   // (B,H,DK,T)
    u16*  pproj = (u16*) (W + (size_t)44*MB);   // 2048x512
    char* big   = W + (size_t)48*MB;            // shared region
    u16*  ffh   = (u16*)big;                    // 16 MB FFN hidden
    unsigned int* t2i = (unsigned int*)big;     // 8 MB conv (a,g) pairs
    u16*  t3u   = (u16*)(big + (size_t)8*MB);   // 4 MB dwconv out (bf16)
    float* stats= (float*)(W + (size_t)112*MB); // 4 KB (atomics; zeroed in prep)
    float* wt   = stats + 4096;                 // (31,512) f32
    float* bqkv = wt + 15872;                   // 1536 f32

    u16* ff1w1T = wall;
    u16* ff1w2T = wall + 1048576;
    u16* wqT    = wall + 2097152;   // wq/wk/wv contiguous -> N=1536 merged GEMM
    u16* wkT    = wall + 2359296;
    u16* wvT    = wall + 2621440;
    u16* wpT    = wall + 2883584;
    u16* woT    = wall + 3145728;
    u16* ff2w1T = wall + 3407872;
    u16* ff2w2T = wall + 4456448;
    u16* pw1b   = wall + 5505024;
    u16* pw2b   = wall + 6029312;
    u16* posb   = wall + 6291456;

    dim3 blk(256);

    // ---------------- weight prep + ln1 + stats zero (1 launch) -------------
    Prep9 P;
    P.s[0]=ff1_w1; P.d[0]=ff1w1T; P.R[0]=512;  P.C[0]=2048;
    P.s[1]=ff1_w2; P.d[1]=ff1w2T; P.R[1]=2048; P.C[1]=512;
    P.s[2]=wq;     P.d[2]=wqT;    P.R[2]=512;  P.C[2]=512;
    P.s[3]=wk;     P.d[3]=wkT;    P.R[3]=512;  P.C[3]=512;
    P.s[4]=wv;     P.d[4]=wvT;    P.R[4]=512;  P.C[4]=512;
    P.s[5]=wp;     P.d[5]=wpT;    P.R[5]=512;  P.C[5]=512;
    P.s[6]=wo;     P.d[6]=woT;    P.R[6]=512;  P.C[6]=512;
    P.s[7]=ff2_w1; P.d[7]=ff2w1T; P.R[7]=512;  P.C[7]=2048;
    P.s[8]=ff2_w2; P.d[8]=ff2w2T; P.R[8]=2048; P.C[8]=512;
    int tc[9] = {1024,1024,256,256,256,256,256,1024,1024};
    P.t0[0]=0; for (int e=0;e<9;e++) P.t0[e+1]=P.t0[e]+tc[e];
    prep_all<<<dim3(13637), blk, 0, stream>>>(P, pw1_w, pw2_w, pos_emb, dw_w,
                                              bq, bk, bv,
                                              pw1b, pw2b, posb, wt, bqkv,
                                              x, ln1_g, ln1_b, xn, stats);

    // ---------------- FFN1: h = x + 0.5*ffn(ln1(x)) ----------------
    bgemm128<1><<<dim3(16,32), blk, 0, stream>>>(xn,512, ff1w1T,512,
        ffh,2048, 512, ff1_b1,1);
    bgemm64k<<<dim3(8,64), blk, 0, stream>>>(ffh,2048, ff1w2T,2048,
        h,512, 2048, ff1_b2,0.5f, x, nullptr);

    // ---------------- Attention: h = h + attn(ln2(h)) ----------------
    ln_kernel<1,1><<<dim3(NTOK/4), blk, 0, stream>>>(h, ln2_g, ln2_b, xn);
    qkvp_gemm<<<dim3(16,32), blk, 0, stream>>>(xn, wqT, posb, wpT,
        qub, pproj, bqkv, pos_u, pos_v);

    attn_fused<<<dim3(512), blk, 0, stream>>>(qub, qvb, kb, vt, pproj, xn);

    bgemm64<<<dim3(8,64), blk, 0, stream>>>(xn,512, woT,512,
        h,512, 512, bo,1.f, h);

    // ---------------- Conv module ----------------
    ln_kernel<1,1><<<dim3(NTOK/4), blk, 0, stream>>>(h, ln3_g, ln3_b, xn);
    bgemm128<6><<<dim3(8,32), blk, 0, stream>>>(xn,512, pw1b,512,
        t2i,1024, 512, pw1_b,0);
    dwconv_kernel<<<dim3(2,512), blk, 0, stream>>>(t2i, wt, dw_b, t3u, stats);
    bn_apply_kernel<<<dim3(NTOK*DD/256), blk, 0, stream>>>(t3u, stats, bn_g, bn_b, xn);
    bgemm64<<<dim3(8,64), blk, 0, stream>>>(xn,512, pw2b,512,
        h,512, 512, pw2_b,1.f, h);

    // ---------------- FFN2 ----------------
    ln_kernel<1,1><<<dim3(NTOK/4), blk, 0, stream>>>(h, ln4_g, ln4_b, xn);
    bgemm128<1><<<dim3(16,32), blk, 0, stream>>>(xn,512, ff2w1T,512,
        ffh,2048, 512, ff2_b1,1);
    bgemm64k<<<dim3(8,64), blk, 0, stream>>>(ffh,2048, ff2w2T,2048,
        h,512, 2048, ff2_b2,0.5f, nullptr, h);

    // ---------------- Final LN ----------------
    ln_kernel<1,0><<<dim3(NTOK/4), blk, 0, stream>>>(h, ln5_g, ln5_b, (float*)d_out);
}

// Round 14
// 258.119 us; speedup vs baseline: 1.7638x; 1.0127x over previous
//
#include <hip/hip_runtime.h>
#include <math.h>

#define TT   1024
#define BBZ  4
#define DD   512
#define DFF_ 2048
#define HH   8
#define DKK  64
#define NTOK 4096
#define EPSF 1e-5f
#define MB   1048576
// 0.125 * log2(e): scores produced directly in log2 domain
#define QSCALE 0.18033688011112042f
#define M0OFF  24.0f

typedef unsigned short u16;
typedef __attribute__((ext_vector_type(8))) short s8v;    // 8 bf16 (4 VGPRs)
typedef __attribute__((ext_vector_type(4))) float f32x4;
typedef __attribute__((ext_vector_type(4))) unsigned short us4;
typedef __attribute__((ext_vector_type(8))) unsigned short us8;

__device__ __forceinline__ float b2f(u16 v){
    union { unsigned int u; float f; } x; x.u = ((unsigned int)v) << 16; return x.f;
}
__device__ __forceinline__ u16 f2b(float f){
    union { float f; unsigned int u; } x; x.f = f;
    unsigned int r = x.u + 0x7fffu + ((x.u >> 16) & 1u);
    return (u16)(r >> 16);
}
__device__ __forceinline__ float sigmoidf_(float x){ return 1.0f/(1.0f+__expf(-x)); }

__device__ __forceinline__ void gld16(const u16* g, u16* l){
    __builtin_amdgcn_global_load_lds(
        (const __attribute__((address_space(1))) unsigned int*)g,
        (__attribute__((address_space(3))) unsigned int*)l, 16, 0, 0);
}

// ================= 128x128-tile MFMA GEMM, BK=128 =================
// OMODE 1: bf16 out (+bias, act)
// OMODE 6: interleaved GLU-pair bf16 store: (row, d, a/g) for dwconv.
template<int OMODE>
__global__ __launch_bounds__(256) void bgemm128(
    const u16* __restrict__ A, int lda,
    const u16* __restrict__ B, int ldb,
    void* __restrict__ Cv, int ldc, int K,
    const float* __restrict__ bias, int act)
{
    int n0 = blockIdx.x * 128;
    int m0 = blockIdx.y * 128;

    __shared__ u16 As[128*128];   // 32 KB
    __shared__ u16 Bs[128*128];   // 32 KB

    int t = threadIdx.x;
    int w = t >> 6, l = t & 63;
    int r4 = l >> 4;
    int s16 = l & 15;
    int kswz = (s16 ^ (w*4 + r4)) * 8;
    int wm = w >> 1, wn = w & 1;
    int lr = l & 15, lk = l >> 4;

    f32x4 acc[4][4] = {};

    for (int k0 = 0; k0 < K; k0 += 128){
        #pragma unroll
        for (int cb = 0; cb < 8; ++cb){
            int rowu = cb*16 + w*4;
            gld16(A + (size_t)(m0 + rowu + r4)*lda + k0 + kswz, &As[rowu*128]);
            gld16(B + (size_t)(n0 + rowu + r4)*ldb + k0 + kswz, &Bs[rowu*128]);
        }
        __syncthreads();

        #pragma unroll
        for (int kh = 0; kh < 4; ++kh){
            int sl = ((kh*4 + lk) ^ lr) * 8;
            s8v af[4], bf[4];
            #pragma unroll
            for (int mi = 0; mi < 4; ++mi)
                af[mi] = *(const s8v*)&As[(wm*64 + mi*16 + lr)*128 + sl];
            #pragma unroll
            for (int ni = 0; ni < 4; ++ni)
                bf[ni] = *(const s8v*)&Bs[(wn*64 + ni*16 + lr)*128 + sl];
            #pragma unroll
            for (int mi = 0; mi < 4; ++mi)
                #pragma unroll
                for (int ni = 0; ni < 4; ++ni)
                    acc[mi][ni] = __builtin_amdgcn_mfma_f32_16x16x32_bf16(
                        af[mi], bf[ni], acc[mi][ni], 0, 0, 0);
        }
        __syncthreads();
    }

    #pragma unroll
    for (int mi = 0; mi < 4; ++mi){
        #pragma unroll
        for (int ni = 0; ni < 4; ++ni){
            int gn = n0 + wn*64 + ni*16 + lr;
            float bval = bias ? bias[gn] : 0.0f;
            #pragma unroll
            for (int r = 0; r < 4; ++r){
                int gm = m0 + wm*64 + mi*16 + lk*4 + r;
                float vv = acc[mi][ni][r] + bval;
                if (act) vv = vv * sigmoidf_(vv);
                if (OMODE == 1){
                    ((u16*)Cv)[(size_t)gm*ldc + gn] = f2b(vv);
                } else { // 6: interleaved (a,g) bf16 pairs for dwconv
                    u16* base = (u16*)Cv;
                    size_t idx = (gn < 512)
                        ? ((size_t)gm*512 + gn)*2
                        : ((size_t)gm*512 + (gn-512))*2 + 1;
                    base[idx] = f2b(vv);
                }
            }
        }
    }
}

// ================= fused QKV + P-projection GEMM, BK=128 (one dispatch) =====
__global__ __launch_bounds__(256) void qkvp_gemm(
    const u16* __restrict__ xn, const u16* __restrict__ wqT,
    const u16* __restrict__ posb, const u16* __restrict__ wpT,
    u16* __restrict__ qkvbase, u16* __restrict__ pproj,
    const float* __restrict__ bqkv,
    const float* __restrict__ posu, const float* __restrict__ posv)
{
    bool isP = (blockIdx.x >= 12);
    if (isP && blockIdx.y >= 16) return;
    const u16* A = isP ? posb : xn;
    const u16* B = isP ? wpT : wqT;
    int n0 = isP ? (blockIdx.x - 12)*128 : blockIdx.x*128;
    int m0 = blockIdx.y * 128;

    __shared__ u16 As[128*128];
    __shared__ u16 Bs[128*128];

    int t = threadIdx.x;
    int w = t >> 6, l = t & 63;
    int r4 = l >> 4;
    int s16 = l & 15;
    int kswz = (s16 ^ (w*4 + r4)) * 8;
    int wm = w >> 1, wn = w & 1;
    int lr = l & 15, lk = l >> 4;

    f32x4 acc[4][4] = {};

    for (int k0 = 0; k0 < 512; k0 += 128){
        #pragma unroll
        for (int cb = 0; cb < 8; ++cb){
            int rowu = cb*16 + w*4;
            gld16(A + (size_t)(m0 + rowu + r4)*512 + k0 + kswz, &As[rowu*128]);
            gld16(B + (size_t)(n0 + rowu + r4)*512 + k0 + kswz, &Bs[rowu*128]);
        }
        __syncthreads();

        #pragma unroll
        for (int kh = 0; kh < 4; ++kh){
            int sl = ((kh*4 + lk) ^ lr) * 8;
            s8v af[4], bf[4];
            #pragma unroll
            for (int mi = 0; mi < 4; ++mi)
                af[mi] = *(const s8v*)&As[(wm*64 + mi*16 + lr)*128 + sl];
            #pragma unroll
            for (int ni = 0; ni < 4; ++ni)
                bf[ni] = *(const s8v*)&Bs[(wn*64 + ni*16 + lr)*128 + sl];
            #pragma unroll
            for (int mi = 0; mi < 4; ++mi)
                #pragma unroll
                for (int ni = 0; ni < 4; ++ni)
                    acc[mi][ni] = __builtin_amdgcn_mfma_f32_16x16x32_bf16(
                        af[mi], bf[ni], acc[mi][ni], 0, 0, 0);
        }
        __syncthreads();
    }

    #pragma unroll
    for (int mi = 0; mi < 4; ++mi){
        #pragma unroll
        for (int ni = 0; ni < 4; ++ni){
            int gn = n0 + wn*64 + ni*16 + lr;
            float bval = isP ? 0.0f : bqkv[gn];
            #pragma unroll
            for (int r = 0; r < 4; ++r){
                int gm = m0 + wm*64 + mi*16 + lk*4 + r;
                float vv = acc[mi][ni][r] + bval;
                if (isP){
                    pproj[(size_t)gm*512 + gn] = f2b(vv);
                } else {
                    u16* base = qkvbase;
                    if (gn < 512){
                        size_t idx = (size_t)gm*512 + gn;
                        base[idx]              = f2b((vv + posu[gn])*QSCALE);
                        base[idx + (2u<<20)]   = f2b((vv + posv[gn])*QSCALE);
                    } else if (gn < 1024){
                        base[(4u<<20) + (size_t)gm*512 + (gn-512)] = f2b(vv);
                    } else {
                        int gnp = gn - 1024;
                        int bb = gm >> 10, tt2 = gm & 1023;
                        size_t idx = (((size_t)(bb*8 + (gnp>>6)))*64 + (gnp&63))*1024 + tt2;
                        base[(6u<<20) + idx] = f2b(vv);
                    }
                }
            }
        }
    }
}

// ================= 64x64-tile MFMA GEMM, BK=128 (all N=512 shapes) ==========
// bf16 out: (acc+bias)*alpha + (f32 residF | bf16 residB).
__global__ __launch_bounds__(256) void bgemm64k(
    const u16* __restrict__ A, int lda,
    const u16* __restrict__ B, int ldb,
    u16* __restrict__ C, int ldc, int K,
    const float* __restrict__ bias, float alpha,
    const float* __restrict__ residF, const u16* __restrict__ residB)
{
    int n0 = blockIdx.x * 64;
    int m0 = blockIdx.y * 64;

    __shared__ u16 As[64*128];    // 16 KB
    __shared__ u16 Bs[64*128];    // 16 KB

    int t = threadIdx.x;
    int w = t >> 6, l = t & 63;
    int r4 = l >> 4;
    int s16 = l & 15;
    int kswz = (s16 ^ (w*4 + r4)) * 8;
    int wm = w >> 1, wn = w & 1;
    int lr = l & 15, lk = l >> 4;

    f32x4 acc[2][2] = {};

    for (int k0 = 0; k0 < K; k0 += 128){
        #pragma unroll
        for (int cb = 0; cb < 4; ++cb){
            int rowu = cb*16 + w*4;
            gld16(A + (size_t)(m0 + rowu + r4)*lda + k0 + kswz, &As[rowu*128]);
            gld16(B + (size_t)(n0 + rowu + r4)*ldb + k0 + kswz, &Bs[rowu*128]);
        }
        __syncthreads();

        #pragma unroll
        for (int kh = 0; kh < 4; ++kh){
            int sl = ((kh*4 + lk) ^ lr) * 8;
            s8v af[2], bf[2];
            #pragma unroll
            for (int mi = 0; mi < 2; ++mi)
                af[mi] = *(const s8v*)&As[(wm*32 + mi*16 + lr)*128 + sl];
            #pragma unroll
            for (int ni = 0; ni < 2; ++ni)
                bf[ni] = *(const s8v*)&Bs[(wn*32 + ni*16 + lr)*128 + sl];
            #pragma unroll
            for (int mi = 0; mi < 2; ++mi)
                #pragma unroll
                for (int ni = 0; ni < 2; ++ni)
                    acc[mi][ni] = __builtin_amdgcn_mfma_f32_16x16x32_bf16(
                        af[mi], bf[ni], acc[mi][ni], 0, 0, 0);
        }
        __syncthreads();
    }

    #pragma unroll
    for (int mi = 0; mi < 2; ++mi){
        #pragma unroll
        for (int ni = 0; ni < 2; ++ni){
            int gn = n0 + wn*32 + ni*16 + lr;
            float bval = bias ? bias[gn] : 0.0f;
            #pragma unroll
            for (int r = 0; r < 4; ++r){
                int gm = m0 + wm*32 + mi*16 + lk*4 + r;
                float vv = (acc[mi][ni][r] + bval) * alpha;
                size_t idx = (size_t)gm*ldc + gn;
                if (residF) vv += residF[idx];
                if (residB) vv += b2f(residB[idx]);
                C[idx] = f2b(vv);
            }
        }
    }
}

// ================= fused rel-pos flash attention =================
// 1D grid 512, XCD-aware: s = xcd + 8*(zhi*16 + xx); all 16 i-blocks of a z
// land on one XCD -> K/V/P L2-resident. Fixed-offset base-2 softmax;
// diagonal band, bank-hashed.
__global__ __launch_bounds__(256) void attn_fused(
    const u16* __restrict__ qub, const u16* __restrict__ qvb,
    const u16* __restrict__ kb,  const u16* __restrict__ vt,
    const u16* __restrict__ pp,  u16* __restrict__ out)
{
    int s   = blockIdx.x;
    int xcd = s & 7;
    int k9  = s >> 3;            // 0..63
    int zhi = k9 >> 4;           // 0..3  = b
    int xx  = k9 & 15;           // i-block
    int z   = (zhi << 3) | xcd;  // b*8 + hh
    int b = zhi, hh = xcd;
    int i0 = xx * 64;

    __shared__ u16 Kb2[2][64*64];     // 16 KB
    __shared__ u16 Vb2[2][64*64];     // 16 KB
    __shared__ u16 Pring[3][64*64];   // 24 KB
    __shared__ u16 PT[64*64];         //  8 KB
    __shared__ float Bandd[4][1024];  // 16 KB per-wave [64 diag][16 hashed]

    int t = threadIdx.x;
    int w = t >> 6, l = t & 63;
    int lrow = l >> 3, lslot = l & 7;
    int kswz = (lslot ^ lrow) * 8;
    int lr = l & 15, lk = l >> 4;

    // ---- prologue: qu -> PT, qv -> Bandd (as u16), frags to regs ----
    #pragma unroll
    for (int it = 0; it < 2; ++it){
        int rb = it*32 + w*8;
        gld16(qub + (size_t)(b*TT + i0 + rb + lrow)*DD + hh*64 + kswz, &PT[rb*64]);
        gld16(qvb + (size_t)(b*TT + i0 + rb + lrow)*DD + hh*64 + kswz,
              (u16*)&Bandd[0][0] + rb*64);
    }
    __syncthreads();
    s8v af_u[2], af_v[2];
    #pragma unroll
    for (int kh = 0; kh < 2; ++kh){
        int sl = (kh*4 + lk) ^ (lr & 7);
        af_u[kh] = *(const s8v*)&PT[(w*16 + lr)*64 + sl*8];
        af_v[kh] = *(const s8v*)((const u16*)&Bandd[0][0] + (w*16 + lr)*64 + sl*8);
    }
    // stage K_0 -> Kb2[0], V_0 -> Vb2[0], P chunks 0,1 -> ring
    #pragma unroll
    for (int it = 0; it < 2; ++it){
        int rb = it*32 + w*8;
        gld16(kb + (size_t)(b*TT +        rb + lrow)*DD + hh*64 + kswz, &Kb2[0][rb*64]);
        gld16(vt + ((size_t)z*64 + rb + lrow)*TT +                kswz, &Vb2[0][rb*64]);
        gld16(pp + (size_t)(960  - i0 +   rb + lrow)*DD + hh*64 + kswz, &Pring[0][rb*64]);
        gld16(pp + (size_t)(1024 - i0 +   rb + lrow)*DD + hh*64 + kswz, &Pring[1][rb*64]);
    }

    f32x4 o_[4] = {};
    float Lp[4] = {0.f, 0.f, 0.f, 0.f};   // per-lane partial denominators

    int s0 = 0, s1 = 1, s2 = 2;

    for (int jt = 0; jt < 16; ++jt){
        int cur = jt & 1;
        __syncthreads();  // all staged loads for THIS iter have landed

        // issue next-iter staging (full-iteration landing window)
        if (jt < 15){
            #pragma unroll
            for (int it = 0; it < 2; ++it){
                int rb = it*32 + w*8;
                gld16(kb + (size_t)(b*TT + (jt+1)*64 + rb + lrow)*DD + hh*64 + kswz,
                      &Kb2[cur^1][rb*64]);
                gld16(vt + ((size_t)z*64 + rb + lrow)*TT + (jt+1)*64 + kswz,
                      &Vb2[cur^1][rb*64]);
                gld16(pp + (size_t)(960 + (jt+2)*64 - i0 + rb + lrow)*DD + hh*64 + kswz,
                      &Pring[s2][rb*64]);
            }
        }

        // ---- S_ac (16x64) and band G (16x80) per wave ----
        f32x4 sac[4] = {};
        f32x4 g[5] = {};
        __builtin_amdgcn_s_setprio(1);
        #pragma unroll
        for (int kh = 0; kh < 2; ++kh){
            int sl = (kh*4 + lk) ^ (lr & 7);
            #pragma unroll
            for (int n = 0; n < 4; ++n){
                s8v bK = *(const s8v*)&Kb2[cur][(n*16 + lr)*64 + sl*8];
                sac[n] = __builtin_amdgcn_mfma_f32_16x16x32_bf16(af_u[kh], bK, sac[n], 0,0,0);
            }
            #pragma unroll
            for (int n = 0; n < 5; ++n){
                int nn = (3 - w) + n;
                const u16* pc = (nn & 4) ? &Pring[s1][0] : &Pring[s0][0];
                s8v bP = *(const s8v*)&pc[(((nn&3)*16) + lr)*64 + sl*8];
                g[n] = __builtin_amdgcn_mfma_f32_16x16x32_bf16(af_v[kh], bP, g[n], 0,0,0);
            }
        }
        __builtin_amdgcn_s_setprio(0);

        // ---- band write: diagonal-major, bank-hashed, packed b128 ----
        #pragma unroll
        for (int n = 0; n < 4; ++n){
            int c = (3 - w + n)*16 + lr;
            int d = (c - 63) & 63;
            int rho = (d >> 2) & 3;
            f32x4 vv;
            if (n == 0){
                #pragma unroll
                for (int r = 0; r < 4; ++r){
                    int iia = w*16 + lk*4 + r;
                    vv[r] = (iia >= 63 - c) ? g[0][r] : g[4][r];
                }
            } else {
                vv = g[n];
            }
            bool sw1 = rho & 1, sw2 = rho & 2;
            float b0 = sw1 ? vv[1] : vv[0];
            float b1 = sw1 ? vv[0] : vv[1];
            float b2 = sw1 ? vv[3] : vv[2];
            float b3 = sw1 ? vv[2] : vv[3];
            f32x4 vvp;
            vvp[0] = sw2 ? b2 : b0;
            vvp[1] = sw2 ? b3 : b1;
            vvp[2] = sw2 ? b0 : b2;
            vvp[3] = sw2 ? b1 : b3;
            *(f32x4*)&Bandd[w][d*16 + ((lk + d) & 3)*4] = vvp;
        }

        // ---- combine band + fixed-offset exp2 (wave-local, no shuffles) ----
        float p_[4][4];
        #pragma unroll
        for (int r = 0; r < 4; ++r){
            int ii_l = lk*4 + r;
            float rs = 0.0f;
            #pragma unroll
            for (int n = 0; n < 4; ++n){
                int jj = n*16 + lr;
                int d  = (jj - 16*w - ii_l) & 63;
                float bd = Bandd[w][d*16 + (((ii_l>>2) + d) & 3)*4
                                         + ((ii_l ^ (d>>2)) & 3)];
                float pv = __builtin_amdgcn_exp2f(sac[n][r] + bd - M0OFF);
                p_[n][r] = pv; rs += pv;
            }
            Lp[r] += rs;
        }

        // write P-tilde (swizzled bf16, wave-local rows; read by same wave only)
        #pragma unroll
        for (int n = 0; n < 4; ++n)
            #pragma unroll
            for (int r = 0; r < 4; ++r){
                int ii  = w*16 + lk*4 + r;
                int col = n*16 + lr;
                int sl  = (col>>3) ^ (ii&7);
                PT[ii*64 + sl*8 + (col&7)] = f2b(p_[n][r]);
            }

        // ---- PV (V_jt landed at this iter's top barrier) ----
        __builtin_amdgcn_s_setprio(1);
        #pragma unroll
        for (int kh = 0; kh < 2; ++kh){
            int sl = (kh*4 + lk) ^ (lr & 7);
            s8v ap = *(const s8v*)&PT[(w*16 + lr)*64 + sl*8];
            #pragma unroll
            for (int n = 0; n < 4; ++n){
                s8v bV = *(const s8v*)&Vb2[cur][(n*16 + lr)*64 + sl*8];
                o_[n] = __builtin_amdgcn_mfma_f32_16x16x32_bf16(ap, bV, o_[n], 0,0,0);
            }
        }
        __builtin_amdgcn_s_setprio(0);
        int tmp = s0; s0 = s1; s1 = s2; s2 = tmp;
    }

    // ---- one-time L reduction across the 16-lane col group ----
    float Lr[4];
    #pragma unroll
    for (int r = 0; r < 4; ++r){
        float Lv = Lp[r];
        #pragma unroll
        for (int msk = 1; msk < 16; msk <<= 1) Lv += __shfl_xor(Lv, msk);
        Lr[r] = 1.0f / Lv;
    }

    #pragma unroll
    for (int n = 0; n < 4; ++n)
        #pragma unroll
        for (int r = 0; r < 4; ++r){
            int i  = i0 + w*16 + lk*4 + r;
            int dk = n*16 + lr;
            out[(size_t)(b*TT + i)*DD + hh*64 + dk] = f2b(o_[n][r] * Lr[r]);
        }
}

// ================= LayerNorm: wave per row, shuffle reduce =====
// IB: 1 = bf16 input, 0 = f32 input.  OB: 1 = bf16 out, 0 = f32 out.
template<int IB, int OB>
__global__ __launch_bounds__(256) void ln_kernel(const void* __restrict__ inp,
    const float* __restrict__ g, const float* __restrict__ b, void* __restrict__ outv)
{
    int w = threadIdx.x >> 6, l = threadIdx.x & 63;
    int row = blockIdx.x*4 + w;
    float v[8];
    if (IB){
        us8 xv = ((const us8*)((const u16*)inp + (size_t)row*DD))[l];
        #pragma unroll
        for (int e=0;e<8;e++) v[e] = b2f(xv[e]);
    } else {
        const float4* xr = (const float4*)((const float*)inp + (size_t)row*DD);
        float4 a = xr[2*l], c = xr[2*l+1];
        v[0]=a.x; v[1]=a.y; v[2]=a.z; v[3]=a.w;
        v[4]=c.x; v[5]=c.y; v[6]=c.z; v[7]=c.w;
    }
    float s = 0.f, q = 0.f;
    #pragma unroll
    for (int e=0;e<8;e++){ s += v[e]; q += v[e]*v[e]; }
    #pragma unroll
    for (int msk = 1; msk < 64; msk <<= 1){
        s += __shfl_xor(s, msk);
        q += __shfl_xor(q, msk);
    }
    float mean = s*(1.0f/DD);
    float var  = q*(1.0f/DD) - mean*mean;
    float rinv = rsqrtf(var+EPSF);
    float4 g0 = ((const float4*)g)[2*l], g1 = ((const float4*)g)[2*l+1];
    float4 b0 = ((const float4*)b)[2*l], b1 = ((const float4*)b)[2*l+1];
    float gv[8] = {g0.x,g0.y,g0.z,g0.w,g1.x,g1.y,g1.z,g1.w};
    float bv[8] = {b0.x,b0.y,b0.z,b0.w,b1.x,b1.y,b1.z,b1.w};
    float y[8];
    #pragma unroll
    for (int e=0;e<8;e++) y[e] = (v[e]-mean)*rinv*gv[e] + bv[e];
    if (OB){
        us8 o;
        #pragma unroll
        for (int e=0;e<8;e++) o[e] = f2b(y[e]);
        ((us8*)((u16*)outv + (size_t)row*DD))[l] = o;
    } else {
        float4 o0 = {y[0],y[1],y[2],y[3]};
        float4 o1 = {y[4],y[5],y[6],y[7]};
        float4* op = (float4*)((float*)outv + (size_t)row*DD);
        op[2*l] = o0; op[2*l+1] = o1;
    }
}

// ============ consolidated weight prep + ln1 + stats zero (ONE kernel) ======
struct Prep9 {
    const float* s[9];
    u16* d[9];
    int R[9], C[9];
    int t0[10];
};

__global__ __launch_bounds__(256) void prep_all(Prep9 P,
    const float* __restrict__ pw1_w, const float* __restrict__ pw2_w,
    const float* __restrict__ pos_emb, const float* __restrict__ dw_w,
    const float* __restrict__ bq, const float* __restrict__ bk,
    const float* __restrict__ bv,
    u16* __restrict__ pw1b, u16* __restrict__ pw2b,
    u16* __restrict__ posb, float* __restrict__ wt, float* __restrict__ bqkv,
    const float* __restrict__ x, const float* __restrict__ ln1_g,
    const float* __restrict__ ln1_b, u16* __restrict__ xn,
    float* __restrict__ stats)
{
    __shared__ float tile[32][33];
    int bid = blockIdx.x;
    if (bid < 5376){
        int j = 0;
        #pragma unroll
        for (int e=1; e<9; e++) if (bid >= P.t0[e]) j = e;
        int lb = bid - P.t0[j];
        int nx = P.C[j] >> 5;
        int c0 = (lb % nx) << 5;
        int r0 = (lb / nx) << 5;
        const float* in = P.s[j];
        u16* out = P.d[j];
        int R = P.R[j], C = P.C[j];
        int tx = threadIdx.x & 31, ty = threadIdx.x >> 5;
        #pragma unroll
        for (int i=0;i<4;i++){
            int rr = ty + i*8;
            tile[rr][tx] = in[(size_t)(r0+rr)*C + c0+tx];
        }
        __syncthreads();
        #pragma unroll
        for (int i=0;i<4;i++){
            int cc = ty + i*8;
            out[(size_t)(c0+cc)*R + r0+tx] = f2b(tile[tx][cc]);
        }
        return;
    }
    if (bid >= 12612 && bid < 13636){
        // ln1: wave per row over x (f32) -> xn (bf16)
        int w = threadIdx.x >> 6, l = threadIdx.x & 63;
        int row = (bid - 12612)*4 + w;
        const float4* xr = (const float4*)(x + (size_t)row*DD);
        float4 a = xr[2*l], c = xr[2*l+1];
        float v[8] = {a.x,a.y,a.z,a.w,c.x,c.y,c.z,c.w};
        float s = 0.f, q = 0.f;
        #pragma unroll
        for (int e=0;e<8;e++){ s += v[e]; q += v[e]*v[e]; }
        #pragma unroll
        for (int msk = 1; msk < 64; msk <<= 1){
            s += __shfl_xor(s, msk);
            q += __shfl_xor(q, msk);
        }
        float mean = s*(1.0f/DD);
        float var  = q*(1.0f/DD) - mean*mean;
        float rinv = rsqrtf(var+EPSF);
        float4 g0 = ((const float4*)ln1_g)[2*l], g1 = ((const float4*)ln1_g)[2*l+1];
        float4 b0 = ((const float4*)ln1_b)[2*l], b1 = ((const float4*)ln1_b)[2*l+1];
        float gv[8] = {g0.x,g0.y,g0.z,g0.w,g1.x,g1.y,g1.z,g1.w};
        float bv[8] = {b0.x,b0.y,b0.z,b0.w,b1.x,b1.y,b1.z,b1.w};
        us8 o;
        #pragma unroll
        for (int e=0;e<8;e++) o[e] = f2b((v[e]-mean)*rinv*gv[e] + bv[e]);
        ((us8*)(xn + (size_t)row*DD))[l] = o;
        return;
    }
    if (bid >= 13636){
        int i = threadIdx.x;
        stats[i] = 0.0f; stats[256+i] = 0.0f; stats[512+i] = 0.0f; stats[768+i] = 0.0f;
        return;
    }
    int i = (bid - 5376)*256 + threadIdx.x;
    if (i < 524288) { pw1b[i] = f2b(pw1_w[i]); return; }
    i -= 524288;
    if (i < 262144) { pw2b[i] = f2b(pw2_w[i]); return; }
    i -= 262144;
    if (i < 1048576) { posb[i] = (i < 2047*512) ? f2b(pos_emb[i]) : (u16)0; return; }
    i -= 1048576;
    if (i < 15872) { int kk = i >> 9, d = i & 511; wt[i] = dw_w[d*31+kk]; return; }
    i -= 15872;
    if (i < 1536) bqkv[i] = (i < 512) ? bq[i] : (i < 1024 ? bk[i-512] : bv[i-1024]);
}

// ================= conv-module =================
// depthwise conv K=31, GLU fused, BN-stats fused (f32 atomics into zeroed stats)
__global__ __launch_bounds__(256) void dwconv_kernel(const unsigned int* __restrict__ t2i,
    const float* __restrict__ wt, const float* __restrict__ bias, u16* __restrict__ z,
    float* __restrict__ stats)
{
    int d  = blockIdx.x*256 + threadIdx.x;   // gridDim.x = 2
    int c  = blockIdx.y;                     // 0..511
    int b  = c >> 7;
    int t0 = (c & 127) << 3;
    const unsigned int* pa = t2i + (size_t)b*TT*512 + d;
    float wv[31];
    #pragma unroll
    for (int kk=0;kk<31;kk++) wv[kk] = wt[kk*512 + d];
    float xv[38];
    #pragma unroll
    for (int e=0;e<38;e++){
        int tp = t0 - 15 + e;
        if (tp >= 0 && tp < TT){
            unsigned int pv = pa[(size_t)tp*512];
            float a  = b2f((u16)(pv & 0xffffu));
            float gg = b2f((u16)(pv >> 16));
            xv[e] = a * sigmoidf_(gg);
        } else xv[e] = 0.0f;
    }
    float bsv = bias[d];
    float s = 0.f, q = 0.f;
    #pragma unroll
    for (int j=0;j<8;j++){
        float sum = bsv;
        #pragma unroll
        for (int kk=0;kk<31;kk++) sum = fmaf(xv[j+kk], wv[kk], sum);
        z[(size_t)(b*TT+t0+j)*DD + d] = f2b(sum);
        s += sum; q += sum*sum;
    }
    atomicAdd(&stats[d],       s);
    atomicAdd(&stats[512 + d], q);
}

__global__ __launch_bounds__(256) void bn_apply_kernel(const u16* __restrict__ z,
    const float* __restrict__ stats, const float* __restrict__ g, const float* __restrict__ b,
    u16* __restrict__ out)
{
    int idx = blockIdx.x*256 + threadIdx.x;
    int c = idx & (DD-1);
    float m   = stats[c]*(1.0f/NTOK);
    float var = stats[DD+c]*(1.0f/NTOK) - m*m;
    float vv  = (b2f(z[idx])-m)*rsqrtf(var+EPSF)*g[c] + b[c];
    out[idx]  = f2b(vv*sigmoidf_(vv));
}

extern "C" void kernel_launch(void* const* d_in, const int* in_sizes, int n_in,
                              void* d_out, int out_size, void* d_ws, size_t ws_size,
                              hipStream_t stream)
{
    const float* x       = (const float*)d_in[0];
    const float* pos_emb = (const float*)d_in[1];
    const float* ln1_g=(const float*)d_in[2],  *ln1_b=(const float*)d_in[3];
    const float* ln2_g=(const float*)d_in[4],  *ln2_b=(const float*)d_in[5];
    const float* ln3_g=(const float*)d_in[6],  *ln3_b=(const float*)d_in[7];
    const float* ln4_g=(const float*)d_in[8],  *ln4_b=(const float*)d_in[9];
    const float* ln5_g=(const float*)d_in[10], *ln5_b=(const float*)d_in[11];
    const float* ff1_w1=(const float*)d_in[12], *ff1_b1=(const float*)d_in[13];
    const float* ff1_w2=(const float*)d_in[14], *ff1_b2=(const float*)d_in[15];
    const float* wq=(const float*)d_in[16], *bq=(const float*)d_in[17];
    const float* wk=(const float*)d_in[18], *bk=(const float*)d_in[19];
    const float* wv=(const float*)d_in[20], *bv=(const float*)d_in[21];
    const float* wp=(const float*)d_in[22];
    const float* wo=(const float*)d_in[23], *bo=(const float*)d_in[24];
    const float* pos_u=(const float*)d_in[25], *pos_v=(const float*)d_in[26];
    const float* pw1_w=(const float*)d_in[27], *pw1_b=(const float*)d_in[28];
    const float* dw_w=(const float*)d_in[29],  *dw_b=(const float*)d_in[30];
    const float* bn_g=(const float*)d_in[31],  *bn_b=(const float*)d_in[32];
    const float* pw2_w=(const float*)d_in[33], *pw2_b=(const float*)d_in[34];
    const float* ff2_w1=(const float*)d_in[35], *ff2_b1=(const float*)d_in[36];
    const float* ff2_w2=(const float*)d_in[37], *ff2_b2=(const float*)d_in[38];

    char* W = (char*)d_ws;
    u16*  h     = (u16*) (W);                   // 4 MB bf16 residual stream
    u16*  xn    = (u16*) (W + (size_t) 8*MB);   // 4 MB (ln out / attn out)
    u16*  wall  = (u16*) (W + (size_t)12*MB);   // 16 MB prepped weights
    u16*  qub   = (u16*) (W + (size_t)28*MB);   // qub/qvb/kb/vt contiguous
    u16*  qvb   = (u16*) (W + (size_t)32*MB);
    u16*  kb    = (u16*) (W + (size_t)36*MB);
    u16*  vt    = (u16*) (W + (size_t)40*MB);   // (B,H,DK,T)
    u16*  pproj = (u16*) (W + (size_t)44*MB);   // 2048x512
    char* big   = W + (size_t)48*MB;            // shared region
    u16*  ffh   = (u16*)big;                    // 16 MB FFN hidden
    unsigned int* t2i = (unsigned int*)big;     // 8 MB conv (a,g) pairs
    u16*  t3u   = (u16*)(big + (size_t)8*MB);   // 4 MB dwconv out (bf16)
    float* stats= (float*)(W + (size_t)112*MB); // 4 KB (atomics; zeroed in prep)
    float* wt   = stats + 4096;                 // (31,512) f32
    float* bqkv = wt + 15872;                   // 1536 f32

    u16* ff1w1T = wall;
    u16* ff1w2T = wall + 1048576;
    u16* wqT    = wall + 2097152;   // wq/wk/wv contiguous -> N=1536 merged GEMM
    u16* wkT    = wall + 2359296;
    u16* wvT    = wall + 2621440;
    u16* wpT    = wall + 2883584;
    u16* woT    = wall + 3145728;
    u16* ff2w1T = wall + 3407872;
    u16* ff2w2T = wall + 4456448;
    u16* pw1b   = wall + 5505024;
    u16* pw2b   = wall + 6029312;
    u16* posb   = wall + 6291456;

    dim3 blk(256);

    // ---------------- weight prep + ln1 + stats zero (1 launch) -------------
    Prep9 P;
    P.s[0]=ff1_w1; P.d[0]=ff1w1T; P.R[0]=512;  P.C[0]=2048;
    P.s[1]=ff1_w2; P.d[1]=ff1w2T; P.R[1]=2048; P.C[1]=512;
    P.s[2]=wq;     P.d[2]=wqT;    P.R[2]=512;  P.C[2]=512;
    P.s[3]=wk;     P.d[3]=wkT;    P.R[3]=512;  P.C[3]=512;
    P.s[4]=wv;     P.d[4]=wvT;    P.R[4]=512;  P.C[4]=512;
    P.s[5]=wp;     P.d[5]=wpT;    P.R[5]=512;  P.C[5]=512;
    P.s[6]=wo;     P.d[6]=woT;    P.R[6]=512;  P.C[6]=512;
    P.s[7]=ff2_w1; P.d[7]=ff2w1T; P.R[7]=512;  P.C[7]=2048;
    P.s[8]=ff2_w2; P.d[8]=ff2w2T; P.R[8]=2048; P.C[8]=512;
    int tc[9] = {1024,1024,256,256,256,256,256,1024,1024};
    P.t0[0]=0; for (int e=0;e<9;e++) P.t0[e+1]=P.t0[e]+tc[e];
    prep_all<<<dim3(13637), blk, 0, stream>>>(P, pw1_w, pw2_w, pos_emb, dw_w,
                                              bq, bk, bv,
                                              pw1b, pw2b, posb, wt, bqkv,
                                              x, ln1_g, ln1_b, xn, stats);

    // ---------------- FFN1: h = x + 0.5*ffn(ln1(x)) ----------------
    bgemm128<1><<<dim3(16,32), blk, 0, stream>>>(xn,512, ff1w1T,512,
        ffh,2048, 512, ff1_b1,1);
    bgemm64k<<<dim3(8,64), blk, 0, stream>>>(ffh,2048, ff1w2T,2048,
        h,512, 2048, ff1_b2,0.5f, x, nullptr);

    // ---------------- Attention: h = h + attn(ln2(h)) ----------------
    ln_kernel<1,1><<<dim3(NTOK/4), blk, 0, stream>>>(h, ln2_g, ln2_b, xn);
    qkvp_gemm<<<dim3(16,32), blk, 0, stream>>>(xn, wqT, posb, wpT,
        qub, pproj, bqkv, pos_u, pos_v);

    attn_fused<<<dim3(512), blk, 0, stream>>>(qub, qvb, kb, vt, pproj, xn);

    bgemm64k<<<dim3(8,64), blk, 0, stream>>>(xn,512, woT,512,
        h,512, 512, bo,1.f, nullptr, h);

    // ---------------- Conv module ----------------
    ln_kernel<1,1><<<dim3(NTOK/4), blk, 0, stream>>>(h, ln3_g, ln3_b, xn);
    bgemm128<6><<<dim3(8,32), blk, 0, stream>>>(xn,512, pw1b,512,
        t2i,1024, 512, pw1_b,0);
    dwconv_kernel<<<dim3(2,512), blk, 0, stream>>>(t2i, wt, dw_b, t3u, stats);
    bn_apply_kernel<<<dim3(NTOK*DD/256), blk, 0, stream>>>(t3u, stats, bn_g, bn_b, xn);
    bgemm64k<<<dim3(8,64), blk, 0, stream>>>(xn,512, pw2b,512,
        h,512, 512, pw2_b,1.f, nullptr, h);

    // ---------------- FFN2 ----------------
    ln_kernel<1,1><<<dim3(NTOK/4), blk, 0, stream>>>(h, ln4_g, ln4_b, xn);
    bgemm128<1><<<dim3(16,32), blk, 0, stream>>>(xn,512, ff2w1T,512,
        ffh,2048, 512, ff2_b1,1);
    bgemm64k<<<dim3(8,64), blk, 0, stream>>>(ffh,2048, ff2w2T,2048,
        h,512, 2048, ff2_b2,0.5f, nullptr, h);

    // ---------------- Final LN ----------------
    ln_kernel<1,0><<<dim3(NTOK/4), blk, 0, stream>>>(h, ln5_g, ln5_b, (float*)d_out);
}

// Round 15
// 255.332 us; speedup vs baseline: 1.7830x; 1.0109x over previous
//
#include <hip/hip_runtime.h>
#include <math.h>

#define TT   1024
#define BBZ  4
#define DD   512
#define DFF_ 2048
#define HH   8
#define DKK  64
#define NTOK 4096
#define EPSF 1e-5f
#define MB   1048576
// 0.125 * log2(e): scores produced directly in log2 domain
#define QSCALE 0.18033688011112042f
#define M0OFF  24.0f

typedef unsigned short u16;
typedef __attribute__((ext_vector_type(8))) short s8v;    // 8 bf16 (4 VGPRs)
typedef __attribute__((ext_vector_type(4))) float f32x4;
typedef __attribute__((ext_vector_type(4))) unsigned short us4;
typedef __attribute__((ext_vector_type(8))) unsigned short us8;

__device__ __forceinline__ float b2f(u16 v){
    union { unsigned int u; float f; } x; x.u = ((unsigned int)v) << 16; return x.f;
}
__device__ __forceinline__ u16 f2b(float f){
    union { float f; unsigned int u; } x; x.f = f;
    unsigned int r = x.u + 0x7fffu + ((x.u >> 16) & 1u);
    return (u16)(r >> 16);
}
__device__ __forceinline__ float sigmoidf_(float x){ return 1.0f/(1.0f+__expf(-x)); }

__device__ __forceinline__ void gld16(const u16* g, u16* l){
    __builtin_amdgcn_global_load_lds(
        (const __attribute__((address_space(1))) unsigned int*)g,
        (__attribute__((address_space(3))) unsigned int*)l, 16, 0, 0);
}

// ================= 128x128-tile MFMA GEMM, BK=128 =================
// OMODE 1: bf16 out (+bias, act)
template<int OMODE>
__global__ __launch_bounds__(256) void bgemm128(
    const u16* __restrict__ A, int lda,
    const u16* __restrict__ B, int ldb,
    void* __restrict__ Cv, int ldc, int K,
    const float* __restrict__ bias, int act)
{
    int n0 = blockIdx.x * 128;
    int m0 = blockIdx.y * 128;

    __shared__ u16 As[128*128];   // 32 KB
    __shared__ u16 Bs[128*128];   // 32 KB

    int t = threadIdx.x;
    int w = t >> 6, l = t & 63;
    int r4 = l >> 4;
    int s16 = l & 15;
    int kswz = (s16 ^ (w*4 + r4)) * 8;
    int wm = w >> 1, wn = w & 1;
    int lr = l & 15, lk = l >> 4;

    f32x4 acc[4][4] = {};

    for (int k0 = 0; k0 < K; k0 += 128){
        #pragma unroll
        for (int cb = 0; cb < 8; ++cb){
            int rowu = cb*16 + w*4;
            gld16(A + (size_t)(m0 + rowu + r4)*lda + k0 + kswz, &As[rowu*128]);
            gld16(B + (size_t)(n0 + rowu + r4)*ldb + k0 + kswz, &Bs[rowu*128]);
        }
        __syncthreads();

        #pragma unroll
        for (int kh = 0; kh < 4; ++kh){
            int sl = ((kh*4 + lk) ^ lr) * 8;
            s8v af[4], bf[4];
            #pragma unroll
            for (int mi = 0; mi < 4; ++mi)
                af[mi] = *(const s8v*)&As[(wm*64 + mi*16 + lr)*128 + sl];
            #pragma unroll
            for (int ni = 0; ni < 4; ++ni)
                bf[ni] = *(const s8v*)&Bs[(wn*64 + ni*16 + lr)*128 + sl];
            #pragma unroll
            for (int mi = 0; mi < 4; ++mi)
                #pragma unroll
                for (int ni = 0; ni < 4; ++ni)
                    acc[mi][ni] = __builtin_amdgcn_mfma_f32_16x16x32_bf16(
                        af[mi], bf[ni], acc[mi][ni], 0, 0, 0);
        }
        __syncthreads();
    }

    #pragma unroll
    for (int mi = 0; mi < 4; ++mi){
        #pragma unroll
        for (int ni = 0; ni < 4; ++ni){
            int gn = n0 + wn*64 + ni*16 + lr;
            float bval = bias ? bias[gn] : 0.0f;
            #pragma unroll
            for (int r = 0; r < 4; ++r){
                int gm = m0 + wm*64 + mi*16 + lk*4 + r;
                float vv = acc[mi][ni][r] + bval;
                if (act) vv = vv * sigmoidf_(vv);
                ((u16*)Cv)[(size_t)gm*ldc + gn] = f2b(vv);
            }
        }
    }
}

// ================= fused QKV + P-projection GEMM, BK=128 (one dispatch) =====
__global__ __launch_bounds__(256) void qkvp_gemm(
    const u16* __restrict__ xn, const u16* __restrict__ wqT,
    const u16* __restrict__ posb, const u16* __restrict__ wpT,
    u16* __restrict__ qkvbase, u16* __restrict__ pproj,
    const float* __restrict__ bqkv,
    const float* __restrict__ posu, const float* __restrict__ posv)
{
    bool isP = (blockIdx.x >= 12);
    if (isP && blockIdx.y >= 16) return;
    const u16* A = isP ? posb : xn;
    const u16* B = isP ? wpT : wqT;
    int n0 = isP ? (blockIdx.x - 12)*128 : blockIdx.x*128;
    int m0 = blockIdx.y * 128;

    __shared__ u16 As[128*128];
    __shared__ u16 Bs[128*128];

    int t = threadIdx.x;
    int w = t >> 6, l = t & 63;
    int r4 = l >> 4;
    int s16 = l & 15;
    int kswz = (s16 ^ (w*4 + r4)) * 8;
    int wm = w >> 1, wn = w & 1;
    int lr = l & 15, lk = l >> 4;

    f32x4 acc[4][4] = {};

    for (int k0 = 0; k0 < 512; k0 += 128){
        #pragma unroll
        for (int cb = 0; cb < 8; ++cb){
            int rowu = cb*16 + w*4;
            gld16(A + (size_t)(m0 + rowu + r4)*512 + k0 + kswz, &As[rowu*128]);
            gld16(B + (size_t)(n0 + rowu + r4)*512 + k0 + kswz, &Bs[rowu*128]);
        }
        __syncthreads();

        #pragma unroll
        for (int kh = 0; kh < 4; ++kh){
            int sl = ((kh*4 + lk) ^ lr) * 8;
            s8v af[4], bf[4];
            #pragma unroll
            for (int mi = 0; mi < 4; ++mi)
                af[mi] = *(const s8v*)&As[(wm*64 + mi*16 + lr)*128 + sl];
            #pragma unroll
            for (int ni = 0; ni < 4; ++ni)
                bf[ni] = *(const s8v*)&Bs[(wn*64 + ni*16 + lr)*128 + sl];
            #pragma unroll
            for (int mi = 0; mi < 4; ++mi)
                #pragma unroll
                for (int ni = 0; ni < 4; ++ni)
                    acc[mi][ni] = __builtin_amdgcn_mfma_f32_16x16x32_bf16(
                        af[mi], bf[ni], acc[mi][ni], 0, 0, 0);
        }
        __syncthreads();
    }

    #pragma unroll
    for (int mi = 0; mi < 4; ++mi){
        #pragma unroll
        for (int ni = 0; ni < 4; ++ni){
            int gn = n0 + wn*64 + ni*16 + lr;
            float bval = isP ? 0.0f : bqkv[gn];
            #pragma unroll
            for (int r = 0; r < 4; ++r){
                int gm = m0 + wm*64 + mi*16 + lk*4 + r;
                float vv = acc[mi][ni][r] + bval;
                if (isP){
                    pproj[(size_t)gm*512 + gn] = f2b(vv);
                } else {
                    u16* base = qkvbase;
                    if (gn < 512){
                        size_t idx = (size_t)gm*512 + gn;
                        base[idx]              = f2b((vv + posu[gn])*QSCALE);
                        base[idx + (2u<<20)]   = f2b((vv + posv[gn])*QSCALE);
                    } else if (gn < 1024){
                        base[(4u<<20) + (size_t)gm*512 + (gn-512)] = f2b(vv);
                    } else {
                        int gnp = gn - 1024;
                        int bb = gm >> 10, tt2 = gm & 1023;
                        size_t idx = (((size_t)(bb*8 + (gnp>>6)))*64 + (gnp&63))*1024 + tt2;
                        base[(6u<<20) + idx] = f2b(vv);
                    }
                }
            }
        }
    }
}

// ======== 64x64-tile MFMA GEMM, BK=128, DOUBLE-BUFFERED prefetch ============
// attn-style loop: one barrier/iter; next K-tile staged while computing cur.
// OMODE 0: bf16 out, (acc+bias)*alpha + (f32 residF | bf16 residB)
// OMODE 6: interleaved GLU-pair bf16 store (row, d, a/g) for dwconv
template<int OMODE>
__global__ __launch_bounds__(256) void bgemm64k(
    const u16* __restrict__ A, int lda,
    const u16* __restrict__ B, int ldb,
    void* __restrict__ Cv, int ldc, int K,
    const float* __restrict__ bias, float alpha,
    const float* __restrict__ residF, const u16* __restrict__ residB)
{
    int n0 = blockIdx.x * 64;
    int m0 = blockIdx.y * 64;

    __shared__ u16 As[2][64*128];    // 32 KB
    __shared__ u16 Bs[2][64*128];    // 32 KB

    int t = threadIdx.x;
    int w = t >> 6, l = t & 63;
    int r4 = l >> 4;
    int s16 = l & 15;
    int kswz = (s16 ^ (w*4 + r4)) * 8;
    int wm = w >> 1, wn = w & 1;
    int lr = l & 15, lk = l >> 4;

    f32x4 acc[2][2] = {};

    // stage tile 0 into buffer 0
    #pragma unroll
    for (int cb = 0; cb < 4; ++cb){
        int rowu = cb*16 + w*4;
        gld16(A + (size_t)(m0 + rowu + r4)*lda + kswz, &As[0][rowu*128]);
        gld16(B + (size_t)(n0 + rowu + r4)*ldb + kswz, &Bs[0][rowu*128]);
    }

    int nk = K >> 7;
    for (int kt = 0; kt < nk; ++kt){
        int cur = kt & 1;
        __syncthreads();   // drains staged loads for tile kt; prev buf free

        if (kt + 1 < nk){
            int k0n = (kt+1) << 7;
            #pragma unroll
            for (int cb = 0; cb < 4; ++cb){
                int rowu = cb*16 + w*4;
                gld16(A + (size_t)(m0 + rowu + r4)*lda + k0n + kswz, &As[cur^1][rowu*128]);
                gld16(B + (size_t)(n0 + rowu + r4)*ldb + k0n + kswz, &Bs[cur^1][rowu*128]);
            }
        }

        #pragma unroll
        for (int kh = 0; kh < 4; ++kh){
            int sl = ((kh*4 + lk) ^ lr) * 8;
            s8v af[2], bf[2];
            #pragma unroll
            for (int mi = 0; mi < 2; ++mi)
                af[mi] = *(const s8v*)&As[cur][(wm*32 + mi*16 + lr)*128 + sl];
            #pragma unroll
            for (int ni = 0; ni < 2; ++ni)
                bf[ni] = *(const s8v*)&Bs[cur][(wn*32 + ni*16 + lr)*128 + sl];
            #pragma unroll
            for (int mi = 0; mi < 2; ++mi)
                #pragma unroll
                for (int ni = 0; ni < 2; ++ni)
                    acc[mi][ni] = __builtin_amdgcn_mfma_f32_16x16x32_bf16(
                        af[mi], bf[ni], acc[mi][ni], 0, 0, 0);
        }
    }

    #pragma unroll
    for (int mi = 0; mi < 2; ++mi){
        #pragma unroll
        for (int ni = 0; ni < 2; ++ni){
            int gn = n0 + wn*32 + ni*16 + lr;
            float bval = bias ? bias[gn] : 0.0f;
            #pragma unroll
            for (int r = 0; r < 4; ++r){
                int gm = m0 + wm*32 + mi*16 + lk*4 + r;
                float vv = acc[mi][ni][r] + bval;
                if (OMODE == 0){
                    vv *= alpha;
                    size_t idx = (size_t)gm*ldc + gn;
                    if (residF) vv += residF[idx];
                    if (residB) vv += b2f(residB[idx]);
                    ((u16*)Cv)[idx] = f2b(vv);
                } else { // 6: interleaved (a,g) bf16 pairs for dwconv
                    u16* base = (u16*)Cv;
                    size_t idx = (gn < 512)
                        ? ((size_t)gm*512 + gn)*2
                        : ((size_t)gm*512 + (gn-512))*2 + 1;
                    base[idx] = f2b(vv);
                }
            }
        }
    }
}

// ================= fused rel-pos flash attention =================
// 1D grid 512, XCD-aware: s = xcd + 8*(zhi*16 + xx); all 16 i-blocks of a z
// land on one XCD -> K/V/P L2-resident. Fixed-offset base-2 softmax;
// diagonal band, bank-hashed.
__global__ __launch_bounds__(256) void attn_fused(
    const u16* __restrict__ qub, const u16* __restrict__ qvb,
    const u16* __restrict__ kb,  const u16* __restrict__ vt,
    const u16* __restrict__ pp,  u16* __restrict__ out)
{
    int s   = blockIdx.x;
    int xcd = s & 7;
    int k9  = s >> 3;            // 0..63
    int zhi = k9 >> 4;           // 0..3  = b
    int xx  = k9 & 15;           // i-block
    int z   = (zhi << 3) | xcd;  // b*8 + hh
    int b = zhi, hh = xcd;
    int i0 = xx * 64;

    __shared__ u16 Kb2[2][64*64];     // 16 KB
    __shared__ u16 Vb2[2][64*64];     // 16 KB
    __shared__ u16 Pring[3][64*64];   // 24 KB
    __shared__ u16 PT[64*64];         //  8 KB
    __shared__ float Bandd[4][1024];  // 16 KB per-wave [64 diag][16 hashed]

    int t = threadIdx.x;
    int w = t >> 6, l = t & 63;
    int lrow = l >> 3, lslot = l & 7;
    int kswz = (lslot ^ lrow) * 8;
    int lr = l & 15, lk = l >> 4;

    // ---- prologue: qu -> PT, qv -> Bandd (as u16), frags to regs ----
    #pragma unroll
    for (int it = 0; it < 2; ++it){
        int rb = it*32 + w*8;
        gld16(qub + (size_t)(b*TT + i0 + rb + lrow)*DD + hh*64 + kswz, &PT[rb*64]);
        gld16(qvb + (size_t)(b*TT + i0 + rb + lrow)*DD + hh*64 + kswz,
              (u16*)&Bandd[0][0] + rb*64);
    }
    __syncthreads();
    s8v af_u[2], af_v[2];
    #pragma unroll
    for (int kh = 0; kh < 2; ++kh){
        int sl = (kh*4 + lk) ^ (lr & 7);
        af_u[kh] = *(const s8v*)&PT[(w*16 + lr)*64 + sl*8];
        af_v[kh] = *(const s8v*)((const u16*)&Bandd[0][0] + (w*16 + lr)*64 + sl*8);
    }
    // stage K_0 -> Kb2[0], V_0 -> Vb2[0], P chunks 0,1 -> ring
    #pragma unroll
    for (int it = 0; it < 2; ++it){
        int rb = it*32 + w*8;
        gld16(kb + (size_t)(b*TT +        rb + lrow)*DD + hh*64 + kswz, &Kb2[0][rb*64]);
        gld16(vt + ((size_t)z*64 + rb + lrow)*TT +                kswz, &Vb2[0][rb*64]);
        gld16(pp + (size_t)(960  - i0 +   rb + lrow)*DD + hh*64 + kswz, &Pring[0][rb*64]);
        gld16(pp + (size_t)(1024 - i0 +   rb + lrow)*DD + hh*64 + kswz, &Pring[1][rb*64]);
    }

    f32x4 o_[4] = {};
    float Lp[4] = {0.f, 0.f, 0.f, 0.f};   // per-lane partial denominators

    int s0 = 0, s1 = 1, s2 = 2;

    for (int jt = 0; jt < 16; ++jt){
        int cur = jt & 1;
        __syncthreads();  // all staged loads for THIS iter have landed

        // issue next-iter staging (full-iteration landing window)
        if (jt < 15){
            #pragma unroll
            for (int it = 0; it < 2; ++it){
                int rb = it*32 + w*8;
                gld16(kb + (size_t)(b*TT + (jt+1)*64 + rb + lrow)*DD + hh*64 + kswz,
                      &Kb2[cur^1][rb*64]);
                gld16(vt + ((size_t)z*64 + rb + lrow)*TT + (jt+1)*64 + kswz,
                      &Vb2[cur^1][rb*64]);
                gld16(pp + (size_t)(960 + (jt+2)*64 - i0 + rb + lrow)*DD + hh*64 + kswz,
                      &Pring[s2][rb*64]);
            }
        }

        // ---- S_ac (16x64) and band G (16x80) per wave ----
        f32x4 sac[4] = {};
        f32x4 g[5] = {};
        __builtin_amdgcn_s_setprio(1);
        #pragma unroll
        for (int kh = 0; kh < 2; ++kh){
            int sl = (kh*4 + lk) ^ (lr & 7);
            #pragma unroll
            for (int n = 0; n < 4; ++n){
                s8v bK = *(const s8v*)&Kb2[cur][(n*16 + lr)*64 + sl*8];
                sac[n] = __builtin_amdgcn_mfma_f32_16x16x32_bf16(af_u[kh], bK, sac[n], 0,0,0);
            }
            #pragma unroll
            for (int n = 0; n < 5; ++n){
                int nn = (3 - w) + n;
                const u16* pc = (nn & 4) ? &Pring[s1][0] : &Pring[s0][0];
                s8v bP = *(const s8v*)&pc[(((nn&3)*16) + lr)*64 + sl*8];
                g[n] = __builtin_amdgcn_mfma_f32_16x16x32_bf16(af_v[kh], bP, g[n], 0,0,0);
            }
        }
        __builtin_amdgcn_s_setprio(0);

        // ---- band write: diagonal-major, bank-hashed, packed b128 ----
        #pragma unroll
        for (int n = 0; n < 4; ++n){
            int c = (3 - w + n)*16 + lr;
            int d = (c - 63) & 63;
            int rho = (d >> 2) & 3;
            f32x4 vv;
            if (n == 0){
                #pragma unroll
                for (int r = 0; r < 4; ++r){
                    int iia = w*16 + lk*4 + r;
                    vv[r] = (iia >= 63 - c) ? g[0][r] : g[4][r];
                }
            } else {
                vv = g[n];
            }
            bool sw1 = rho & 1, sw2 = rho & 2;
            float b0 = sw1 ? vv[1] : vv[0];
            float b1 = sw1 ? vv[0] : vv[1];
            float b2 = sw1 ? vv[3] : vv[2];
            float b3 = sw1 ? vv[2] : vv[3];
            f32x4 vvp;
            vvp[0] = sw2 ? b2 : b0;
            vvp[1] = sw2 ? b3 : b1;
            vvp[2] = sw2 ? b0 : b2;
            vvp[3] = sw2 ? b1 : b3;
            *(f32x4*)&Bandd[w][d*16 + ((lk + d) & 3)*4] = vvp;
        }

        // ---- combine band + fixed-offset exp2 (wave-local, no shuffles) ----
        float p_[4][4];
        #pragma unroll
        for (int r = 0; r < 4; ++r){
            int ii_l = lk*4 + r;
            float rs = 0.0f;
            #pragma unroll
            for (int n = 0; n < 4; ++n){
                int jj = n*16 + lr;
                int d  = (jj - 16*w - ii_l) & 63;
                float bd = Bandd[w][d*16 + (((ii_l>>2) + d) & 3)*4
                                         + ((ii_l ^ (d>>2)) & 3)];
                float pv = __builtin_amdgcn_exp2f(sac[n][r] + bd - M0OFF);
                p_[n][r] = pv; rs += pv;
            }
            Lp[r] += rs;
        }

        // write P-tilde (swizzled bf16, wave-local rows; read by same wave only)
        #pragma unroll
        for (int n = 0; n < 4; ++n)
            #pragma unroll
            for (int r = 0; r < 4; ++r){
                int ii  = w*16 + lk*4 + r;
                int col = n*16 + lr;
                int sl  = (col>>3) ^ (ii&7);
                PT[ii*64 + sl*8 + (col&7)] = f2b(p_[n][r]);
            }

        // ---- PV (V_jt landed at this iter's top barrier) ----
        __builtin_amdgcn_s_setprio(1);
        #pragma unroll
        for (int kh = 0; kh < 2; ++kh){
            int sl = (kh*4 + lk) ^ (lr & 7);
            s8v ap = *(const s8v*)&PT[(w*16 + lr)*64 + sl*8];
            #pragma unroll
            for (int n = 0; n < 4; ++n){
                s8v bV = *(const s8v*)&Vb2[cur][(n*16 + lr)*64 + sl*8];
                o_[n] = __builtin_amdgcn_mfma_f32_16x16x32_bf16(ap, bV, o_[n], 0,0,0);
            }
        }
        __builtin_amdgcn_s_setprio(0);
        int tmp = s0; s0 = s1; s1 = s2; s2 = tmp;
    }

    // ---- one-time L reduction across the 16-lane col group ----
    float Lr[4];
    #pragma unroll
    for (int r = 0; r < 4; ++r){
        float Lv = Lp[r];
        #pragma unroll
        for (int msk = 1; msk < 16; msk <<= 1) Lv += __shfl_xor(Lv, msk);
        Lr[r] = 1.0f / Lv;
    }

    #pragma unroll
    for (int n = 0; n < 4; ++n)
        #pragma unroll
        for (int r = 0; r < 4; ++r){
            int i  = i0 + w*16 + lk*4 + r;
            int dk = n*16 + lr;
            out[(size_t)(b*TT + i)*DD + hh*64 + dk] = f2b(o_[n][r] * Lr[r]);
        }
}

// ================= LayerNorm: wave per row, shuffle reduce =====
// IB: 1 = bf16 input, 0 = f32 input.  OB: 1 = bf16 out, 0 = f32 out.
template<int IB, int OB>
__global__ __launch_bounds__(256) void ln_kernel(const void* __restrict__ inp,
    const float* __restrict__ g, const float* __restrict__ b, void* __restrict__ outv)
{
    int w = threadIdx.x >> 6, l = threadIdx.x & 63;
    int row = blockIdx.x*4 + w;
    float v[8];
    if (IB){
        us8 xv = ((const us8*)((const u16*)inp + (size_t)row*DD))[l];
        #pragma unroll
        for (int e=0;e<8;e++) v[e] = b2f(xv[e]);
    } else {
        const float4* xr = (const float4*)((const float*)inp + (size_t)row*DD);
        float4 a = xr[2*l], c = xr[2*l+1];
        v[0]=a.x; v[1]=a.y; v[2]=a.z; v[3]=a.w;
        v[4]=c.x; v[5]=c.y; v[6]=c.z; v[7]=c.w;
    }
    float s = 0.f, q = 0.f;
    #pragma unroll
    for (int e=0;e<8;e++){ s += v[e]; q += v[e]*v[e]; }
    #pragma unroll
    for (int msk = 1; msk < 64; msk <<= 1){
        s += __shfl_xor(s, msk);
        q += __shfl_xor(q, msk);
    }
    float mean = s*(1.0f/DD);
    float var  = q*(1.0f/DD) - mean*mean;
    float rinv = rsqrtf(var+EPSF);
    float4 g0 = ((const float4*)g)[2*l], g1 = ((const float4*)g)[2*l+1];
    float4 b0 = ((const float4*)b)[2*l], b1 = ((const float4*)b)[2*l+1];
    float gv[8] = {g0.x,g0.y,g0.z,g0.w,g1.x,g1.y,g1.z,g1.w};
    float bv[8] = {b0.x,b0.y,b0.z,b0.w,b1.x,b1.y,b1.z,b1.w};
    float y[8];
    #pragma unroll
    for (int e=0;e<8;e++) y[e] = (v[e]-mean)*rinv*gv[e] + bv[e];
    if (OB){
        us8 o;
        #pragma unroll
        for (int e=0;e<8;e++) o[e] = f2b(y[e]);
        ((us8*)((u16*)outv + (size_t)row*DD))[l] = o;
    } else {
        float4 o0 = {y[0],y[1],y[2],y[3]};
        float4 o1 = {y[4],y[5],y[6],y[7]};
        float4* op = (float4*)((float*)outv + (size_t)row*DD);
        op[2*l] = o0; op[2*l+1] = o1;
    }
}

// ============ consolidated weight prep + ln1 + stats zero (ONE kernel) ======
struct Prep9 {
    const float* s[9];
    u16* d[9];
    int R[9], C[9];
    int t0[10];
};

__global__ __launch_bounds__(256) void prep_all(Prep9 P,
    const float* __restrict__ pw1_w, const float* __restrict__ pw2_w,
    const float* __restrict__ pos_emb, const float* __restrict__ dw_w,
    const float* __restrict__ bq, const float* __restrict__ bk,
    const float* __restrict__ bv,
    u16* __restrict__ pw1b, u16* __restrict__ pw2b,
    u16* __restrict__ posb, float* __restrict__ wt, float* __restrict__ bqkv,
    const float* __restrict__ x, const float* __restrict__ ln1_g,
    const float* __restrict__ ln1_b, u16* __restrict__ xn,
    float* __restrict__ stats)
{
    __shared__ float tile[32][33];
    int bid = blockIdx.x;
    if (bid < 5376){
        int j = 0;
        #pragma unroll
        for (int e=1; e<9; e++) if (bid >= P.t0[e]) j = e;
        int lb = bid - P.t0[j];
        int nx = P.C[j] >> 5;
        int c0 = (lb % nx) << 5;
        int r0 = (lb / nx) << 5;
        const float* in = P.s[j];
        u16* out = P.d[j];
        int R = P.R[j], C = P.C[j];
        int tx = threadIdx.x & 31, ty = threadIdx.x >> 5;
        #pragma unroll
        for (int i=0;i<4;i++){
            int rr = ty + i*8;
            tile[rr][tx] = in[(size_t)(r0+rr)*C + c0+tx];
        }
        __syncthreads();
        #pragma unroll
        for (int i=0;i<4;i++){
            int cc = ty + i*8;
            out[(size_t)(c0+cc)*R + r0+tx] = f2b(tile[tx][cc]);
        }
        return;
    }
    if (bid >= 12612 && bid < 13636){
        // ln1: wave per row over x (f32) -> xn (bf16)
        int w = threadIdx.x >> 6, l = threadIdx.x & 63;
        int row = (bid - 12612)*4 + w;
        const float4* xr = (const float4*)(x + (size_t)row*DD);
        float4 a = xr[2*l], c = xr[2*l+1];
        float v[8] = {a.x,a.y,a.z,a.w,c.x,c.y,c.z,c.w};
        float s = 0.f, q = 0.f;
        #pragma unroll
        for (int e=0;e<8;e++){ s += v[e]; q += v[e]*v[e]; }
        #pragma unroll
        for (int msk = 1; msk < 64; msk <<= 1){
            s += __shfl_xor(s, msk);
            q += __shfl_xor(q, msk);
        }
        float mean = s*(1.0f/DD);
        float var  = q*(1.0f/DD) - mean*mean;
        float rinv = rsqrtf(var+EPSF);
        float4 g0 = ((const float4*)ln1_g)[2*l], g1 = ((const float4*)ln1_g)[2*l+1];
        float4 b0 = ((const float4*)ln1_b)[2*l], b1 = ((const float4*)ln1_b)[2*l+1];
        float gv[8] = {g0.x,g0.y,g0.z,g0.w,g1.x,g1.y,g1.z,g1.w};
        float bv[8] = {b0.x,b0.y,b0.z,b0.w,b1.x,b1.y,b1.z,b1.w};
        us8 o;
        #pragma unroll
        for (int e=0;e<8;e++) o[e] = f2b((v[e]-mean)*rinv*gv[e] + bv[e]);
        ((us8*)(xn + (size_t)row*DD))[l] = o;
        return;
    }
    if (bid >= 13636){
        int i = threadIdx.x;
        stats[i] = 0.0f; stats[256+i] = 0.0f; stats[512+i] = 0.0f; stats[768+i] = 0.0f;
        return;
    }
    int i = (bid - 5376)*256 + threadIdx.x;
    if (i < 524288) { pw1b[i] = f2b(pw1_w[i]); return; }
    i -= 524288;
    if (i < 262144) { pw2b[i] = f2b(pw2_w[i]); return; }
    i -= 262144;
    if (i < 1048576) { posb[i] = (i < 2047*512) ? f2b(pos_emb[i]) : (u16)0; return; }
    i -= 1048576;
    if (i < 15872) { int kk = i >> 9, d = i & 511; wt[i] = dw_w[d*31+kk]; return; }
    i -= 15872;
    if (i < 1536) bqkv[i] = (i < 512) ? bq[i] : (i < 1024 ? bk[i-512] : bv[i-1024]);
}

// ================= conv-module =================
// depthwise conv K=31, GLU fused, BN-stats fused (f32 atomics into zeroed stats)
__global__ __launch_bounds__(256) void dwconv_kernel(const unsigned int* __restrict__ t2i,
    const float* __restrict__ wt, const float* __restrict__ bias, u16* __restrict__ z,
    float* __restrict__ stats)
{
    int d  = blockIdx.x*256 + threadIdx.x;   // gridDim.x = 2
    int c  = blockIdx.y;                     // 0..511
    int b  = c >> 7;
    int t0 = (c & 127) << 3;
    const unsigned int* pa = t2i + (size_t)b*TT*512 + d;
    float wv[31];
    #pragma unroll
    for (int kk=0;kk<31;kk++) wv[kk] = wt[kk*512 + d];
    float xv[38];
    #pragma unroll
    for (int e=0;e<38;e++){
        int tp = t0 - 15 + e;
        if (tp >= 0 && tp < TT){
            unsigned int pv = pa[(size_t)tp*512];
            float a  = b2f((u16)(pv & 0xffffu));
            float gg = b2f((u16)(pv >> 16));
            xv[e] = a * sigmoidf_(gg);
        } else xv[e] = 0.0f;
    }
    float bsv = bias[d];
    float s = 0.f, q = 0.f;
    #pragma unroll
    for (int j=0;j<8;j++){
        float sum = bsv;
        #pragma unroll
        for (int kk=0;kk<31;kk++) sum = fmaf(xv[j+kk], wv[kk], sum);
        z[(size_t)(b*TT+t0+j)*DD + d] = f2b(sum);
        s += sum; q += sum*sum;
    }
    atomicAdd(&stats[d],       s);
    atomicAdd(&stats[512 + d], q);
}

__global__ __launch_bounds__(256) void bn_apply_kernel(const u16* __restrict__ z,
    const float* __restrict__ stats, const float* __restrict__ g, const float* __restrict__ b,
    u16* __restrict__ out)
{
    int idx = blockIdx.x*256 + threadIdx.x;
    int c = idx & (DD-1);
    float m   = stats[c]*(1.0f/NTOK);
    float var = stats[DD+c]*(1.0f/NTOK) - m*m;
    float vv  = (b2f(z[idx])-m)*rsqrtf(var+EPSF)*g[c] + b[c];
    out[idx]  = f2b(vv*sigmoidf_(vv));
}

extern "C" void kernel_launch(void* const* d_in, const int* in_sizes, int n_in,
                              void* d_out, int out_size, void* d_ws, size_t ws_size,
                              hipStream_t stream)
{
    const float* x       = (const float*)d_in[0];
    const float* pos_emb = (const float*)d_in[1];
    const float* ln1_g=(const float*)d_in[2],  *ln1_b=(const float*)d_in[3];
    const float* ln2_g=(const float*)d_in[4],  *ln2_b=(const float*)d_in[5];
    const float* ln3_g=(const float*)d_in[6],  *ln3_b=(const float*)d_in[7];
    const float* ln4_g=(const float*)d_in[8],  *ln4_b=(const float*)d_in[9];
    const float* ln5_g=(const float*)d_in[10], *ln5_b=(const float*)d_in[11];
    const float* ff1_w1=(const float*)d_in[12], *ff1_b1=(const float*)d_in[13];
    const float* ff1_w2=(const float*)d_in[14], *ff1_b2=(const float*)d_in[15];
    const float* wq=(const float*)d_in[16], *bq=(const float*)d_in[17];
    const float* wk=(const float*)d_in[18], *bk=(const float*)d_in[19];
    const float* wv=(const float*)d_in[20], *bv=(const float*)d_in[21];
    const float* wp=(const float*)d_in[22];
    const float* wo=(const float*)d_in[23], *bo=(const float*)d_in[24];
    const float* pos_u=(const float*)d_in[25], *pos_v=(const float*)d_in[26];
    const float* pw1_w=(const float*)d_in[27], *pw1_b=(const float*)d_in[28];
    const float* dw_w=(const float*)d_in[29],  *dw_b=(const float*)d_in[30];
    const float* bn_g=(const float*)d_in[31],  *bn_b=(const float*)d_in[32];
    const float* pw2_w=(const float*)d_in[33], *pw2_b=(const float*)d_in[34];
    const float* ff2_w1=(const float*)d_in[35], *ff2_b1=(const float*)d_in[36];
    const float* ff2_w2=(const float*)d_in[37], *ff2_b2=(const float*)d_in[38];

    char* W = (char*)d_ws;
    u16*  h     = (u16*) (W);                   // 4 MB bf16 residual stream
    u16*  xn    = (u16*) (W + (size_t) 8*MB);   // 4 MB (ln out / attn out)
    u16*  wall  = (u16*) (W + (size_t)12*MB);   // 16 MB prepped weights
    u16*  qub   = (u16*) (W + (size_t)28*MB);   // qub/qvb/kb/vt contiguous
    u16*  qvb   = (u16*) (W + (size_t)32*MB);
    u16*  kb    = (u16*) (W + (size_t)36*MB);
    u16*  vt    = (u16*) (W + (size_t)40*MB);   // (B,H,DK,T)
    u16*  pproj = (u16*) (W + (size_t)44*MB);   // 2048x512
    char* big   = W + (size_t)48*MB;            // shared region
    u16*  ffh   = (u16*)big;                    // 16 MB FFN hidden
    unsigned int* t2i = (unsigned int*)big;     // 8 MB conv (a,g) pairs
    u16*  t3u   = (u16*)(big + (size_t)8*MB);   // 4 MB dwconv out (bf16)
    float* stats= (float*)(W + (size_t)112*MB); // 4 KB (atomics; zeroed in prep)
    float* wt   = stats + 4096;                 // (31,512) f32
    float* bqkv = wt + 15872;                   // 1536 f32

    u16* ff1w1T = wall;
    u16* ff1w2T = wall + 1048576;
    u16* wqT    = wall + 2097152;   // wq/wk/wv contiguous -> N=1536 merged GEMM
    u16* wkT    = wall + 2359296;
    u16* wvT    = wall + 2621440;
    u16* wpT    = wall + 2883584;
    u16* woT    = wall + 3145728;
    u16* ff2w1T = wall + 3407872;
    u16* ff2w2T = wall + 4456448;
    u16* pw1b   = wall + 5505024;
    u16* pw2b   = wall + 6029312;
    u16* posb   = wall + 6291456;

    dim3 blk(256);

    // ---------------- weight prep + ln1 + stats zero (1 launch) -------------
    Prep9 P;
    P.s[0]=ff1_w1; P.d[0]=ff1w1T; P.R[0]=512;  P.C[0]=2048;
    P.s[1]=ff1_w2; P.d[1]=ff1w2T; P.R[1]=2048; P.C[1]=512;
    P.s[2]=wq;     P.d[2]=wqT;    P.R[2]=512;  P.C[2]=512;
    P.s[3]=wk;     P.d[3]=wkT;    P.R[3]=512;  P.C[3]=512;
    P.s[4]=wv;     P.d[4]=wvT;    P.R[4]=512;  P.C[4]=512;
    P.s[5]=wp;     P.d[5]=wpT;    P.R[5]=512;  P.C[5]=512;
    P.s[6]=wo;     P.d[6]=woT;    P.R[6]=512;  P.C[6]=512;
    P.s[7]=ff2_w1; P.d[7]=ff2w1T; P.R[7]=512;  P.C[7]=2048;
    P.s[8]=ff2_w2; P.d[8]=ff2w2T; P.R[8]=2048; P.C[8]=512;
    int tc[9] = {1024,1024,256,256,256,256,256,1024,1024};
    P.t0[0]=0; for (int e=0;e<9;e++) P.t0[e+1]=P.t0[e]+tc[e];
    prep_all<<<dim3(13637), blk, 0, stream>>>(P, pw1_w, pw2_w, pos_emb, dw_w,
                                              bq, bk, bv,
                                              pw1b, pw2b, posb, wt, bqkv,
                                              x, ln1_g, ln1_b, xn, stats);

    // ---------------- FFN1: h = x + 0.5*ffn(ln1(x)) ----------------
    bgemm128<1><<<dim3(16,32), blk, 0, stream>>>(xn,512, ff1w1T,512,
        ffh,2048, 512, ff1_b1,1);
    bgemm64k<0><<<dim3(8,64), blk, 0, stream>>>(ffh,2048, ff1w2T,2048,
        h,512, 2048, ff1_b2,0.5f, x, nullptr);

    // ---------------- Attention: h = h + attn(ln2(h)) ----------------
    ln_kernel<1,1><<<dim3(NTOK/4), blk, 0, stream>>>(h, ln2_g, ln2_b, xn);
    qkvp_gemm<<<dim3(16,32), blk, 0, stream>>>(xn, wqT, posb, wpT,
        qub, pproj, bqkv, pos_u, pos_v);

    attn_fused<<<dim3(512), blk, 0, stream>>>(qub, qvb, kb, vt, pproj, xn);

    bgemm64k<0><<<dim3(8,64), blk, 0, stream>>>(xn,512, woT,512,
        h,512, 512, bo,1.f, nullptr, h);

    // ---------------- Conv module ----------------
    ln_kernel<1,1><<<dim3(NTOK/4), blk, 0, stream>>>(h, ln3_g, ln3_b, xn);
    bgemm64k<6><<<dim3(16,64), blk, 0, stream>>>(xn,512, pw1b,512,
        t2i,1024, 512, pw1_b,1.f, nullptr, nullptr);
    dwconv_kernel<<<dim3(2,512), blk, 0, stream>>>(t2i, wt, dw_b, t3u, stats);
    bn_apply_kernel<<<dim3(NTOK*DD/256), blk, 0, stream>>>(t3u, stats, bn_g, bn_b, xn);
    bgemm64k<0><<<dim3(8,64), blk, 0, stream>>>(xn,512, pw2b,512,
        h,512, 512, pw2_b,1.f, nullptr, h);

    // ---------------- FFN2 ----------------
    ln_kernel<1,1><<<dim3(NTOK/4), blk, 0, stream>>>(h, ln4_g, ln4_b, xn);
    bgemm128<1><<<dim3(16,32), blk, 0, stream>>>(xn,512, ff2w1T,512,
        ffh,2048, 512, ff2_b1,1);
    bgemm64k<0><<<dim3(8,64), blk, 0, stream>>>(ffh,2048, ff2w2T,2048,
        h,512, 2048, ff2_b2,0.5f, nullptr, h);

    // ---------------- Final LN ----------------
    ln_kernel<1,0><<<dim3(NTOK/4), blk, 0, stream>>>(h, ln5_g, ln5_b, (float*)d_out);
}